// Round 12
// baseline (555.348 us; speedup 1.0000x reference)
//
#include <hip/hip_runtime.h>
#include <math.h>

// GNN denoiser: N=32768 (=512 base x 64 batch), HID=128, L=4.
// Base-major node layout. Edge MLP v7 (cooperative build, W2 in regs).
// Node MLP / AB / out-proj: BARRIER-FREE — MFMA B-frags streamed from
// global (L2-hot weights), A-frags wave-private; only 4KB/wave LDS for
// in-wave transposes. LN fused; node-MLP emits next layer's [A|B].

#define HIDDEN 128
#define NLAYERS 4
#define NBASE 512
#define NB 64
#define CODE 1024

typedef __attribute__((ext_vector_type(8))) short s16x8;
typedef __attribute__((ext_vector_type(4))) float f32x4;

__device__ __forceinline__ unsigned int cvt_pk_bf16(float lo, float hi) {
    unsigned int d;
    asm("v_cvt_pk_bf16_f32 %0, %1, %2" : "=v"(d) : "v"(lo), "v"(hi));
    return d;
}
__device__ __forceinline__ unsigned short f2bf(float x) {
    return (unsigned short)cvt_pk_bf16(x, x);
}
__device__ __forceinline__ float silu_f(float x) {
    float e = __expf(-x);
    float r;
    asm("v_rcp_f32 %0, %1" : "=v"(r) : "v"(1.f + e));
    return x * r;
}

// ---------------- fused prep: all weight conversion + graph prep ----------
__device__ __forceinline__ void conv_body(
    const float* __restrict__ s, unsigned short* __restrict__ d,
    int blk, int tid, int n) {
    int i = (blk * 256 + tid) * 4;
    if (i >= n) return;
    float4 v = *reinterpret_cast<const float4*>(s + i);
    uint2 o = { cvt_pk_bf16(v.x, v.y), cvt_pk_bf16(v.z, v.w) };
    *reinterpret_cast<uint2*>(d + i) = o;
}

__global__ __launch_bounds__(256) void prep_all(
    const float* __restrict__ W_in, const float* __restrict__ W_out,
    const float* __restrict__ nW1, const float* __restrict__ nW2,
    const float* __restrict__ eW2, const float* __restrict__ eW1,
    const float* __restrict__ eb1,
    const int* __restrict__ row, const int* __restrict__ col,
    const float* __restrict__ gc,
    unsigned short* __restrict__ winbf, unsigned short* __restrict__ woutbf,
    unsigned short* __restrict__ wn1bf, unsigned short* __restrict__ wn2bf,
    unsigned short* __restrict__ w2bf, unsigned short* __restrict__ w1ab,
    float* __restrict__ bias256, float* __restrict__ c01,
    int* __restrict__ brp, int* __restrict__ bcol, int baseE) {
    int blk = blockIdx.x, tid = threadIdx.x;
    if (blk < 128)      { conv_body(W_in,  winbf,  blk,       tid, HIDDEN * CODE); return; }
    if (blk < 256)      { conv_body(W_out, woutbf, blk - 128, tid, CODE * HIDDEN); return; }
    if (blk < 384)      { conv_body(nW1,   wn1bf,  blk - 256, tid, NLAYERS * HIDDEN * 256); return; }
    if (blk < 448)      { conv_body(nW2,   wn2bf,  blk - 384, tid, NLAYERS * HIDDEN * HIDDEN); return; }
    if (blk < 512)      { conv_body(eW2,   w2bf,   blk - 448, tid, NLAYERS * HIDDEN * HIDDEN); return; }
    if (blk < 516) {    // per-layer pack
        int l = blk - 512;
        const float* w = eW1 + (size_t)l * HIDDEN * 257;
        for (int i = tid; i < 256 * 128; i += 256) {
            int n = i >> 7, k = i & 127;
            float v = (n < 128) ? w[(size_t)n * 257 + k]
                                : w[(size_t)(n - 128) * 257 + 128 + k];
            w1ab[(size_t)l * 256 * 128 + i] = f2bf(v);
        }
        if (tid < 256)
            bias256[(size_t)l * 256 + tid] =
                (tid < 128) ? 0.f : eb1[(size_t)l * HIDDEN + tid - 128];
        if (tid < 128) {
            float wd = w[(size_t)tid * 257 + 256];
            c01[(size_t)l * 256 + tid] = 2.f * wd;
            c01[(size_t)l * 256 + 128 + tid] = sqrtf(8.f) * wd;
        }
        return;
    }
    if (blk < 519) {    // rowptr over base graph
        int v = (blk - 516) * 256 + tid;
        if (v > NBASE) return;
        int lo = 0, hi = baseE;
        while (lo < hi) {
            int mid = (lo + hi) >> 1;
            if (row[mid] < v) lo = mid + 1; else hi = mid;
        }
        brp[v] = lo;
        return;
    }
    {   // basecol: packed cls<<15 | j
        int t = (blk - 519) * 256 + tid;
        if (t >= baseE) return;
        int u = col[t], v = row[t];
        float dx = gc[(size_t)u * 3 + 0] - gc[(size_t)v * 3 + 0];
        float dy = gc[(size_t)u * 3 + 1] - gc[(size_t)v * 3 + 1];
        float dz = gc[(size_t)u * 3 + 2] - gc[(size_t)v * 3 + 2];
        float d2 = dx * dx + dy * dy + dz * dz;
        bcol[t] = u | ((d2 > 6.f ? 1 : 0) << 15);
    }
}

// ---------------- barrier-free row GEMM: wave = 16 rows x 128 cols --------
// C[.., cb..cb+128] = A[M,K] @ W[Ntot,K]^T + bias ; K%32==0. No LDS.
__global__ __launch_bounds__(256) void rggemm(
    const unsigned short* __restrict__ A, int K,
    const unsigned short* __restrict__ W,
    const float* __restrict__ bias,
    float* __restrict__ Cf, unsigned short* __restrict__ Cb, int ldC, int perm) {
    int tid = threadIdx.x;
    int wid = tid >> 6, l = tid & 63, lr = l & 15, lg = l >> 4;
    int rowb = blockIdx.x * 64 + wid * 16;
    int cb = blockIdx.y * 128;
    f32x4 acc[8];
#pragma unroll
    for (int ni = 0; ni < 8; ++ni) {
        f32x4 z = { 0.f, 0.f, 0.f, 0.f };
        acc[ni] = z;
    }
    for (int ks = 0; ks < (K >> 5); ++ks) {
        s16x8 af = *reinterpret_cast<const s16x8*>(
            A + (size_t)(rowb + lr) * K + ks * 32 + lg * 8);
#pragma unroll
        for (int ni = 0; ni < 8; ++ni) {
            s16x8 bf = *reinterpret_cast<const s16x8*>(
                W + (size_t)(cb + ni * 16 + lr) * K + ks * 32 + lg * 8);
            acc[ni] = __builtin_amdgcn_mfma_f32_16x16x32_bf16(af, bf, acc[ni], 0, 0, 0);
        }
    }
#pragma unroll
    for (int ni = 0; ni < 8; ++ni) {
        int colg = cb + ni * 16 + lr;
        float bs = bias ? bias[colg] : 0.f;
#pragma unroll
        for (int r4 = 0; r4 < 4; ++r4) {
            int rowg = rowb + lg * 4 + r4;
            int orow = (perm == 2) ? (rowg & 63) * 512 + (rowg >> 6) : rowg;
            float v = acc[ni][r4] + bs;
            if (Cf) Cf[(size_t)orow * ldC + colg] = v;
            if (Cb) Cb[(size_t)orow * ldC + colg] = f2bf(v);
        }
    }
}

// ---------------- in-projection + fused LN0, pipelined K-loop ------------
__global__ __launch_bounds__(256) void inproj_ln(
    const float* __restrict__ y,
    const unsigned short* __restrict__ W, const float* __restrict__ bias,
    const float* __restrict__ g, const float* __restrict__ bet,
    float* __restrict__ hn, unsigned short* __restrict__ hnbf) {
    __shared__ __align__(16) unsigned short As[64 * 128];
    __shared__ __align__(16) unsigned short Ws[128 * 128];
    int tid = threadIdx.x;
    int wid = tid >> 6, l = tid & 63, lr = l & 15, lg = l >> 4;
    int row0 = blockIdx.x * 64;
    f32x4 acc[8];
#pragma unroll
    for (int ni = 0; ni < 8; ++ni) {
        f32x4 z = { 0.f, 0.f, 0.f, 0.f };
        acc[ni] = z;
    }
    float4 pa0[4], pa1[4];
    s16x8 pw[8];
    auto loadc = [&](int kc) {
#pragma unroll
        for (int jj = 0; jj < 4; ++jj) {
            int j = tid + jj * 256, r = j >> 4, c = j & 15;
            const float* p = y + (size_t)(row0 + r) * CODE + kc + c * 8;
            pa0[jj] = *reinterpret_cast<const float4*>(p);
            pa1[jj] = *reinterpret_cast<const float4*>(p + 4);
        }
#pragma unroll
        for (int jj = 0; jj < 8; ++jj) {
            int j = tid + jj * 256, r = j >> 4, c = j & 15;
            pw[jj] = *reinterpret_cast<const s16x8*>(W + (size_t)r * CODE + kc + c * 8);
        }
    };
    auto storec = [&]() {
#pragma unroll
        for (int jj = 0; jj < 4; ++jj) {
            int j = tid + jj * 256, r = j >> 4, c = j & 15;
            union { s16x8 s; unsigned int w[4]; } pk;
            pk.w[0] = cvt_pk_bf16(pa0[jj].x, pa0[jj].y);
            pk.w[1] = cvt_pk_bf16(pa0[jj].z, pa0[jj].w);
            pk.w[2] = cvt_pk_bf16(pa1[jj].x, pa1[jj].y);
            pk.w[3] = cvt_pk_bf16(pa1[jj].z, pa1[jj].w);
            *reinterpret_cast<s16x8*>(&As[r * 128 + ((c ^ (r & 7)) << 3)]) = pk.s;
        }
#pragma unroll
        for (int jj = 0; jj < 8; ++jj) {
            int j = tid + jj * 256, r = j >> 4, c = j & 15;
            *reinterpret_cast<s16x8*>(&Ws[r * 128 + ((c ^ (r & 7)) << 3)]) = pw[jj];
        }
    };
    loadc(0);
    for (int kc8 = 0; kc8 < 8; ++kc8) {
        storec();
        __syncthreads();
        if (kc8 < 7) loadc((kc8 + 1) * 128);   // prefetch next chunk to regs
#pragma unroll
        for (int ks = 0; ks < 4; ++ks) {
            int c = ks * 4 + lg;
            int r = wid * 16 + lr;
            s16x8 af = *reinterpret_cast<s16x8*>(&As[r * 128 + ((c ^ (r & 7)) << 3)]);
#pragma unroll
            for (int ni = 0; ni < 8; ++ni) {
                int n = ni * 16 + lr;
                s16x8 bf = *reinterpret_cast<s16x8*>(&Ws[n * 128 + ((c ^ (n & 7)) << 3)]);
                acc[ni] = __builtin_amdgcn_mfma_f32_16x16x32_bf16(af, bf, acc[ni], 0, 0, 0);
            }
        }
        __syncthreads();
    }
#pragma unroll
    for (int ni = 0; ni < 8; ++ni) {
        float bs = bias[ni * 16 + lr];
#pragma unroll
        for (int r4 = 0; r4 < 4; ++r4) acc[ni][r4] += bs;
    }
    float s[4], q[4];
#pragma unroll
    for (int r4 = 0; r4 < 4; ++r4) {
        float ss = 0.f, qq = 0.f;
#pragma unroll
        for (int ni = 0; ni < 8; ++ni) {
            float v = acc[ni][r4];
            ss += v; qq += v * v;
        }
#pragma unroll
        for (int o = 1; o < 16; o <<= 1) {
            ss += __shfl_xor(ss, o, 64);
            qq += __shfl_xor(qq, o, 64);
        }
        float mu = ss * (1.f / 128.f);
        float var = qq * (1.f / 128.f) - mu * mu;
        s[r4] = mu;
        q[r4] = rsqrtf(var + 1e-5f);
    }
#pragma unroll
    for (int ni = 0; ni < 8; ++ni) {
        int col = ni * 16 + lr;
        float gg = g[col], bb = bet[col];
#pragma unroll
        for (int r4 = 0; r4 < 4; ++r4) {
            int rowg = row0 + wid * 16 + lg * 4 + r4;
            int orow = (rowg & 511) * 64 + (rowg >> 9);
            float o = (acc[ni][r4] - s[r4]) * q[r4] * gg + bb;
            hn[(size_t)orow * HIDDEN + col] = o;
            hnbf[(size_t)orow * HIDDEN + col] = f2bf(o);
        }
    }
}

// ---------------- barrier-free fused node MLP + next LN + next [A|B] -----
// Wave = 16 rows. Weights streamed from global (L2-hot). LDS: 4KB/wave
// private region only for in-wave transposes (t, hn'). Zero barriers.
__global__ __launch_bounds__(256) void nmlp2(
    const unsigned short* __restrict__ hnbf,
    const unsigned short* __restrict__ magbf,
    const unsigned short* __restrict__ w1, const float* __restrict__ b1,
    const unsigned short* __restrict__ w2, const float* __restrict__ b2,
    const float* __restrict__ resid,
    const float* __restrict__ g, const float* __restrict__ bet,
    float* __restrict__ hn_out, unsigned short* __restrict__ hnbf_out,
    unsigned short* __restrict__ hbf_out,
    const unsigned short* __restrict__ w1ab_next,
    const float* __restrict__ eb1_next,
    unsigned short* __restrict__ ab_out) {
    __shared__ __align__(16) unsigned short As[64 * 128];
    int tid = threadIdx.x;
    int wid = tid >> 6, l = tid & 63, lr = l & 15, lg = l >> 4;
    int rowb = blockIdx.x * 64 + wid * 16;
    unsigned short* myT = As + wid * 16 * 128;   // wave-private 4KB
    f32x4 acc[8];
#pragma unroll
    for (int ni = 0; ni < 8; ++ni) {
        f32x4 z = { 0.f, 0.f, 0.f, 0.f };
        acc[ni] = z;
    }
    // stage 1: [hn | mag] @ W1^T  (A-frags from global, B-frags from global)
#pragma unroll
    for (int kc = 0; kc < 2; ++kc) {
        const unsigned short* Xsrc = kc ? magbf : hnbf;
#pragma unroll
        for (int ks = 0; ks < 4; ++ks) {
            s16x8 af = *reinterpret_cast<const s16x8*>(
                Xsrc + (size_t)(rowb + lr) * 128 + ks * 32 + lg * 8);
#pragma unroll
            for (int ni = 0; ni < 8; ++ni) {
                s16x8 bf = *reinterpret_cast<const s16x8*>(
                    w1 + (size_t)(ni * 16 + lr) * 256 + kc * 128 + ks * 32 + lg * 8);
                acc[ni] = __builtin_amdgcn_mfma_f32_16x16x32_bf16(af, bf, acc[ni], 0, 0, 0);
            }
        }
    }
    // t = silu(acc + b1) -> wave-private LDS (swizzled)
#pragma unroll
    for (int ni = 0; ni < 8; ++ni) {
        int col = ni * 16 + lr;
        float bs = b1[col];
        int cc = col >> 3, cin = col & 7;
#pragma unroll
        for (int r4 = 0; r4 < 4; ++r4) {
            int rl = lg * 4 + r4;
            myT[rl * 128 + ((cc ^ (rl & 7)) << 3) + cin] =
                f2bf(silu_f(acc[ni][r4] + bs));
            acc[ni][r4] = 0.f;
        }
    }
    // stage 2: t @ W2^T
#pragma unroll
    for (int ks = 0; ks < 4; ++ks) {
        int cc = ks * 4 + lg;
        s16x8 af = *reinterpret_cast<s16x8*>(&myT[lr * 128 + ((cc ^ (lr & 7)) << 3)]);
#pragma unroll
        for (int ni = 0; ni < 8; ++ni) {
            s16x8 bf = *reinterpret_cast<const s16x8*>(
                w2 + (size_t)(ni * 16 + lr) * 128 + ks * 32 + lg * 8);
            acc[ni] = __builtin_amdgcn_mfma_f32_16x16x32_bf16(af, bf, acc[ni], 0, 0, 0);
        }
    }
    // h = acc + b2 + resid
#pragma unroll
    for (int ni = 0; ni < 8; ++ni) {
        int col = ni * 16 + lr;
        float bs = b2[col];
#pragma unroll
        for (int r4 = 0; r4 < 4; ++r4) {
            int rowg = rowb + lg * 4 + r4;
            acc[ni][r4] += bs + resid[(size_t)rowg * HIDDEN + col];
        }
    }
    if (!g) {   // last layer: h as bf16 for out-proj
#pragma unroll
        for (int ni = 0; ni < 8; ++ni) {
            int col = ni * 16 + lr;
#pragma unroll
            for (int r4 = 0; r4 < 4; ++r4) {
                int rowg = rowb + lg * 4 + r4;
                hbf_out[(size_t)rowg * HIDDEN + col] = f2bf(acc[ni][r4]);
            }
        }
        return;
    }
    // LN (acc <- hn')
    float s[4], q[4];
#pragma unroll
    for (int r4 = 0; r4 < 4; ++r4) {
        float ss = 0.f, qq = 0.f;
#pragma unroll
        for (int ni = 0; ni < 8; ++ni) {
            float v = acc[ni][r4];
            ss += v; qq += v * v;
        }
#pragma unroll
        for (int o = 1; o < 16; o <<= 1) {
            ss += __shfl_xor(ss, o, 64);
            qq += __shfl_xor(qq, o, 64);
        }
        float mu = ss * (1.f / 128.f);
        float var = qq * (1.f / 128.f) - mu * mu;
        s[r4] = mu;
        q[r4] = rsqrtf(var + 1e-5f);
    }
#pragma unroll
    for (int ni = 0; ni < 8; ++ni) {
        int col = ni * 16 + lr;
        float gg = g[col], bb = bet[col];
#pragma unroll
        for (int r4 = 0; r4 < 4; ++r4) {
            int rowg = rowb + lg * 4 + r4;
            float o = (acc[ni][r4] - s[r4]) * q[r4] * gg + bb;
            hn_out[(size_t)rowg * HIDDEN + col] = o;
            hnbf_out[(size_t)rowg * HIDDEN + col] = f2bf(o);
            acc[ni][r4] = o;
        }
    }
    // next layer [A|B]: hn' -> wave-private LDS, two W halves from global
#pragma unroll
    for (int ni = 0; ni < 8; ++ni) {
        int col = ni * 16 + lr;
        int cc = col >> 3, cin = col & 7;
#pragma unroll
        for (int r4 = 0; r4 < 4; ++r4) {
            int rl = lg * 4 + r4;
            myT[rl * 128 + ((cc ^ (rl & 7)) << 3) + cin] = f2bf(acc[ni][r4]);
        }
    }
#pragma unroll
    for (int half = 0; half < 2; ++half) {
#pragma unroll
        for (int ni = 0; ni < 8; ++ni) {
            f32x4 z = { 0.f, 0.f, 0.f, 0.f };
            acc[ni] = z;
        }
#pragma unroll
        for (int ks = 0; ks < 4; ++ks) {
            int cc = ks * 4 + lg;
            s16x8 af = *reinterpret_cast<s16x8*>(&myT[lr * 128 + ((cc ^ (lr & 7)) << 3)]);
#pragma unroll
            for (int ni = 0; ni < 8; ++ni) {
                s16x8 bf = *reinterpret_cast<const s16x8*>(
                    w1ab_next + (size_t)(half * 128 + ni * 16 + lr) * 128 + ks * 32 + lg * 8);
                acc[ni] = __builtin_amdgcn_mfma_f32_16x16x32_bf16(af, bf, acc[ni], 0, 0, 0);
            }
        }
#pragma unroll
        for (int ni = 0; ni < 8; ++ni) {
            int col = ni * 16 + lr;
            float bs = half ? eb1_next[col] : 0.f;
#pragma unroll
            for (int r4 = 0; r4 < 4; ++r4) {
                int rowg = rowb + lg * 4 + r4;
                ab_out[(size_t)rowg * 256 + half * 128 + col] =
                    f2bf(acc[ni][r4] + bs);
            }
        }
    }
}

// ---------------- edge MLP v7: cooperative build, W2 in registers ---------
__global__ __launch_bounds__(256, 4) void edge_mfma7(
    const unsigned short* __restrict__ ABbf,
    const int* __restrict__ bcol,
    const int* __restrict__ brp,
    const unsigned short* __restrict__ w2bf,
    const float* __restrict__ c01,
    const float* __restrict__ eb2l,
    unsigned short* __restrict__ magbf) {
    __shared__ __align__(16) unsigned short m1[2][16 * 128];
    int tid = threadIdx.x;
    int blk = blockIdx.x;
    int i = blk >> 2, qtr = blk & 3;
    int wid = tid >> 6, l = tid & 63, lr = l & 15, lg = l >> 4;
    int rowb = qtr * 16;
    int col0 = wid * 32;

    s16x8 wfr[4][2];
#pragma unroll
    for (int ks = 0; ks < 4; ++ks)
#pragma unroll
        for (int ni = 0; ni < 2; ++ni) {
            int n = col0 + ni * 16 + lr;
            wfr[ks][ni] = *reinterpret_cast<const s16x8*>(
                w2bf + (size_t)n * 128 + (ks * 4 + lg) * 8);
        }

    int s = brp[i], e = brp[i + 1];

    int br = tid >> 4, bc = tid & 15;
    s16x8 Bp[2];
    {
        union { s16x8 s; unsigned int w[4]; } bv;
        bv.s = *reinterpret_cast<const s16x8*>(
            ABbf + ((size_t)i * NB + rowb + br) * 256 + 128 + bc * 8);
#pragma unroll
        for (int cls = 0; cls < 2; ++cls) {
            const float* cp = c01 + cls * 128 + bc * 8;
            float4 ca = *reinterpret_cast<const float4*>(cp);
            float4 cb = *reinterpret_cast<const float4*>(cp + 4);
            union { s16x8 s; unsigned int w[4]; } pk;
            pk.w[0] = cvt_pk_bf16(__uint_as_float(bv.w[0] << 16) + ca.x,
                                  __uint_as_float(bv.w[0] & 0xffff0000u) + ca.y);
            pk.w[1] = cvt_pk_bf16(__uint_as_float(bv.w[1] << 16) + ca.z,
                                  __uint_as_float(bv.w[1] & 0xffff0000u) + ca.w);
            pk.w[2] = cvt_pk_bf16(__uint_as_float(bv.w[2] << 16) + cb.x,
                                  __uint_as_float(bv.w[2] & 0xffff0000u) + cb.y);
            pk.w[3] = cvt_pk_bf16(__uint_as_float(bv.w[3] << 16) + cb.z,
                                  __uint_as_float(bv.w[3] & 0xffff0000u) + cb.w);
            Bp[cls] = pk.s;
        }
    }
    float e2[2], se[2];
#pragma unroll
    for (int ni = 0; ni < 2; ++ni) {
        e2[ni] = eb2l[col0 + ni * 16 + lr];
        se[ni] = silu_f(e2[ni]);
    }
    f32x4 agg[2];
#pragma unroll
    for (int ni = 0; ni < 2; ++ni) {
        f32x4 z = { 0.f, 0.f, 0.f, 0.f };
        agg[ni] = z;
    }

    int pk0 = __builtin_amdgcn_readfirstlane(bcol[s]);
    s16x8 Areg = *reinterpret_cast<const s16x8*>(
        ABbf + ((size_t)(pk0 & 0x7fff) * NB + rowb + br) * 256 + bc * 8);

    for (int t = s; t < e; ++t) {
        int cls = (pk0 >> 15) & 1;
        int pkn = pk0;
        s16x8 An = Areg;
        if (t + 1 < e) {
            pkn = __builtin_amdgcn_readfirstlane(bcol[t + 1]);
            An = *reinterpret_cast<const s16x8*>(
                ABbf + ((size_t)(pkn & 0x7fff) * NB + rowb + br) * 256 + bc * 8);
        }
        {
            union { s16x8 s; unsigned int w[4]; } av, bv2, pkv;
            av.s = Areg;
            bv2.s = cls ? Bp[1] : Bp[0];
#pragma unroll
            for (int q = 0; q < 4; ++q) {
                float a0 = __uint_as_float(av.w[q] << 16);
                float a1 = __uint_as_float(av.w[q] & 0xffff0000u);
                float b0 = __uint_as_float(bv2.w[q] << 16);
                float b1 = __uint_as_float(bv2.w[q] & 0xffff0000u);
                pkv.w[q] = cvt_pk_bf16(silu_f(a0 + b0), silu_f(a1 + b1));
            }
            *reinterpret_cast<s16x8*>(
                &m1[t & 1][br * 128 + ((bc ^ (br & 7)) << 3)]) = pkv.s;
        }
        __syncthreads();
        f32x4 acc[2];
#pragma unroll
        for (int ni = 0; ni < 2; ++ni) {
            f32x4 iv = { e2[ni], e2[ni], e2[ni], e2[ni] };
            acc[ni] = iv;
        }
#pragma unroll
        for (int ks = 0; ks < 4; ++ks) {
            int cc = ks * 4 + lg;
            s16x8 af = *reinterpret_cast<s16x8*>(
                &m1[t & 1][lr * 128 + ((cc ^ (lr & 7)) << 3)]);
            acc[0] = __builtin_amdgcn_mfma_f32_16x16x32_bf16(af, wfr[ks][0], acc[0], 0, 0, 0);
            acc[1] = __builtin_amdgcn_mfma_f32_16x16x32_bf16(af, wfr[ks][1], acc[1], 0, 0, 0);
        }
#pragma unroll
        for (int ni = 0; ni < 2; ++ni)
#pragma unroll
            for (int r4 = 0; r4 < 4; ++r4)
                agg[ni][r4] += silu_f(acc[ni][r4]) - se[ni];
        pk0 = pkn;
        Areg = An;
    }

    float inv = (e > s) ? 1.f / (float)(e - s) : 0.f;
#pragma unroll
    for (int ni = 0; ni < 2; ++ni) {
#pragma unroll
        for (int r4 = 0; r4 < 4; ++r4) {
            size_t rowg = (size_t)i * NB + rowb + lg * 4 + r4;
            magbf[rowg * 128 + col0 + ni * 16 + lr] =
                f2bf(agg[ni][r4] * inv + se[ni]);
        }
    }
}

extern "C" void kernel_launch(void* const* d_in, const int* in_sizes, int n_in,
                              void* d_out, int out_size, void* d_ws, size_t ws_size,
                              hipStream_t stream) {
    const float* y     = (const float*)d_in[0];
    const float* gc    = (const float*)d_in[1];
    const int*   eidx  = (const int*)d_in[2];
    const float* W_in  = (const float*)d_in[3];
    const float* b_in  = (const float*)d_in[4];
    const float* gam   = (const float*)d_in[5];
    const float* bet   = (const float*)d_in[6];
    const float* eW1   = (const float*)d_in[7];
    const float* eb1   = (const float*)d_in[8];
    const float* eW2   = (const float*)d_in[9];
    const float* eb2   = (const float*)d_in[10];
    const float* nW1   = (const float*)d_in[11];
    const float* nb1   = (const float*)d_in[12];
    const float* nW2   = (const float*)d_in[13];
    const float* nb2   = (const float*)d_in[14];
    const float* W_out = (const float*)d_in[15];
    const float* b_out = (const float*)d_in[16];

    const int M = in_sizes[0] / CODE;       // 32768 (= NBASE * NB)
    const int E = in_sizes[2] / 2;
    const int baseE = E / NB;

    float* out = (float*)d_out;

    char* ws = (char*)d_ws;
    size_t off = 0;
    auto carve = [&](size_t bytes) {
        char* p = ws + off;
        off += (bytes + 255) & ~(size_t)255;
        return p;
    };
    float*          buf_hn  = (float*)carve((size_t)M * HIDDEN * 4);
    unsigned short* hnbf    = (unsigned short*)carve((size_t)M * HIDDEN * 2);
    unsigned short* ABbf    = (unsigned short*)carve((size_t)M * 256 * 2);
    unsigned short* magbf   = (unsigned short*)carve((size_t)M * HIDDEN * 2);
    unsigned short* hbf     = (unsigned short*)carve((size_t)M * HIDDEN * 2);
    int*            brp     = (int*)carve((size_t)(NBASE + 1) * 4);
    int*            bcol    = (int*)carve((size_t)baseE * 4);
    unsigned short* winbf   = (unsigned short*)carve((size_t)HIDDEN * CODE * 2);
    unsigned short* woutbf  = (unsigned short*)carve((size_t)CODE * HIDDEN * 2);
    unsigned short* wn1bf   = (unsigned short*)carve((size_t)NLAYERS * HIDDEN * 256 * 2);
    unsigned short* wn2bf   = (unsigned short*)carve((size_t)NLAYERS * HIDDEN * HIDDEN * 2);
    unsigned short* w2bf    = (unsigned short*)carve((size_t)NLAYERS * HIDDEN * HIDDEN * 2);
    unsigned short* w1ab    = (unsigned short*)carve((size_t)NLAYERS * 256 * HIDDEN * 2);
    float*          bias256 = (float*)carve((size_t)NLAYERS * 256 * 4);
    float*          c01     = (float*)carve((size_t)NLAYERS * 256 * 4);

    const int* row  = eidx;
    const int* colA = eidx + E;

    int prep_blocks = 519 + (baseE + 255) / 256;
    prep_all<<<dim3(prep_blocks), 256, 0, stream>>>(
        W_in, W_out, nW1, nW2, eW2, eW1, eb1, row, colA, gc,
        winbf, woutbf, wn1bf, wn2bf, w2bf, w1ab, bias256, c01,
        brp, bcol, baseE);

    // h0 = y @ W_in^T + b_in ; hn0 = LN0(h0) (base-major out)
    inproj_ln<<<dim3(M / 64), 256, 0, stream>>>(
        y, winbf, b_in, gam, bet, buf_hn, hnbf);

    // layer 0's [A|B] (barrier-free row GEMM, 2 col-blocks)
    rggemm<<<dim3(M / 64, 2), 256, 0, stream>>>(
        hnbf, HIDDEN, w1ab, bias256, nullptr, ABbf, 256, 0);

    for (int l = 0; l < NLAYERS; ++l) {
        edge_mfma7<<<dim3(NBASE * 4), 256, 0, stream>>>(
            ABbf, bcol, brp,
            w2bf + (size_t)l * HIDDEN * HIDDEN, c01 + (size_t)l * 256,
            eb2 + (size_t)l * HIDDEN, magbf);

        bool last = (l == NLAYERS - 1);
        nmlp2<<<dim3(M / 64), 256, 0, stream>>>(
            hnbf, magbf,
            wn1bf + (size_t)l * HIDDEN * 256, nb1 + (size_t)l * HIDDEN,
            wn2bf + (size_t)l * HIDDEN * HIDDEN, nb2 + (size_t)l * HIDDEN,
            buf_hn,
            last ? nullptr : gam + (size_t)(l + 1) * HIDDEN,
            last ? nullptr : bet + (size_t)(l + 1) * HIDDEN,
            buf_hn, hnbf, hbf,
            last ? nullptr : w1ab + (size_t)(l + 1) * 256 * HIDDEN,
            last ? nullptr : eb1 + (size_t)(l + 1) * HIDDEN,
            last ? nullptr : ABbf);
    }

    // out = h @ W_out^T + b_out (rows permuted base-major -> b-major)
    rggemm<<<dim3(M / 64, CODE / 128), 256, 0, stream>>>(
        hbf, HIDDEN, woutbf, b_out, out, nullptr, CODE, 2);
}

// Round 13
// 455.280 us; speedup vs baseline: 1.2198x; 1.2198x over previous
//
#include <hip/hip_runtime.h>
#include <math.h>

// GNN denoiser: N=32768 (=512 base x 64 batch), HID=128, L=4.
// Base-major node layout. Edge MLP v7 (cooperative build, W2 in regs).
// GEMMs: LDS-staged bf16 MFMA (r11 structure). Out-proj gathers A rows
// (base-major->b-major) so OUTPUT WRITES ARE CONTIGUOUS (perm=3).
// LN fused into in-proj / node-MLP epilogues; node-MLP emits next [A|B].

#define HIDDEN 128
#define NLAYERS 4
#define NBASE 512
#define NB 64
#define CODE 1024

typedef __attribute__((ext_vector_type(8))) short s16x8;
typedef __attribute__((ext_vector_type(4))) float f32x4;

__device__ __forceinline__ unsigned int cvt_pk_bf16(float lo, float hi) {
    unsigned int d;
    asm("v_cvt_pk_bf16_f32 %0, %1, %2" : "=v"(d) : "v"(lo), "v"(hi));
    return d;
}
__device__ __forceinline__ unsigned short f2bf(float x) {
    return (unsigned short)cvt_pk_bf16(x, x);
}
__device__ __forceinline__ float silu_f(float x) {
    float e = __expf(-x);
    float r;
    asm("v_rcp_f32 %0, %1" : "=v"(r) : "v"(1.f + e));
    return x * r;
}

// ---------------- fused prep: all weight conversion + graph prep ----------
__device__ __forceinline__ void conv_body(
    const float* __restrict__ s, unsigned short* __restrict__ d,
    int blk, int tid, int n) {
    int i = (blk * 256 + tid) * 4;
    if (i >= n) return;
    float4 v = *reinterpret_cast<const float4*>(s + i);
    uint2 o = { cvt_pk_bf16(v.x, v.y), cvt_pk_bf16(v.z, v.w) };
    *reinterpret_cast<uint2*>(d + i) = o;
}

__global__ __launch_bounds__(256) void prep_all(
    const float* __restrict__ W_in, const float* __restrict__ W_out,
    const float* __restrict__ nW1, const float* __restrict__ nW2,
    const float* __restrict__ eW2, const float* __restrict__ eW1,
    const float* __restrict__ eb1,
    const int* __restrict__ row, const int* __restrict__ col,
    const float* __restrict__ gc,
    unsigned short* __restrict__ winbf, unsigned short* __restrict__ woutbf,
    unsigned short* __restrict__ wn1bf, unsigned short* __restrict__ wn2bf,
    unsigned short* __restrict__ w2bf, unsigned short* __restrict__ w1ab,
    float* __restrict__ bias256, float* __restrict__ c01,
    int* __restrict__ brp, int* __restrict__ bcol, int baseE) {
    int blk = blockIdx.x, tid = threadIdx.x;
    if (blk < 128)      { conv_body(W_in,  winbf,  blk,       tid, HIDDEN * CODE); return; }
    if (blk < 256)      { conv_body(W_out, woutbf, blk - 128, tid, CODE * HIDDEN); return; }
    if (blk < 384)      { conv_body(nW1,   wn1bf,  blk - 256, tid, NLAYERS * HIDDEN * 256); return; }
    if (blk < 448)      { conv_body(nW2,   wn2bf,  blk - 384, tid, NLAYERS * HIDDEN * HIDDEN); return; }
    if (blk < 512)      { conv_body(eW2,   w2bf,   blk - 448, tid, NLAYERS * HIDDEN * HIDDEN); return; }
    if (blk < 516) {    // per-layer pack
        int l = blk - 512;
        const float* w = eW1 + (size_t)l * HIDDEN * 257;
        for (int i = tid; i < 256 * 128; i += 256) {
            int n = i >> 7, k = i & 127;
            float v = (n < 128) ? w[(size_t)n * 257 + k]
                                : w[(size_t)(n - 128) * 257 + 128 + k];
            w1ab[(size_t)l * 256 * 128 + i] = f2bf(v);
        }
        if (tid < 256)
            bias256[(size_t)l * 256 + tid] =
                (tid < 128) ? 0.f : eb1[(size_t)l * HIDDEN + tid - 128];
        if (tid < 128) {
            float wd = w[(size_t)tid * 257 + 256];
            c01[(size_t)l * 256 + tid] = 2.f * wd;
            c01[(size_t)l * 256 + 128 + tid] = sqrtf(8.f) * wd;
        }
        return;
    }
    if (blk < 519) {    // rowptr over base graph
        int v = (blk - 516) * 256 + tid;
        if (v > NBASE) return;
        int lo = 0, hi = baseE;
        while (lo < hi) {
            int mid = (lo + hi) >> 1;
            if (row[mid] < v) lo = mid + 1; else hi = mid;
        }
        brp[v] = lo;
        return;
    }
    {   // basecol: packed cls<<15 | j
        int t = (blk - 519) * 256 + tid;
        if (t >= baseE) return;
        int u = col[t], v = row[t];
        float dx = gc[(size_t)u * 3 + 0] - gc[(size_t)v * 3 + 0];
        float dy = gc[(size_t)u * 3 + 1] - gc[(size_t)v * 3 + 1];
        float dz = gc[(size_t)u * 3 + 2] - gc[(size_t)v * 3 + 2];
        float d2 = dx * dx + dy * dy + dz * dz;
        bcol[t] = u | ((d2 > 6.f ? 1 : 0) << 15);
    }
}

// ---------------- generic bf16 MFMA GEMM, BM=64 ----------------
// perm 0: direct rows. perm 3: block owns contiguous OUTPUT rows (b-major);
// A rows gathered via base-major mapping; writes contiguous.
__global__ __launch_bounds__(256) void mgemm64(
    const unsigned short* __restrict__ A, int K,
    const unsigned short* __restrict__ W,
    const float* __restrict__ bias,
    float* __restrict__ Cf, unsigned short* __restrict__ Cb, int ldC, int perm) {
    __shared__ __align__(16) unsigned short As[64 * 128];
    __shared__ __align__(16) unsigned short Ws[128 * 128];
    int tid = threadIdx.x;
    int wid = tid >> 6, l = tid & 63, lr = l & 15, lg = l >> 4;
    int wm = wid >> 1, wn = wid & 1;
    int row0 = blockIdx.x * 64;
    int cb = blockIdx.y * 128;
    f32x4 acc[2][4];
#pragma unroll
    for (int i = 0; i < 2; ++i)
#pragma unroll
        for (int j = 0; j < 4; ++j) {
            f32x4 z = { 0.f, 0.f, 0.f, 0.f };
            acc[i][j] = z;
        }
    for (int kc = 0; kc < K; kc += 128) {
#pragma unroll
        for (int jj = 0; jj < 4; ++jj) {
            int j = tid + jj * 256;
            int r = j >> 4, c = j & 15;
            int srow = row0 + r;
            if (perm == 3) srow = ((srow & 511) << 6) | (srow >> 9);
            s16x8 v = *reinterpret_cast<const s16x8*>(
                A + (size_t)srow * K + kc + c * 8);
            *reinterpret_cast<s16x8*>(&As[r * 128 + ((c ^ (r & 7)) << 3)]) = v;
        }
#pragma unroll
        for (int jj = 0; jj < 8; ++jj) {
            int j = tid + jj * 256;
            int r = j >> 4, c = j & 15;
            s16x8 wv = *reinterpret_cast<const s16x8*>(
                W + (size_t)(cb + r) * K + kc + c * 8);
            *reinterpret_cast<s16x8*>(&Ws[r * 128 + ((c ^ (r & 7)) << 3)]) = wv;
        }
        __syncthreads();
#pragma unroll
        for (int ks = 0; ks < 4; ++ks) {
            int c = ks * 4 + lg;
            s16x8 af[2], bf[4];
#pragma unroll
            for (int mi = 0; mi < 2; ++mi) {
                int r = wm * 32 + mi * 16 + lr;
                af[mi] = *reinterpret_cast<s16x8*>(&As[r * 128 + ((c ^ (r & 7)) << 3)]);
            }
#pragma unroll
            for (int ni = 0; ni < 4; ++ni) {
                int n = wn * 64 + ni * 16 + lr;
                bf[ni] = *reinterpret_cast<s16x8*>(&Ws[n * 128 + ((c ^ (n & 7)) << 3)]);
            }
#pragma unroll
            for (int mi = 0; mi < 2; ++mi)
#pragma unroll
                for (int ni = 0; ni < 4; ++ni)
                    acc[mi][ni] = __builtin_amdgcn_mfma_f32_16x16x32_bf16(
                        af[mi], bf[ni], acc[mi][ni], 0, 0, 0);
        }
        __syncthreads();
    }
#pragma unroll
    for (int mi = 0; mi < 2; ++mi) {
#pragma unroll
        for (int ni = 0; ni < 4; ++ni) {
            int colg = cb + wn * 64 + ni * 16 + lr;
            float bs = bias ? bias[colg] : 0.f;
#pragma unroll
            for (int r4 = 0; r4 < 4; ++r4) {
                int rowg = row0 + wm * 32 + mi * 16 + lg * 4 + r4;
                float v = acc[mi][ni][r4] + bs;
                if (Cf) Cf[(size_t)rowg * ldC + colg] = v;
                if (Cb) Cb[(size_t)rowg * ldC + colg] = f2bf(v);
            }
        }
    }
}

// ---------------- in-projection + fused LN0, pipelined K-loop ------------
__global__ __launch_bounds__(256) void inproj_ln(
    const float* __restrict__ y,
    const unsigned short* __restrict__ W, const float* __restrict__ bias,
    const float* __restrict__ g, const float* __restrict__ bet,
    float* __restrict__ hn, unsigned short* __restrict__ hnbf) {
    __shared__ __align__(16) unsigned short As[64 * 128];
    __shared__ __align__(16) unsigned short Ws[128 * 128];
    int tid = threadIdx.x;
    int wid = tid >> 6, l = tid & 63, lr = l & 15, lg = l >> 4;
    int row0 = blockIdx.x * 64;
    f32x4 acc[8];
#pragma unroll
    for (int ni = 0; ni < 8; ++ni) {
        f32x4 z = { 0.f, 0.f, 0.f, 0.f };
        acc[ni] = z;
    }
    float4 pa0[4], pa1[4];
    s16x8 pw[8];
    auto loadc = [&](int kc) {
#pragma unroll
        for (int jj = 0; jj < 4; ++jj) {
            int j = tid + jj * 256, r = j >> 4, c = j & 15;
            const float* p = y + (size_t)(row0 + r) * CODE + kc + c * 8;
            pa0[jj] = *reinterpret_cast<const float4*>(p);
            pa1[jj] = *reinterpret_cast<const float4*>(p + 4);
        }
#pragma unroll
        for (int jj = 0; jj < 8; ++jj) {
            int j = tid + jj * 256, r = j >> 4, c = j & 15;
            pw[jj] = *reinterpret_cast<const s16x8*>(W + (size_t)r * CODE + kc + c * 8);
        }
    };
    auto storec = [&]() {
#pragma unroll
        for (int jj = 0; jj < 4; ++jj) {
            int j = tid + jj * 256, r = j >> 4, c = j & 15;
            union { s16x8 s; unsigned int w[4]; } pk;
            pk.w[0] = cvt_pk_bf16(pa0[jj].x, pa0[jj].y);
            pk.w[1] = cvt_pk_bf16(pa0[jj].z, pa0[jj].w);
            pk.w[2] = cvt_pk_bf16(pa1[jj].x, pa1[jj].y);
            pk.w[3] = cvt_pk_bf16(pa1[jj].z, pa1[jj].w);
            *reinterpret_cast<s16x8*>(&As[r * 128 + ((c ^ (r & 7)) << 3)]) = pk.s;
        }
#pragma unroll
        for (int jj = 0; jj < 8; ++jj) {
            int j = tid + jj * 256, r = j >> 4, c = j & 15;
            *reinterpret_cast<s16x8*>(&Ws[r * 128 + ((c ^ (r & 7)) << 3)]) = pw[jj];
        }
    };
    loadc(0);
    for (int kc8 = 0; kc8 < 8; ++kc8) {
        storec();
        __syncthreads();
        if (kc8 < 7) loadc((kc8 + 1) * 128);   // prefetch next chunk to regs
#pragma unroll
        for (int ks = 0; ks < 4; ++ks) {
            int c = ks * 4 + lg;
            int r = wid * 16 + lr;
            s16x8 af = *reinterpret_cast<s16x8*>(&As[r * 128 + ((c ^ (r & 7)) << 3)]);
#pragma unroll
            for (int ni = 0; ni < 8; ++ni) {
                int n = ni * 16 + lr;
                s16x8 bf = *reinterpret_cast<s16x8*>(&Ws[n * 128 + ((c ^ (n & 7)) << 3)]);
                acc[ni] = __builtin_amdgcn_mfma_f32_16x16x32_bf16(af, bf, acc[ni], 0, 0, 0);
            }
        }
        __syncthreads();
    }
#pragma unroll
    for (int ni = 0; ni < 8; ++ni) {
        float bs = bias[ni * 16 + lr];
#pragma unroll
        for (int r4 = 0; r4 < 4; ++r4) acc[ni][r4] += bs;
    }
    float s[4], q[4];
#pragma unroll
    for (int r4 = 0; r4 < 4; ++r4) {
        float ss = 0.f, qq = 0.f;
#pragma unroll
        for (int ni = 0; ni < 8; ++ni) {
            float v = acc[ni][r4];
            ss += v; qq += v * v;
        }
#pragma unroll
        for (int o = 1; o < 16; o <<= 1) {
            ss += __shfl_xor(ss, o, 64);
            qq += __shfl_xor(qq, o, 64);
        }
        float mu = ss * (1.f / 128.f);
        float var = qq * (1.f / 128.f) - mu * mu;
        s[r4] = mu;
        q[r4] = rsqrtf(var + 1e-5f);
    }
#pragma unroll
    for (int ni = 0; ni < 8; ++ni) {
        int col = ni * 16 + lr;
        float gg = g[col], bb = bet[col];
#pragma unroll
        for (int r4 = 0; r4 < 4; ++r4) {
            int rowg = row0 + wid * 16 + lg * 4 + r4;
            int orow = (rowg & 511) * 64 + (rowg >> 9);
            float o = (acc[ni][r4] - s[r4]) * q[r4] * gg + bb;
            hn[(size_t)orow * HIDDEN + col] = o;
            hnbf[(size_t)orow * HIDDEN + col] = f2bf(o);
        }
    }
}

// ---------------- fused node MLP + next LN + next-layer [A|B] ------------
__global__ __launch_bounds__(256) void nmlp_ln(
    const unsigned short* __restrict__ hnbf,
    const unsigned short* __restrict__ magbf,
    const unsigned short* __restrict__ w1, const float* __restrict__ b1,
    const unsigned short* __restrict__ w2, const float* __restrict__ b2,
    const float* __restrict__ resid,
    const float* __restrict__ g, const float* __restrict__ bet,
    float* __restrict__ hn_out, unsigned short* __restrict__ hnbf_out,
    unsigned short* __restrict__ hbf_out,
    const unsigned short* __restrict__ w1ab_next,
    const float* __restrict__ eb1_next,
    unsigned short* __restrict__ ab_out) {
    __shared__ __align__(16) unsigned short As[64 * 128];
    __shared__ __align__(16) unsigned short Ws[128 * 128];
    int tid = threadIdx.x;
    int wid = tid >> 6, l = tid & 63, lr = l & 15, lg = l >> 4;
    int row0 = blockIdx.x * 64;
    f32x4 acc[8];
#pragma unroll
    for (int ni = 0; ni < 8; ++ni) {
        f32x4 z = { 0.f, 0.f, 0.f, 0.f };
        acc[ni] = z;
    }
    // stage 1: K=256 over [hn | mag]
    for (int kc = 0; kc < 2; ++kc) {
        const unsigned short* Xsrc = kc ? magbf : hnbf;
#pragma unroll
        for (int jj = 0; jj < 4; ++jj) {
            int j = tid + jj * 256;
            int r = j >> 4, c = j & 15;
            s16x8 v = *reinterpret_cast<const s16x8*>(
                Xsrc + (size_t)(row0 + r) * 128 + c * 8);
            *reinterpret_cast<s16x8*>(&As[r * 128 + ((c ^ (r & 7)) << 3)]) = v;
        }
#pragma unroll
        for (int jj = 0; jj < 8; ++jj) {
            int j = tid + jj * 256;
            int r = j >> 4, c = j & 15;
            s16x8 wv = *reinterpret_cast<const s16x8*>(
                w1 + (size_t)r * 256 + kc * 128 + c * 8);
            *reinterpret_cast<s16x8*>(&Ws[r * 128 + ((c ^ (r & 7)) << 3)]) = wv;
        }
        __syncthreads();
#pragma unroll
        for (int ks = 0; ks < 4; ++ks) {
            int c = ks * 4 + lg;
            int r = wid * 16 + lr;
            s16x8 af = *reinterpret_cast<s16x8*>(&As[r * 128 + ((c ^ (r & 7)) << 3)]);
#pragma unroll
            for (int ni = 0; ni < 8; ++ni) {
                int n = ni * 16 + lr;
                s16x8 bf = *reinterpret_cast<s16x8*>(&Ws[n * 128 + ((c ^ (n & 7)) << 3)]);
                acc[ni] = __builtin_amdgcn_mfma_f32_16x16x32_bf16(af, bf, acc[ni], 0, 0, 0);
            }
        }
        __syncthreads();
    }
    // t = silu(acc + b1) -> As (own rows, swizzled)
#pragma unroll
    for (int ni = 0; ni < 8; ++ni) {
        int col = ni * 16 + lr;
        float bs = b1[col];
        int cc = col >> 3, cin = col & 7;
#pragma unroll
        for (int r4 = 0; r4 < 4; ++r4) {
            int rl = wid * 16 + lg * 4 + r4;
            As[rl * 128 + ((cc ^ (rl & 7)) << 3) + cin] =
                f2bf(silu_f(acc[ni][r4] + bs));
            acc[ni][r4] = 0.f;
        }
    }
#pragma unroll
    for (int jj = 0; jj < 8; ++jj) {
        int j = tid + jj * 256;
        int r = j >> 4, c = j & 15;
        s16x8 wv = *reinterpret_cast<const s16x8*>(w2 + (size_t)r * 128 + c * 8);
        *reinterpret_cast<s16x8*>(&Ws[r * 128 + ((c ^ (r & 7)) << 3)]) = wv;
    }
    __syncthreads();
    // stage 2: t @ W2^T
#pragma unroll
    for (int ks = 0; ks < 4; ++ks) {
        int c = ks * 4 + lg;
        int r = wid * 16 + lr;
        s16x8 af = *reinterpret_cast<s16x8*>(&As[r * 128 + ((c ^ (r & 7)) << 3)]);
#pragma unroll
        for (int ni = 0; ni < 8; ++ni) {
            int n = ni * 16 + lr;
            s16x8 bf = *reinterpret_cast<s16x8*>(&Ws[n * 128 + ((c ^ (n & 7)) << 3)]);
            acc[ni] = __builtin_amdgcn_mfma_f32_16x16x32_bf16(af, bf, acc[ni], 0, 0, 0);
        }
    }
    // h = acc + b2 + resid
#pragma unroll
    for (int ni = 0; ni < 8; ++ni) {
        int col = ni * 16 + lr;
        float bs = b2[col];
#pragma unroll
        for (int r4 = 0; r4 < 4; ++r4) {
            int rowg = row0 + wid * 16 + lg * 4 + r4;
            acc[ni][r4] += bs + resid[(size_t)rowg * HIDDEN + col];
        }
    }
    if (!g) {   // last layer: h as bf16 for out-proj; no LN, no AB
#pragma unroll
        for (int ni = 0; ni < 8; ++ni) {
            int col = ni * 16 + lr;
#pragma unroll
            for (int r4 = 0; r4 < 4; ++r4) {
                int rowg = row0 + wid * 16 + lg * 4 + r4;
                hbf_out[(size_t)rowg * HIDDEN + col] = f2bf(acc[ni][r4]);
            }
        }
        return;
    }
    // LN (acc <- hn')
    float s[4], q[4];
#pragma unroll
    for (int r4 = 0; r4 < 4; ++r4) {
        float ss = 0.f, qq = 0.f;
#pragma unroll
        for (int ni = 0; ni < 8; ++ni) {
            float v = acc[ni][r4];
            ss += v; qq += v * v;
        }
#pragma unroll
        for (int o = 1; o < 16; o <<= 1) {
            ss += __shfl_xor(ss, o, 64);
            qq += __shfl_xor(qq, o, 64);
        }
        float mu = ss * (1.f / 128.f);
        float var = qq * (1.f / 128.f) - mu * mu;
        s[r4] = mu;
        q[r4] = rsqrtf(var + 1e-5f);
    }
#pragma unroll
    for (int ni = 0; ni < 8; ++ni) {
        int col = ni * 16 + lr;
        float gg = g[col], bb = bet[col];
#pragma unroll
        for (int r4 = 0; r4 < 4; ++r4) {
            int rowg = row0 + wid * 16 + lg * 4 + r4;
            float o = (acc[ni][r4] - s[r4]) * q[r4] * gg + bb;
            hn_out[(size_t)rowg * HIDDEN + col] = o;
            hnbf_out[(size_t)rowg * HIDDEN + col] = f2bf(o);
            acc[ni][r4] = o;
        }
    }
    // ---- next layer [A|B]: hn' -> As (own rows), two W halves ----
#pragma unroll
    for (int ni = 0; ni < 8; ++ni) {
        int col = ni * 16 + lr;
        int cc = col >> 3, cin = col & 7;
#pragma unroll
        for (int r4 = 0; r4 < 4; ++r4) {
            int rl = wid * 16 + lg * 4 + r4;
            As[rl * 128 + ((cc ^ (rl & 7)) << 3) + cin] = f2bf(acc[ni][r4]);
        }
    }
    __syncthreads();    // all waves done reading Ws (stage 2)
#pragma unroll
    for (int half = 0; half < 2; ++half) {
#pragma unroll
        for (int jj = 0; jj < 8; ++jj) {
            int j = tid + jj * 256;
            int r = j >> 4, c = j & 15;
            s16x8 wv = *reinterpret_cast<const s16x8*>(
                w1ab_next + (size_t)(half * 128 + r) * 128 + c * 8);
            *reinterpret_cast<s16x8*>(&Ws[r * 128 + ((c ^ (r & 7)) << 3)]) = wv;
        }
        __syncthreads();
#pragma unroll
        for (int ni = 0; ni < 8; ++ni) {
            f32x4 z = { 0.f, 0.f, 0.f, 0.f };
            acc[ni] = z;
        }
#pragma unroll
        for (int ks = 0; ks < 4; ++ks) {
            int c = ks * 4 + lg;
            int r = wid * 16 + lr;
            s16x8 af = *reinterpret_cast<s16x8*>(&As[r * 128 + ((c ^ (r & 7)) << 3)]);
#pragma unroll
            for (int ni = 0; ni < 8; ++ni) {
                int n = ni * 16 + lr;
                s16x8 bf = *reinterpret_cast<s16x8*>(&Ws[n * 128 + ((c ^ (n & 7)) << 3)]);
                acc[ni] = __builtin_amdgcn_mfma_f32_16x16x32_bf16(af, bf, acc[ni], 0, 0, 0);
            }
        }
#pragma unroll
        for (int ni = 0; ni < 8; ++ni) {
            int col = ni * 16 + lr;
            float bs = half ? eb1_next[col] : 0.f;
#pragma unroll
            for (int r4 = 0; r4 < 4; ++r4) {
                int rowg = row0 + wid * 16 + lg * 4 + r4;
                ab_out[(size_t)rowg * 256 + half * 128 + col] =
                    f2bf(acc[ni][r4] + bs);
            }
        }
        if (half == 0) __syncthreads();   // before Ws overwrite
    }
}

// ---------------- edge MLP v7: cooperative build, W2 in registers ---------
__global__ __launch_bounds__(256, 4) void edge_mfma7(
    const unsigned short* __restrict__ ABbf,
    const int* __restrict__ bcol,
    const int* __restrict__ brp,
    const unsigned short* __restrict__ w2bf,
    const float* __restrict__ c01,
    const float* __restrict__ eb2l,
    unsigned short* __restrict__ magbf) {
    __shared__ __align__(16) unsigned short m1[2][16 * 128];
    int tid = threadIdx.x;
    int blk = blockIdx.x;
    int i = blk >> 2, qtr = blk & 3;
    int wid = tid >> 6, l = tid & 63, lr = l & 15, lg = l >> 4;
    int rowb = qtr * 16;
    int col0 = wid * 32;

    s16x8 wfr[4][2];
#pragma unroll
    for (int ks = 0; ks < 4; ++ks)
#pragma unroll
        for (int ni = 0; ni < 2; ++ni) {
            int n = col0 + ni * 16 + lr;
            wfr[ks][ni] = *reinterpret_cast<const s16x8*>(
                w2bf + (size_t)n * 128 + (ks * 4 + lg) * 8);
        }

    int s = brp[i], e = brp[i + 1];

    int br = tid >> 4, bc = tid & 15;
    s16x8 Bp[2];
    {
        union { s16x8 s; unsigned int w[4]; } bv;
        bv.s = *reinterpret_cast<const s16x8*>(
            ABbf + ((size_t)i * NB + rowb + br) * 256 + 128 + bc * 8);
#pragma unroll
        for (int cls = 0; cls < 2; ++cls) {
            const float* cp = c01 + cls * 128 + bc * 8;
            float4 ca = *reinterpret_cast<const float4*>(cp);
            float4 cb = *reinterpret_cast<const float4*>(cp + 4);
            union { s16x8 s; unsigned int w[4]; } pk;
            pk.w[0] = cvt_pk_bf16(__uint_as_float(bv.w[0] << 16) + ca.x,
                                  __uint_as_float(bv.w[0] & 0xffff0000u) + ca.y);
            pk.w[1] = cvt_pk_bf16(__uint_as_float(bv.w[1] << 16) + ca.z,
                                  __uint_as_float(bv.w[1] & 0xffff0000u) + ca.w);
            pk.w[2] = cvt_pk_bf16(__uint_as_float(bv.w[2] << 16) + cb.x,
                                  __uint_as_float(bv.w[2] & 0xffff0000u) + cb.y);
            pk.w[3] = cvt_pk_bf16(__uint_as_float(bv.w[3] << 16) + cb.z,
                                  __uint_as_float(bv.w[3] & 0xffff0000u) + cb.w);
            Bp[cls] = pk.s;
        }
    }
    float e2[2], se[2];
#pragma unroll
    for (int ni = 0; ni < 2; ++ni) {
        e2[ni] = eb2l[col0 + ni * 16 + lr];
        se[ni] = silu_f(e2[ni]);
    }
    f32x4 agg[2];
#pragma unroll
    for (int ni = 0; ni < 2; ++ni) {
        f32x4 z = { 0.f, 0.f, 0.f, 0.f };
        agg[ni] = z;
    }

    int pk0 = __builtin_amdgcn_readfirstlane(bcol[s]);
    s16x8 Areg = *reinterpret_cast<const s16x8*>(
        ABbf + ((size_t)(pk0 & 0x7fff) * NB + rowb + br) * 256 + bc * 8);

    for (int t = s; t < e; ++t) {
        int cls = (pk0 >> 15) & 1;
        int pkn = pk0;
        s16x8 An = Areg;
        if (t + 1 < e) {
            pkn = __builtin_amdgcn_readfirstlane(bcol[t + 1]);
            An = *reinterpret_cast<const s16x8*>(
                ABbf + ((size_t)(pkn & 0x7fff) * NB + rowb + br) * 256 + bc * 8);
        }
        {
            union { s16x8 s; unsigned int w[4]; } av, bv2, pkv;
            av.s = Areg;
            bv2.s = cls ? Bp[1] : Bp[0];
#pragma unroll
            for (int q = 0; q < 4; ++q) {
                float a0 = __uint_as_float(av.w[q] << 16);
                float a1 = __uint_as_float(av.w[q] & 0xffff0000u);
                float b0 = __uint_as_float(bv2.w[q] << 16);
                float b1 = __uint_as_float(bv2.w[q] & 0xffff0000u);
                pkv.w[q] = cvt_pk_bf16(silu_f(a0 + b0), silu_f(a1 + b1));
            }
            *reinterpret_cast<s16x8*>(
                &m1[t & 1][br * 128 + ((bc ^ (br & 7)) << 3)]) = pkv.s;
        }
        __syncthreads();
        f32x4 acc[2];
#pragma unroll
        for (int ni = 0; ni < 2; ++ni) {
            f32x4 iv = { e2[ni], e2[ni], e2[ni], e2[ni] };
            acc[ni] = iv;
        }
#pragma unroll
        for (int ks = 0; ks < 4; ++ks) {
            int cc = ks * 4 + lg;
            s16x8 af = *reinterpret_cast<s16x8*>(
                &m1[t & 1][lr * 128 + ((cc ^ (lr & 7)) << 3)]);
            acc[0] = __builtin_amdgcn_mfma_f32_16x16x32_bf16(af, wfr[ks][0], acc[0], 0, 0, 0);
            acc[1] = __builtin_amdgcn_mfma_f32_16x16x32_bf16(af, wfr[ks][1], acc[1], 0, 0, 0);
        }
#pragma unroll
        for (int ni = 0; ni < 2; ++ni)
#pragma unroll
            for (int r4 = 0; r4 < 4; ++r4)
                agg[ni][r4] += silu_f(acc[ni][r4]) - se[ni];
        pk0 = pkn;
        Areg = An;
    }

    float inv = (e > s) ? 1.f / (float)(e - s) : 0.f;
#pragma unroll
    for (int ni = 0; ni < 2; ++ni) {
#pragma unroll
        for (int r4 = 0; r4 < 4; ++r4) {
            size_t rowg = (size_t)i * NB + rowb + lg * 4 + r4;
            magbf[rowg * 128 + col0 + ni * 16 + lr] =
                f2bf(agg[ni][r4] * inv + se[ni]);
        }
    }
}

extern "C" void kernel_launch(void* const* d_in, const int* in_sizes, int n_in,
                              void* d_out, int out_size, void* d_ws, size_t ws_size,
                              hipStream_t stream) {
    const float* y     = (const float*)d_in[0];
    const float* gc    = (const float*)d_in[1];
    const int*   eidx  = (const int*)d_in[2];
    const float* W_in  = (const float*)d_in[3];
    const float* b_in  = (const float*)d_in[4];
    const float* gam   = (const float*)d_in[5];
    const float* bet   = (const float*)d_in[6];
    const float* eW1   = (const float*)d_in[7];
    const float* eb1   = (const float*)d_in[8];
    const float* eW2   = (const float*)d_in[9];
    const float* eb2   = (const float*)d_in[10];
    const float* nW1   = (const float*)d_in[11];
    const float* nb1   = (const float*)d_in[12];
    const float* nW2   = (const float*)d_in[13];
    const float* nb2   = (const float*)d_in[14];
    const float* W_out = (const float*)d_in[15];
    const float* b_out = (const float*)d_in[16];

    const int M = in_sizes[0] / CODE;       // 32768 (= NBASE * NB)
    const int E = in_sizes[2] / 2;
    const int baseE = E / NB;

    float* out = (float*)d_out;

    char* ws = (char*)d_ws;
    size_t off = 0;
    auto carve = [&](size_t bytes) {
        char* p = ws + off;
        off += (bytes + 255) & ~(size_t)255;
        return p;
    };
    float*          buf_hn  = (float*)carve((size_t)M * HIDDEN * 4);
    unsigned short* hnbf    = (unsigned short*)carve((size_t)M * HIDDEN * 2);
    unsigned short* ABbf    = (unsigned short*)carve((size_t)M * 256 * 2);
    unsigned short* magbf   = (unsigned short*)carve((size_t)M * HIDDEN * 2);
    unsigned short* hbf     = (unsigned short*)carve((size_t)M * HIDDEN * 2);
    int*            brp     = (int*)carve((size_t)(NBASE + 1) * 4);
    int*            bcol    = (int*)carve((size_t)baseE * 4);
    unsigned short* winbf   = (unsigned short*)carve((size_t)HIDDEN * CODE * 2);
    unsigned short* woutbf  = (unsigned short*)carve((size_t)CODE * HIDDEN * 2);
    unsigned short* wn1bf   = (unsigned short*)carve((size_t)NLAYERS * HIDDEN * 256 * 2);
    unsigned short* wn2bf   = (unsigned short*)carve((size_t)NLAYERS * HIDDEN * HIDDEN * 2);
    unsigned short* w2bf    = (unsigned short*)carve((size_t)NLAYERS * HIDDEN * HIDDEN * 2);
    unsigned short* w1ab    = (unsigned short*)carve((size_t)NLAYERS * 256 * HIDDEN * 2);
    float*          bias256 = (float*)carve((size_t)NLAYERS * 256 * 4);
    float*          c01     = (float*)carve((size_t)NLAYERS * 256 * 4);

    const int* row  = eidx;
    const int* colA = eidx + E;

    int prep_blocks = 519 + (baseE + 255) / 256;
    prep_all<<<dim3(prep_blocks), 256, 0, stream>>>(
        W_in, W_out, nW1, nW2, eW2, eW1, eb1, row, colA, gc,
        winbf, woutbf, wn1bf, wn2bf, w2bf, w1ab, bias256, c01,
        brp, bcol, baseE);

    // h0 = y @ W_in^T + b_in ; hn0 = LN0(h0) (base-major out)
    inproj_ln<<<dim3(M / 64), 256, 0, stream>>>(
        y, winbf, b_in, gam, bet, buf_hn, hnbf);

    // layer 0's [A|B]
    mgemm64<<<dim3(M / 64, 2), 256, 0, stream>>>(
        hnbf, HIDDEN, w1ab, bias256, nullptr, ABbf, 256, 0);

    for (int l = 0; l < NLAYERS; ++l) {
        edge_mfma7<<<dim3(NBASE * 4), 256, 0, stream>>>(
            ABbf, bcol, brp,
            w2bf + (size_t)l * HIDDEN * HIDDEN, c01 + (size_t)l * 256,
            eb2 + (size_t)l * HIDDEN, magbf);

        bool last = (l == NLAYERS - 1);
        nmlp_ln<<<dim3(M / 64), 256, 0, stream>>>(
            hnbf, magbf,
            wn1bf + (size_t)l * HIDDEN * 256, nb1 + (size_t)l * HIDDEN,
            wn2bf + (size_t)l * HIDDEN * HIDDEN, nb2 + (size_t)l * HIDDEN,
            buf_hn,
            last ? nullptr : gam + (size_t)(l + 1) * HIDDEN,
            last ? nullptr : bet + (size_t)(l + 1) * HIDDEN,
            buf_hn, hnbf, hbf,
            last ? nullptr : w1ab + (size_t)(l + 1) * 256 * HIDDEN,
            last ? nullptr : eb1 + (size_t)(l + 1) * HIDDEN,
            last ? nullptr : ABbf);
    }

    // out = h @ W_out^T + b_out ; blocks own contiguous OUTPUT rows,
    // A gathered (perm=3) -> streaming writes
    mgemm64<<<dim3(M / 64, CODE / 128), 256, 0, stream>>>(
        hbf, HIDDEN, woutbf, b_out, out, nullptr, CODE, 3);
}

// Round 14
// 437.902 us; speedup vs baseline: 1.2682x; 1.0397x over previous
//
#include <hip/hip_runtime.h>
#include <math.h>

// GNN denoiser: N=32768 (=512 base x 64 batch), HID=128, L=4.
// Base-major node layout. Edge MLP v8: cooperative build, W2 in regs,
// TWO edges per barrier with 4-buffer LDS rotation. Node MLP: stage-1 A
// streamed from global (W in LDS). In-proj fuses LN0 AND layer-0 [A|B].
// Out-proj gathers A rows so writes stream (perm=3).

#define HIDDEN 128
#define NLAYERS 4
#define NBASE 512
#define NB 64
#define CODE 1024

typedef __attribute__((ext_vector_type(8))) short s16x8;
typedef __attribute__((ext_vector_type(4))) float f32x4;

__device__ __forceinline__ unsigned int cvt_pk_bf16(float lo, float hi) {
    unsigned int d;
    asm("v_cvt_pk_bf16_f32 %0, %1, %2" : "=v"(d) : "v"(lo), "v"(hi));
    return d;
}
__device__ __forceinline__ unsigned short f2bf(float x) {
    return (unsigned short)cvt_pk_bf16(x, x);
}
__device__ __forceinline__ float silu_f(float x) {
    float e = __expf(-x);
    float r;
    asm("v_rcp_f32 %0, %1" : "=v"(r) : "v"(1.f + e));
    return x * r;
}

// ---------------- fused prep ----------------
__device__ __forceinline__ void conv_body(
    const float* __restrict__ s, unsigned short* __restrict__ d,
    int blk, int tid, int n) {
    int i = (blk * 256 + tid) * 4;
    if (i >= n) return;
    float4 v = *reinterpret_cast<const float4*>(s + i);
    uint2 o = { cvt_pk_bf16(v.x, v.y), cvt_pk_bf16(v.z, v.w) };
    *reinterpret_cast<uint2*>(d + i) = o;
}

__global__ __launch_bounds__(256) void prep_all(
    const float* __restrict__ W_in, const float* __restrict__ W_out,
    const float* __restrict__ nW1, const float* __restrict__ nW2,
    const float* __restrict__ eW2, const float* __restrict__ eW1,
    const float* __restrict__ eb1,
    const int* __restrict__ row, const int* __restrict__ col,
    const float* __restrict__ gc,
    unsigned short* __restrict__ winbf, unsigned short* __restrict__ woutbf,
    unsigned short* __restrict__ wn1bf, unsigned short* __restrict__ wn2bf,
    unsigned short* __restrict__ w2bf, unsigned short* __restrict__ w1ab,
    float* __restrict__ c01,
    int* __restrict__ brp, int* __restrict__ bcol, int baseE) {
    int blk = blockIdx.x, tid = threadIdx.x;
    if (blk < 128)      { conv_body(W_in,  winbf,  blk,       tid, HIDDEN * CODE); return; }
    if (blk < 256)      { conv_body(W_out, woutbf, blk - 128, tid, CODE * HIDDEN); return; }
    if (blk < 384)      { conv_body(nW1,   wn1bf,  blk - 256, tid, NLAYERS * HIDDEN * 256); return; }
    if (blk < 448)      { conv_body(nW2,   wn2bf,  blk - 384, tid, NLAYERS * HIDDEN * HIDDEN); return; }
    if (blk < 512)      { conv_body(eW2,   w2bf,   blk - 448, tid, NLAYERS * HIDDEN * HIDDEN); return; }
    if (blk < 516) {    // per-layer pack
        int l = blk - 512;
        const float* w = eW1 + (size_t)l * HIDDEN * 257;
        for (int i = tid; i < 256 * 128; i += 256) {
            int n = i >> 7, k = i & 127;
            float v = (n < 128) ? w[(size_t)n * 257 + k]
                                : w[(size_t)(n - 128) * 257 + 128 + k];
            w1ab[(size_t)l * 256 * 128 + i] = f2bf(v);
        }
        if (tid < 128) {
            float wd = w[(size_t)tid * 257 + 256];
            c01[(size_t)l * 256 + tid] = 2.f * wd;
            c01[(size_t)l * 256 + 128 + tid] = sqrtf(8.f) * wd;
        }
        return;
    }
    if (blk < 519) {    // rowptr over base graph
        int v = (blk - 516) * 256 + tid;
        if (v > NBASE) return;
        int lo = 0, hi = baseE;
        while (lo < hi) {
            int mid = (lo + hi) >> 1;
            if (row[mid] < v) lo = mid + 1; else hi = mid;
        }
        brp[v] = lo;
        return;
    }
    {   // basecol: packed cls<<15 | j
        int t = (blk - 519) * 256 + tid;
        if (t >= baseE) return;
        int u = col[t], v = row[t];
        float dx = gc[(size_t)u * 3 + 0] - gc[(size_t)v * 3 + 0];
        float dy = gc[(size_t)u * 3 + 1] - gc[(size_t)v * 3 + 1];
        float dz = gc[(size_t)u * 3 + 2] - gc[(size_t)v * 3 + 2];
        float d2 = dx * dx + dy * dy + dz * dz;
        bcol[t] = u | ((d2 > 6.f ? 1 : 0) << 15);
    }
}

// ---------------- generic bf16 MFMA GEMM, BM=64 (out-proj) ----------------
__global__ __launch_bounds__(256) void mgemm64(
    const unsigned short* __restrict__ A, int K,
    const unsigned short* __restrict__ W,
    const float* __restrict__ bias,
    float* __restrict__ Cf, unsigned short* __restrict__ Cb, int ldC, int perm) {
    __shared__ __align__(16) unsigned short As[64 * 128];
    __shared__ __align__(16) unsigned short Ws[128 * 128];
    int tid = threadIdx.x;
    int wid = tid >> 6, l = tid & 63, lr = l & 15, lg = l >> 4;
    int wm = wid >> 1, wn = wid & 1;
    int row0 = blockIdx.x * 64;
    int cb = blockIdx.y * 128;
    f32x4 acc[2][4];
#pragma unroll
    for (int i = 0; i < 2; ++i)
#pragma unroll
        for (int j = 0; j < 4; ++j) {
            f32x4 z = { 0.f, 0.f, 0.f, 0.f };
            acc[i][j] = z;
        }
    for (int kc = 0; kc < K; kc += 128) {
#pragma unroll
        for (int jj = 0; jj < 4; ++jj) {
            int j = tid + jj * 256;
            int r = j >> 4, c = j & 15;
            int srow = row0 + r;
            if (perm == 3) srow = ((srow & 511) << 6) | (srow >> 9);
            s16x8 v = *reinterpret_cast<const s16x8*>(
                A + (size_t)srow * K + kc + c * 8);
            *reinterpret_cast<s16x8*>(&As[r * 128 + ((c ^ (r & 7)) << 3)]) = v;
        }
#pragma unroll
        for (int jj = 0; jj < 8; ++jj) {
            int j = tid + jj * 256;
            int r = j >> 4, c = j & 15;
            s16x8 wv = *reinterpret_cast<const s16x8*>(
                W + (size_t)(cb + r) * K + kc + c * 8);
            *reinterpret_cast<s16x8*>(&Ws[r * 128 + ((c ^ (r & 7)) << 3)]) = wv;
        }
        __syncthreads();
#pragma unroll
        for (int ks = 0; ks < 4; ++ks) {
            int c = ks * 4 + lg;
            s16x8 af[2], bf[4];
#pragma unroll
            for (int mi = 0; mi < 2; ++mi) {
                int r = wm * 32 + mi * 16 + lr;
                af[mi] = *reinterpret_cast<s16x8*>(&As[r * 128 + ((c ^ (r & 7)) << 3)]);
            }
#pragma unroll
            for (int ni = 0; ni < 4; ++ni) {
                int n = wn * 64 + ni * 16 + lr;
                bf[ni] = *reinterpret_cast<s16x8*>(&Ws[n * 128 + ((c ^ (n & 7)) << 3)]);
            }
#pragma unroll
            for (int mi = 0; mi < 2; ++mi)
#pragma unroll
                for (int ni = 0; ni < 4; ++ni)
                    acc[mi][ni] = __builtin_amdgcn_mfma_f32_16x16x32_bf16(
                        af[mi], bf[ni], acc[mi][ni], 0, 0, 0);
        }
        __syncthreads();
    }
#pragma unroll
    for (int mi = 0; mi < 2; ++mi) {
#pragma unroll
        for (int ni = 0; ni < 4; ++ni) {
            int colg = cb + wn * 64 + ni * 16 + lr;
            float bs = bias ? bias[colg] : 0.f;
#pragma unroll
            for (int r4 = 0; r4 < 4; ++r4) {
                int rowg = row0 + wm * 32 + mi * 16 + lg * 4 + r4;
                float v = acc[mi][ni][r4] + bs;
                if (Cf) Cf[(size_t)rowg * ldC + colg] = v;
                if (Cb) Cb[(size_t)rowg * ldC + colg] = f2bf(v);
            }
        }
    }
}

// ---------------- in-projection + LN0 + layer-0 [A|B] ------------
__global__ __launch_bounds__(256) void inproj_ln(
    const float* __restrict__ y,
    const unsigned short* __restrict__ W, const float* __restrict__ bias,
    const float* __restrict__ g, const float* __restrict__ bet,
    float* __restrict__ hn, unsigned short* __restrict__ hnbf,
    const unsigned short* __restrict__ w1ab0,
    const float* __restrict__ eb1_0,
    unsigned short* __restrict__ ab_out) {
    __shared__ __align__(16) unsigned short As[64 * 128];
    __shared__ __align__(16) unsigned short Ws[128 * 128];
    int tid = threadIdx.x;
    int wid = tid >> 6, l = tid & 63, lr = l & 15, lg = l >> 4;
    int row0 = blockIdx.x * 64;
    f32x4 acc[8];
#pragma unroll
    for (int ni = 0; ni < 8; ++ni) {
        f32x4 z = { 0.f, 0.f, 0.f, 0.f };
        acc[ni] = z;
    }
    float4 pa0[4], pa1[4];
    s16x8 pw[8];
    auto loadc = [&](int kc) {
#pragma unroll
        for (int jj = 0; jj < 4; ++jj) {
            int j = tid + jj * 256, r = j >> 4, c = j & 15;
            const float* p = y + (size_t)(row0 + r) * CODE + kc + c * 8;
            pa0[jj] = *reinterpret_cast<const float4*>(p);
            pa1[jj] = *reinterpret_cast<const float4*>(p + 4);
        }
#pragma unroll
        for (int jj = 0; jj < 8; ++jj) {
            int j = tid + jj * 256, r = j >> 4, c = j & 15;
            pw[jj] = *reinterpret_cast<const s16x8*>(W + (size_t)r * CODE + kc + c * 8);
        }
    };
    auto storec = [&]() {
#pragma unroll
        for (int jj = 0; jj < 4; ++jj) {
            int j = tid + jj * 256, r = j >> 4, c = j & 15;
            union { s16x8 s; unsigned int w[4]; } pk;
            pk.w[0] = cvt_pk_bf16(pa0[jj].x, pa0[jj].y);
            pk.w[1] = cvt_pk_bf16(pa0[jj].z, pa0[jj].w);
            pk.w[2] = cvt_pk_bf16(pa1[jj].x, pa1[jj].y);
            pk.w[3] = cvt_pk_bf16(pa1[jj].z, pa1[jj].w);
            *reinterpret_cast<s16x8*>(&As[r * 128 + ((c ^ (r & 7)) << 3)]) = pk.s;
        }
#pragma unroll
        for (int jj = 0; jj < 8; ++jj) {
            int j = tid + jj * 256, r = j >> 4, c = j & 15;
            *reinterpret_cast<s16x8*>(&Ws[r * 128 + ((c ^ (r & 7)) << 3)]) = pw[jj];
        }
    };
    loadc(0);
    for (int kc8 = 0; kc8 < 8; ++kc8) {
        storec();
        __syncthreads();
        if (kc8 < 7) loadc((kc8 + 1) * 128);
#pragma unroll
        for (int ks = 0; ks < 4; ++ks) {
            int c = ks * 4 + lg;
            int r = wid * 16 + lr;
            s16x8 af = *reinterpret_cast<s16x8*>(&As[r * 128 + ((c ^ (r & 7)) << 3)]);
#pragma unroll
            for (int ni = 0; ni < 8; ++ni) {
                int n = ni * 16 + lr;
                s16x8 bf = *reinterpret_cast<s16x8*>(&Ws[n * 128 + ((c ^ (n & 7)) << 3)]);
                acc[ni] = __builtin_amdgcn_mfma_f32_16x16x32_bf16(af, bf, acc[ni], 0, 0, 0);
            }
        }
        __syncthreads();
    }
#pragma unroll
    for (int ni = 0; ni < 8; ++ni) {
        float bs = bias[ni * 16 + lr];
#pragma unroll
        for (int r4 = 0; r4 < 4; ++r4) acc[ni][r4] += bs;
    }
    float s[4], q[4];
#pragma unroll
    for (int r4 = 0; r4 < 4; ++r4) {
        float ss = 0.f, qq = 0.f;
#pragma unroll
        for (int ni = 0; ni < 8; ++ni) {
            float v = acc[ni][r4];
            ss += v; qq += v * v;
        }
#pragma unroll
        for (int o = 1; o < 16; o <<= 1) {
            ss += __shfl_xor(ss, o, 64);
            qq += __shfl_xor(qq, o, 64);
        }
        float mu = ss * (1.f / 128.f);
        float var = qq * (1.f / 128.f) - mu * mu;
        s[r4] = mu;
        q[r4] = rsqrtf(var + 1e-5f);
    }
    int orow_[4];
#pragma unroll
    for (int ni = 0; ni < 8; ++ni) {
        int col = ni * 16 + lr;
        float gg = g[col], bb = bet[col];
        int cc = col >> 3, cin = col & 7;
#pragma unroll
        for (int r4 = 0; r4 < 4; ++r4) {
            int rowg = row0 + wid * 16 + lg * 4 + r4;
            int orow = (rowg & 511) * 64 + (rowg >> 9);
            orow_[r4] = orow;
            float o = (acc[ni][r4] - s[r4]) * q[r4] * gg + bb;
            hn[(size_t)orow * HIDDEN + col] = o;
            hnbf[(size_t)orow * HIDDEN + col] = f2bf(o);
            // hn' into own As rows (wave-private; all waves past final K barrier)
            int rl = wid * 16 + lg * 4 + r4;
            As[rl * 128 + ((cc ^ (rl & 7)) << 3) + cin] = f2bf(o);
        }
    }
    // layer-0 [A|B]: two W halves
#pragma unroll
    for (int half = 0; half < 2; ++half) {
#pragma unroll
        for (int jj = 0; jj < 8; ++jj) {
            int j = tid + jj * 256;
            int r = j >> 4, c = j & 15;
            s16x8 wv = *reinterpret_cast<const s16x8*>(
                w1ab0 + (size_t)(half * 128 + r) * 128 + c * 8);
            *reinterpret_cast<s16x8*>(&Ws[r * 128 + ((c ^ (r & 7)) << 3)]) = wv;
        }
        __syncthreads();
#pragma unroll
        for (int ni = 0; ni < 8; ++ni) {
            f32x4 z = { 0.f, 0.f, 0.f, 0.f };
            acc[ni] = z;
        }
#pragma unroll
        for (int ks = 0; ks < 4; ++ks) {
            int c = ks * 4 + lg;
            int r = wid * 16 + lr;
            s16x8 af = *reinterpret_cast<s16x8*>(&As[r * 128 + ((c ^ (r & 7)) << 3)]);
#pragma unroll
            for (int ni = 0; ni < 8; ++ni) {
                int n = ni * 16 + lr;
                s16x8 bf = *reinterpret_cast<s16x8*>(&Ws[n * 128 + ((c ^ (n & 7)) << 3)]);
                acc[ni] = __builtin_amdgcn_mfma_f32_16x16x32_bf16(af, bf, acc[ni], 0, 0, 0);
            }
        }
#pragma unroll
        for (int ni = 0; ni < 8; ++ni) {
            int col = ni * 16 + lr;
            float bs = half ? eb1_0[col] : 0.f;
#pragma unroll
            for (int r4 = 0; r4 < 4; ++r4) {
                int rowg = row0 + wid * 16 + lg * 4 + r4;
                int orow = (rowg & 511) * 64 + (rowg >> 9);
                ab_out[(size_t)orow * 256 + half * 128 + col] =
                    f2bf(acc[ni][r4] + bs);
            }
        }
        if (half == 0) __syncthreads();
    }
}

// ---------------- fused node MLP + next LN + next-layer [A|B] ------------
// Stage-1 A streamed from global (wave-own rows); W staged in LDS.
__global__ __launch_bounds__(256) void nmlp_ln(
    const unsigned short* __restrict__ hnbf,
    const unsigned short* __restrict__ magbf,
    const unsigned short* __restrict__ w1, const float* __restrict__ b1,
    const unsigned short* __restrict__ w2, const float* __restrict__ b2,
    const float* __restrict__ resid,
    const float* __restrict__ g, const float* __restrict__ bet,
    float* __restrict__ hn_out, unsigned short* __restrict__ hnbf_out,
    unsigned short* __restrict__ hbf_out,
    const unsigned short* __restrict__ w1ab_next,
    const float* __restrict__ eb1_next,
    unsigned short* __restrict__ ab_out) {
    __shared__ __align__(16) unsigned short As[64 * 128];
    __shared__ __align__(16) unsigned short Ws[128 * 128];
    int tid = threadIdx.x;
    int wid = tid >> 6, l = tid & 63, lr = l & 15, lg = l >> 4;
    int row0 = blockIdx.x * 64;
    int myrow = row0 + wid * 16 + lr;
    f32x4 acc[8];
#pragma unroll
    for (int ni = 0; ni < 8; ++ni) {
        f32x4 z = { 0.f, 0.f, 0.f, 0.f };
        acc[ni] = z;
    }
    // stage 1: K=256 over [hn | mag], A streamed from global
    for (int kc = 0; kc < 2; ++kc) {
        const unsigned short* Xsrc = kc ? magbf : hnbf;
#pragma unroll
        for (int jj = 0; jj < 8; ++jj) {
            int j = tid + jj * 256;
            int r = j >> 4, c = j & 15;
            s16x8 wv = *reinterpret_cast<const s16x8*>(
                w1 + (size_t)r * 256 + kc * 128 + c * 8);
            *reinterpret_cast<s16x8*>(&Ws[r * 128 + ((c ^ (r & 7)) << 3)]) = wv;
        }
        __syncthreads();
#pragma unroll
        for (int ks = 0; ks < 4; ++ks) {
            s16x8 af = *reinterpret_cast<const s16x8*>(
                Xsrc + (size_t)myrow * 128 + ks * 32 + lg * 8);
#pragma unroll
            for (int ni = 0; ni < 8; ++ni) {
                int n = ni * 16 + lr;
                int c = ks * 4 + lg;
                s16x8 bf = *reinterpret_cast<s16x8*>(&Ws[n * 128 + ((c ^ (n & 7)) << 3)]);
                acc[ni] = __builtin_amdgcn_mfma_f32_16x16x32_bf16(af, bf, acc[ni], 0, 0, 0);
            }
        }
        __syncthreads();
    }
    // t = silu(acc + b1) -> As (own rows, swizzled)
#pragma unroll
    for (int ni = 0; ni < 8; ++ni) {
        int col = ni * 16 + lr;
        float bs = b1[col];
        int cc = col >> 3, cin = col & 7;
#pragma unroll
        for (int r4 = 0; r4 < 4; ++r4) {
            int rl = wid * 16 + lg * 4 + r4;
            As[rl * 128 + ((cc ^ (rl & 7)) << 3) + cin] =
                f2bf(silu_f(acc[ni][r4] + bs));
            acc[ni][r4] = 0.f;
        }
    }
#pragma unroll
    for (int jj = 0; jj < 8; ++jj) {
        int j = tid + jj * 256;
        int r = j >> 4, c = j & 15;
        s16x8 wv = *reinterpret_cast<const s16x8*>(w2 + (size_t)r * 128 + c * 8);
        *reinterpret_cast<s16x8*>(&Ws[r * 128 + ((c ^ (r & 7)) << 3)]) = wv;
    }
    __syncthreads();
    // stage 2: t @ W2^T
#pragma unroll
    for (int ks = 0; ks < 4; ++ks) {
        int c = ks * 4 + lg;
        int r = wid * 16 + lr;
        s16x8 af = *reinterpret_cast<s16x8*>(&As[r * 128 + ((c ^ (r & 7)) << 3)]);
#pragma unroll
        for (int ni = 0; ni < 8; ++ni) {
            int n = ni * 16 + lr;
            s16x8 bf = *reinterpret_cast<s16x8*>(&Ws[n * 128 + ((c ^ (n & 7)) << 3)]);
            acc[ni] = __builtin_amdgcn_mfma_f32_16x16x32_bf16(af, bf, acc[ni], 0, 0, 0);
        }
    }
    // h = acc + b2 + resid
#pragma unroll
    for (int ni = 0; ni < 8; ++ni) {
        int col = ni * 16 + lr;
        float bs = b2[col];
#pragma unroll
        for (int r4 = 0; r4 < 4; ++r4) {
            int rowg = row0 + wid * 16 + lg * 4 + r4;
            acc[ni][r4] += bs + resid[(size_t)rowg * HIDDEN + col];
        }
    }
    if (!g) {
#pragma unroll
        for (int ni = 0; ni < 8; ++ni) {
            int col = ni * 16 + lr;
#pragma unroll
            for (int r4 = 0; r4 < 4; ++r4) {
                int rowg = row0 + wid * 16 + lg * 4 + r4;
                hbf_out[(size_t)rowg * HIDDEN + col] = f2bf(acc[ni][r4]);
            }
        }
        return;
    }
    // LN
    float s[4], q[4];
#pragma unroll
    for (int r4 = 0; r4 < 4; ++r4) {
        float ss = 0.f, qq = 0.f;
#pragma unroll
        for (int ni = 0; ni < 8; ++ni) {
            float v = acc[ni][r4];
            ss += v; qq += v * v;
        }
#pragma unroll
        for (int o = 1; o < 16; o <<= 1) {
            ss += __shfl_xor(ss, o, 64);
            qq += __shfl_xor(qq, o, 64);
        }
        float mu = ss * (1.f / 128.f);
        float var = qq * (1.f / 128.f) - mu * mu;
        s[r4] = mu;
        q[r4] = rsqrtf(var + 1e-5f);
    }
#pragma unroll
    for (int ni = 0; ni < 8; ++ni) {
        int col = ni * 16 + lr;
        float gg = g[col], bb = bet[col];
        int cc = col >> 3, cin = col & 7;
#pragma unroll
        for (int r4 = 0; r4 < 4; ++r4) {
            int rowg = row0 + wid * 16 + lg * 4 + r4;
            float o = (acc[ni][r4] - s[r4]) * q[r4] * gg + bb;
            hn_out[(size_t)rowg * HIDDEN + col] = o;
            hnbf_out[(size_t)rowg * HIDDEN + col] = f2bf(o);
            int rl = wid * 16 + lg * 4 + r4;
            As[rl * 128 + ((cc ^ (rl & 7)) << 3) + cin] = f2bf(o);
        }
    }
    __syncthreads();    // all waves done reading Ws (stage 2)
#pragma unroll
    for (int half = 0; half < 2; ++half) {
#pragma unroll
        for (int jj = 0; jj < 8; ++jj) {
            int j = tid + jj * 256;
            int r = j >> 4, c = j & 15;
            s16x8 wv = *reinterpret_cast<const s16x8*>(
                w1ab_next + (size_t)(half * 128 + r) * 128 + c * 8);
            *reinterpret_cast<s16x8*>(&Ws[r * 128 + ((c ^ (r & 7)) << 3)]) = wv;
        }
        __syncthreads();
#pragma unroll
        for (int ni = 0; ni < 8; ++ni) {
            f32x4 z = { 0.f, 0.f, 0.f, 0.f };
            acc[ni] = z;
        }
#pragma unroll
        for (int ks = 0; ks < 4; ++ks) {
            int c = ks * 4 + lg;
            int r = wid * 16 + lr;
            s16x8 af = *reinterpret_cast<s16x8*>(&As[r * 128 + ((c ^ (r & 7)) << 3)]);
#pragma unroll
            for (int ni = 0; ni < 8; ++ni) {
                int n = ni * 16 + lr;
                s16x8 bf = *reinterpret_cast<s16x8*>(&Ws[n * 128 + ((c ^ (n & 7)) << 3)]);
                acc[ni] = __builtin_amdgcn_mfma_f32_16x16x32_bf16(af, bf, acc[ni], 0, 0, 0);
            }
        }
#pragma unroll
        for (int ni = 0; ni < 8; ++ni) {
            int col = ni * 16 + lr;
            float bs = half ? eb1_next[col] : 0.f;
#pragma unroll
            for (int r4 = 0; r4 < 4; ++r4) {
                int rowg = row0 + wid * 16 + lg * 4 + r4;
                ab_out[(size_t)rowg * 256 + half * 128 + col] =
                    f2bf(acc[ni][r4] + bs);
            }
        }
        if (half == 0) __syncthreads();
    }
}

// ---------------- edge MLP v8: 2 edges per barrier, 4 LDS buffers ---------
__global__ __launch_bounds__(256, 4) void edge_mfma8(
    const unsigned short* __restrict__ ABbf,
    const int* __restrict__ bcol,
    const int* __restrict__ brp,
    const unsigned short* __restrict__ w2bf,
    const float* __restrict__ c01,
    const float* __restrict__ eb2l,
    unsigned short* __restrict__ magbf) {
    __shared__ __align__(16) unsigned short m1[4][16 * 128];
    int tid = threadIdx.x;
    int blk = blockIdx.x;
    int i = blk >> 2, qtr = blk & 3;
    int wid = tid >> 6, l = tid & 63, lr = l & 15, lg = l >> 4;
    int rowb = qtr * 16;
    int col0 = wid * 32;

    s16x8 wfr[4][2];
#pragma unroll
    for (int ks = 0; ks < 4; ++ks)
#pragma unroll
        for (int ni = 0; ni < 2; ++ni) {
            int n = col0 + ni * 16 + lr;
            wfr[ks][ni] = *reinterpret_cast<const s16x8*>(
                w2bf + (size_t)n * 128 + (ks * 4 + lg) * 8);
        }

    int s = brp[i], e = brp[i + 1];
    int br = tid >> 4, bc = tid & 15;
    s16x8 Bp[2];
    {
        union { s16x8 s; unsigned int w[4]; } bv;
        bv.s = *reinterpret_cast<const s16x8*>(
            ABbf + ((size_t)i * NB + rowb + br) * 256 + 128 + bc * 8);
#pragma unroll
        for (int cls = 0; cls < 2; ++cls) {
            const float* cp = c01 + cls * 128 + bc * 8;
            float4 ca = *reinterpret_cast<const float4*>(cp);
            float4 cb = *reinterpret_cast<const float4*>(cp + 4);
            union { s16x8 s; unsigned int w[4]; } pk;
            pk.w[0] = cvt_pk_bf16(__uint_as_float(bv.w[0] << 16) + ca.x,
                                  __uint_as_float(bv.w[0] & 0xffff0000u) + ca.y);
            pk.w[1] = cvt_pk_bf16(__uint_as_float(bv.w[1] << 16) + ca.z,
                                  __uint_as_float(bv.w[1] & 0xffff0000u) + ca.w);
            pk.w[2] = cvt_pk_bf16(__uint_as_float(bv.w[2] << 16) + cb.x,
                                  __uint_as_float(bv.w[2] & 0xffff0000u) + cb.y);
            pk.w[3] = cvt_pk_bf16(__uint_as_float(bv.w[3] << 16) + cb.z,
                                  __uint_as_float(bv.w[3] & 0xffff0000u) + cb.w);
            Bp[cls] = pk.s;
        }
    }
    float e2[2], se[2];
#pragma unroll
    for (int ni = 0; ni < 2; ++ni) {
        e2[ni] = eb2l[col0 + ni * 16 + lr];
        se[ni] = silu_f(e2[ni]);
    }
    f32x4 agg[2];
#pragma unroll
    for (int ni = 0; ni < 2; ++ni) {
        f32x4 z = { 0.f, 0.f, 0.f, 0.f };
        agg[ni] = z;
    }

    auto loadA = [&](int t, int& pk) -> s16x8 {
        pk = __builtin_amdgcn_readfirstlane(bcol[t]);
        return *reinterpret_cast<const s16x8*>(
            ABbf + ((size_t)(pk & 0x7fff) * NB + rowb + br) * 256 + bc * 8);
    };
    auto build = [&](s16x8 A, int cls, int buf) {
        union { s16x8 s; unsigned int w[4]; } av, bv2, pkv;
        av.s = A;
        bv2.s = cls ? Bp[1] : Bp[0];
#pragma unroll
        for (int q = 0; q < 4; ++q) {
            float a0 = __uint_as_float(av.w[q] << 16);
            float a1 = __uint_as_float(av.w[q] & 0xffff0000u);
            float b0 = __uint_as_float(bv2.w[q] << 16);
            float b1 = __uint_as_float(bv2.w[q] & 0xffff0000u);
            pkv.w[q] = cvt_pk_bf16(silu_f(a0 + b0), silu_f(a1 + b1));
        }
        *reinterpret_cast<s16x8*>(
            &m1[buf][br * 128 + ((bc ^ (br & 7)) << 3)]) = pkv.s;
    };
    auto mfma_epi = [&](int buf) {
        f32x4 acc[2];
#pragma unroll
        for (int ni = 0; ni < 2; ++ni) {
            f32x4 iv = { e2[ni], e2[ni], e2[ni], e2[ni] };
            acc[ni] = iv;
        }
#pragma unroll
        for (int ks = 0; ks < 4; ++ks) {
            int cc = ks * 4 + lg;
            s16x8 af = *reinterpret_cast<s16x8*>(
                &m1[buf][lr * 128 + ((cc ^ (lr & 7)) << 3)]);
            acc[0] = __builtin_amdgcn_mfma_f32_16x16x32_bf16(af, wfr[ks][0], acc[0], 0, 0, 0);
            acc[1] = __builtin_amdgcn_mfma_f32_16x16x32_bf16(af, wfr[ks][1], acc[1], 0, 0, 0);
        }
#pragma unroll
        for (int ni = 0; ni < 2; ++ni)
#pragma unroll
            for (int r4 = 0; r4 < 4; ++r4)
                agg[ni][r4] += silu_f(acc[ni][r4]) - se[ni];
    };

    int pk0, pk1;
    s16x8 A0 = loadA(s, pk0);
    s16x8 A1 = A0;
    pk1 = pk0;
    if (s + 1 < e) A1 = loadA(s + 1, pk1);

    for (int t = s; t < e; t += 2) {
        int pb = (((t - s) >> 1) & 1) << 1;     // 0 or 2
        bool has2 = (t + 1) < e;
        // prefetch next pair
        int pk2 = pk0, pk3 = pk1;
        s16x8 A2 = A0, A3 = A1;
        if (t + 2 < e) A2 = loadA(t + 2, pk2);
        if (t + 3 < e) A3 = loadA(t + 3, pk3);
        build(A0, (pk0 >> 15) & 1, pb);
        if (has2) build(A1, (pk1 >> 15) & 1, pb + 1);
        __syncthreads();
        mfma_epi(pb);
        if (has2) mfma_epi(pb + 1);
        pk0 = pk2; A0 = A2; pk1 = pk3; A1 = A3;
    }

    float inv = (e > s) ? 1.f / (float)(e - s) : 0.f;
#pragma unroll
    for (int ni = 0; ni < 2; ++ni) {
#pragma unroll
        for (int r4 = 0; r4 < 4; ++r4) {
            size_t rowg = (size_t)i * NB + rowb + lg * 4 + r4;
            magbf[rowg * 128 + col0 + ni * 16 + lr] =
                f2bf(agg[ni][r4] * inv + se[ni]);
        }
    }
}

extern "C" void kernel_launch(void* const* d_in, const int* in_sizes, int n_in,
                              void* d_out, int out_size, void* d_ws, size_t ws_size,
                              hipStream_t stream) {
    const float* y     = (const float*)d_in[0];
    const float* gc    = (const float*)d_in[1];
    const int*   eidx  = (const int*)d_in[2];
    const float* W_in  = (const float*)d_in[3];
    const float* b_in  = (const float*)d_in[4];
    const float* gam   = (const float*)d_in[5];
    const float* bet   = (const float*)d_in[6];
    const float* eW1   = (const float*)d_in[7];
    const float* eb1   = (const float*)d_in[8];
    const float* eW2   = (const float*)d_in[9];
    const float* eb2   = (const float*)d_in[10];
    const float* nW1   = (const float*)d_in[11];
    const float* nb1   = (const float*)d_in[12];
    const float* nW2   = (const float*)d_in[13];
    const float* nb2   = (const float*)d_in[14];
    const float* W_out = (const float*)d_in[15];
    const float* b_out = (const float*)d_in[16];

    const int M = in_sizes[0] / CODE;       // 32768 (= NBASE * NB)
    const int E = in_sizes[2] / 2;
    const int baseE = E / NB;

    float* out = (float*)d_out;

    char* ws = (char*)d_ws;
    size_t off = 0;
    auto carve = [&](size_t bytes) {
        char* p = ws + off;
        off += (bytes + 255) & ~(size_t)255;
        return p;
    };
    float*          buf_hn  = (float*)carve((size_t)M * HIDDEN * 4);
    unsigned short* hnbf    = (unsigned short*)carve((size_t)M * HIDDEN * 2);
    unsigned short* ABbf    = (unsigned short*)carve((size_t)M * 256 * 2);
    unsigned short* magbf   = (unsigned short*)carve((size_t)M * HIDDEN * 2);
    unsigned short* hbf     = (unsigned short*)carve((size_t)M * HIDDEN * 2);
    int*            brp     = (int*)carve((size_t)(NBASE + 1) * 4);
    int*            bcol    = (int*)carve((size_t)baseE * 4);
    unsigned short* winbf   = (unsigned short*)carve((size_t)HIDDEN * CODE * 2);
    unsigned short* woutbf  = (unsigned short*)carve((size_t)CODE * HIDDEN * 2);
    unsigned short* wn1bf   = (unsigned short*)carve((size_t)NLAYERS * HIDDEN * 256 * 2);
    unsigned short* wn2bf   = (unsigned short*)carve((size_t)NLAYERS * HIDDEN * HIDDEN * 2);
    unsigned short* w2bf    = (unsigned short*)carve((size_t)NLAYERS * HIDDEN * HIDDEN * 2);
    unsigned short* w1ab    = (unsigned short*)carve((size_t)NLAYERS * 256 * HIDDEN * 2);
    float*          c01     = (float*)carve((size_t)NLAYERS * 256 * 4);

    const int* row  = eidx;
    const int* colA = eidx + E;

    int prep_blocks = 519 + (baseE + 255) / 256;
    prep_all<<<dim3(prep_blocks), 256, 0, stream>>>(
        W_in, W_out, nW1, nW2, eW2, eW1, eb1, row, colA, gc,
        winbf, woutbf, wn1bf, wn2bf, w2bf, w1ab, c01,
        brp, bcol, baseE);

    // h0 = y @ W_in^T + b_in ; hn0 = LN0 ; layer-0 [A|B] (all fused)
    inproj_ln<<<dim3(M / 64), 256, 0, stream>>>(
        y, winbf, b_in, gam, bet, buf_hn, hnbf, w1ab, eb1, ABbf);

    for (int l = 0; l < NLAYERS; ++l) {
        edge_mfma8<<<dim3(NBASE * 4), 256, 0, stream>>>(
            ABbf, bcol, brp,
            w2bf + (size_t)l * HIDDEN * HIDDEN, c01 + (size_t)l * 256,
            eb2 + (size_t)l * HIDDEN, magbf);

        bool last = (l == NLAYERS - 1);
        nmlp_ln<<<dim3(M / 64), 256, 0, stream>>>(
            hnbf, magbf,
            wn1bf + (size_t)l * HIDDEN * 256, nb1 + (size_t)l * HIDDEN,
            wn2bf + (size_t)l * HIDDEN * HIDDEN, nb2 + (size_t)l * HIDDEN,
            buf_hn,
            last ? nullptr : gam + (size_t)(l + 1) * HIDDEN,
            last ? nullptr : bet + (size_t)(l + 1) * HIDDEN,
            buf_hn, hnbf, hbf,
            last ? nullptr : w1ab + (size_t)(l + 1) * 256 * HIDDEN,
            last ? nullptr : eb1 + (size_t)(l + 1) * HIDDEN,
            last ? nullptr : ABbf);
    }

    // out = h @ W_out^T + b_out ; contiguous output rows, A gathered
    mgemm64<<<dim3(M / 64, CODE / 128), 256, 0, stream>>>(
        hbf, HIDDEN, woutbf, b_out, out, nullptr, CODE, 3);
}

// Round 15
// 422.607 us; speedup vs baseline: 1.3141x; 1.0362x over previous
//
#include <hip/hip_runtime.h>
#include <math.h>

// GNN denoiser: N=32768 (=512 base x 64 batch), HID=128, L=4.
// Base-major node layout. Edge MLP v8 (2 edges/barrier, 4 LDS buffers,
// W2 in regs). Node MLP streams stage-1 A from global. In-proj fuses LN0
// + layer-0 [A|B]. Out-proj gathers A rows (streaming writes).
// NEW: hot-loop barriers are LIGHT (lgkmcnt-only drain) so global register
// prefetches survive across barriers (vmcnt stays in flight).

#define HIDDEN 128
#define NLAYERS 4
#define NBASE 512
#define NB 64
#define CODE 1024

typedef __attribute__((ext_vector_type(8))) short s16x8;
typedef __attribute__((ext_vector_type(4))) float f32x4;

__device__ __forceinline__ unsigned int cvt_pk_bf16(float lo, float hi) {
    unsigned int d;
    asm("v_cvt_pk_bf16_f32 %0, %1, %2" : "=v"(d) : "v"(lo), "v"(hi));
    return d;
}
__device__ __forceinline__ unsigned short f2bf(float x) {
    return (unsigned short)cvt_pk_bf16(x, x);
}
__device__ __forceinline__ float silu_f(float x) {
    float e = __expf(-x);
    float r;
    asm("v_rcp_f32 %0, %1" : "=v"(r) : "v"(1.f + e));
    return x * r;
}
// Barrier that does NOT drain vmcnt: LDS ops are lgkmcnt-tracked, so
// lgkmcnt(0)+s_barrier makes all ds_writes visible; in-flight global
// prefetches keep flying (compiler waits vmcnt at first use).
__device__ __forceinline__ void light_barrier() {
    __builtin_amdgcn_sched_barrier(0);
    asm volatile("s_waitcnt lgkmcnt(0)" ::: "memory");
    __builtin_amdgcn_s_barrier();
    __builtin_amdgcn_sched_barrier(0);
}

// ---------------- fused prep ----------------
__device__ __forceinline__ void conv_body(
    const float* __restrict__ s, unsigned short* __restrict__ d,
    int blk, int tid, int n) {
    int i = (blk * 256 + tid) * 4;
    if (i >= n) return;
    float4 v = *reinterpret_cast<const float4*>(s + i);
    uint2 o = { cvt_pk_bf16(v.x, v.y), cvt_pk_bf16(v.z, v.w) };
    *reinterpret_cast<uint2*>(d + i) = o;
}

__global__ __launch_bounds__(256) void prep_all(
    const float* __restrict__ W_in, const float* __restrict__ W_out,
    const float* __restrict__ nW1, const float* __restrict__ nW2,
    const float* __restrict__ eW2, const float* __restrict__ eW1,
    const float* __restrict__ eb1,
    const int* __restrict__ row, const int* __restrict__ col,
    const float* __restrict__ gc,
    unsigned short* __restrict__ winbf, unsigned short* __restrict__ woutbf,
    unsigned short* __restrict__ wn1bf, unsigned short* __restrict__ wn2bf,
    unsigned short* __restrict__ w2bf, unsigned short* __restrict__ w1ab,
    float* __restrict__ c01,
    int* __restrict__ brp, int* __restrict__ bcol, int baseE) {
    int blk = blockIdx.x, tid = threadIdx.x;
    if (blk < 128)      { conv_body(W_in,  winbf,  blk,       tid, HIDDEN * CODE); return; }
    if (blk < 256)      { conv_body(W_out, woutbf, blk - 128, tid, CODE * HIDDEN); return; }
    if (blk < 384)      { conv_body(nW1,   wn1bf,  blk - 256, tid, NLAYERS * HIDDEN * 256); return; }
    if (blk < 448)      { conv_body(nW2,   wn2bf,  blk - 384, tid, NLAYERS * HIDDEN * HIDDEN); return; }
    if (blk < 512)      { conv_body(eW2,   w2bf,   blk - 448, tid, NLAYERS * HIDDEN * HIDDEN); return; }
    if (blk < 516) {    // per-layer pack
        int l = blk - 512;
        const float* w = eW1 + (size_t)l * HIDDEN * 257;
        for (int i = tid; i < 256 * 128; i += 256) {
            int n = i >> 7, k = i & 127;
            float v = (n < 128) ? w[(size_t)n * 257 + k]
                                : w[(size_t)(n - 128) * 257 + 128 + k];
            w1ab[(size_t)l * 256 * 128 + i] = f2bf(v);
        }
        if (tid < 128) {
            float wd = w[(size_t)tid * 257 + 256];
            c01[(size_t)l * 256 + tid] = 2.f * wd;
            c01[(size_t)l * 256 + 128 + tid] = sqrtf(8.f) * wd;
        }
        return;
    }
    if (blk < 519) {    // rowptr over base graph
        int v = (blk - 516) * 256 + tid;
        if (v > NBASE) return;
        int lo = 0, hi = baseE;
        while (lo < hi) {
            int mid = (lo + hi) >> 1;
            if (row[mid] < v) lo = mid + 1; else hi = mid;
        }
        brp[v] = lo;
        return;
    }
    {   // basecol: packed cls<<15 | j
        int t = (blk - 519) * 256 + tid;
        if (t >= baseE) return;
        int u = col[t], v = row[t];
        float dx = gc[(size_t)u * 3 + 0] - gc[(size_t)v * 3 + 0];
        float dy = gc[(size_t)u * 3 + 1] - gc[(size_t)v * 3 + 1];
        float dz = gc[(size_t)u * 3 + 2] - gc[(size_t)v * 3 + 2];
        float d2 = dx * dx + dy * dy + dz * dz;
        bcol[t] = u | ((d2 > 6.f ? 1 : 0) << 15);
    }
}

// ---------------- generic bf16 MFMA GEMM, BM=64 (out-proj) ----------------
__global__ __launch_bounds__(256) void mgemm64(
    const unsigned short* __restrict__ A, int K,
    const unsigned short* __restrict__ W,
    const float* __restrict__ bias,
    float* __restrict__ Cf, unsigned short* __restrict__ Cb, int ldC, int perm) {
    __shared__ __align__(16) unsigned short As[64 * 128];
    __shared__ __align__(16) unsigned short Ws[128 * 128];
    int tid = threadIdx.x;
    int wid = tid >> 6, l = tid & 63, lr = l & 15, lg = l >> 4;
    int wm = wid >> 1, wn = wid & 1;
    int row0 = blockIdx.x * 64;
    int cb = blockIdx.y * 128;
    f32x4 acc[2][4];
#pragma unroll
    for (int i = 0; i < 2; ++i)
#pragma unroll
        for (int j = 0; j < 4; ++j) {
            f32x4 z = { 0.f, 0.f, 0.f, 0.f };
            acc[i][j] = z;
        }
    for (int kc = 0; kc < K; kc += 128) {
#pragma unroll
        for (int jj = 0; jj < 4; ++jj) {
            int j = tid + jj * 256;
            int r = j >> 4, c = j & 15;
            int srow = row0 + r;
            if (perm == 3) srow = ((srow & 511) << 6) | (srow >> 9);
            s16x8 v = *reinterpret_cast<const s16x8*>(
                A + (size_t)srow * K + kc + c * 8);
            *reinterpret_cast<s16x8*>(&As[r * 128 + ((c ^ (r & 7)) << 3)]) = v;
        }
#pragma unroll
        for (int jj = 0; jj < 8; ++jj) {
            int j = tid + jj * 256;
            int r = j >> 4, c = j & 15;
            s16x8 wv = *reinterpret_cast<const s16x8*>(
                W + (size_t)(cb + r) * K + kc + c * 8);
            *reinterpret_cast<s16x8*>(&Ws[r * 128 + ((c ^ (r & 7)) << 3)]) = wv;
        }
        light_barrier();
#pragma unroll
        for (int ks = 0; ks < 4; ++ks) {
            int c = ks * 4 + lg;
            s16x8 af[2], bf[4];
#pragma unroll
            for (int mi = 0; mi < 2; ++mi) {
                int r = wm * 32 + mi * 16 + lr;
                af[mi] = *reinterpret_cast<s16x8*>(&As[r * 128 + ((c ^ (r & 7)) << 3)]);
            }
#pragma unroll
            for (int ni = 0; ni < 4; ++ni) {
                int n = wn * 64 + ni * 16 + lr;
                bf[ni] = *reinterpret_cast<s16x8*>(&Ws[n * 128 + ((c ^ (n & 7)) << 3)]);
            }
#pragma unroll
            for (int mi = 0; mi < 2; ++mi)
#pragma unroll
                for (int ni = 0; ni < 4; ++ni)
                    acc[mi][ni] = __builtin_amdgcn_mfma_f32_16x16x32_bf16(
                        af[mi], bf[ni], acc[mi][ni], 0, 0, 0);
        }
        light_barrier();
    }
#pragma unroll
    for (int mi = 0; mi < 2; ++mi) {
#pragma unroll
        for (int ni = 0; ni < 4; ++ni) {
            int colg = cb + wn * 64 + ni * 16 + lr;
            float bs = bias ? bias[colg] : 0.f;
#pragma unroll
            for (int r4 = 0; r4 < 4; ++r4) {
                int rowg = row0 + wm * 32 + mi * 16 + lg * 4 + r4;
                float v = acc[mi][ni][r4] + bs;
                if (Cf) Cf[(size_t)rowg * ldC + colg] = v;
                if (Cb) Cb[(size_t)rowg * ldC + colg] = f2bf(v);
            }
        }
    }
}

// ---------------- in-projection + LN0 + layer-0 [A|B] ------------
__global__ __launch_bounds__(256) void inproj_ln(
    const float* __restrict__ y,
    const unsigned short* __restrict__ W, const float* __restrict__ bias,
    const float* __restrict__ g, const float* __restrict__ bet,
    float* __restrict__ hn, unsigned short* __restrict__ hnbf,
    const unsigned short* __restrict__ w1ab0,
    const float* __restrict__ eb1_0,
    unsigned short* __restrict__ ab_out) {
    __shared__ __align__(16) unsigned short As[64 * 128];
    __shared__ __align__(16) unsigned short Ws[128 * 128];
    int tid = threadIdx.x;
    int wid = tid >> 6, l = tid & 63, lr = l & 15, lg = l >> 4;
    int row0 = blockIdx.x * 64;
    f32x4 acc[8];
#pragma unroll
    for (int ni = 0; ni < 8; ++ni) {
        f32x4 z = { 0.f, 0.f, 0.f, 0.f };
        acc[ni] = z;
    }
    float4 pa0[4], pa1[4];
    s16x8 pw[8];
    auto loadc = [&](int kc) {
#pragma unroll
        for (int jj = 0; jj < 4; ++jj) {
            int j = tid + jj * 256, r = j >> 4, c = j & 15;
            const float* p = y + (size_t)(row0 + r) * CODE + kc + c * 8;
            pa0[jj] = *reinterpret_cast<const float4*>(p);
            pa1[jj] = *reinterpret_cast<const float4*>(p + 4);
        }
#pragma unroll
        for (int jj = 0; jj < 8; ++jj) {
            int j = tid + jj * 256, r = j >> 4, c = j & 15;
            pw[jj] = *reinterpret_cast<const s16x8*>(W + (size_t)r * CODE + kc + c * 8);
        }
    };
    auto storec = [&]() {
#pragma unroll
        for (int jj = 0; jj < 4; ++jj) {
            int j = tid + jj * 256, r = j >> 4, c = j & 15;
            union { s16x8 s; unsigned int w[4]; } pk;
            pk.w[0] = cvt_pk_bf16(pa0[jj].x, pa0[jj].y);
            pk.w[1] = cvt_pk_bf16(pa0[jj].z, pa0[jj].w);
            pk.w[2] = cvt_pk_bf16(pa1[jj].x, pa1[jj].y);
            pk.w[3] = cvt_pk_bf16(pa1[jj].z, pa1[jj].w);
            *reinterpret_cast<s16x8*>(&As[r * 128 + ((c ^ (r & 7)) << 3)]) = pk.s;
        }
#pragma unroll
        for (int jj = 0; jj < 8; ++jj) {
            int j = tid + jj * 256, r = j >> 4, c = j & 15;
            *reinterpret_cast<s16x8*>(&Ws[r * 128 + ((c ^ (r & 7)) << 3)]) = pw[jj];
        }
    };
    loadc(0);
    for (int kc8 = 0; kc8 < 8; ++kc8) {
        storec();
        light_barrier();
        if (kc8 < 7) loadc((kc8 + 1) * 128);
#pragma unroll
        for (int ks = 0; ks < 4; ++ks) {
            int c = ks * 4 + lg;
            int r = wid * 16 + lr;
            s16x8 af = *reinterpret_cast<s16x8*>(&As[r * 128 + ((c ^ (r & 7)) << 3)]);
#pragma unroll
            for (int ni = 0; ni < 8; ++ni) {
                int n = ni * 16 + lr;
                s16x8 bf = *reinterpret_cast<s16x8*>(&Ws[n * 128 + ((c ^ (n & 7)) << 3)]);
                acc[ni] = __builtin_amdgcn_mfma_f32_16x16x32_bf16(af, bf, acc[ni], 0, 0, 0);
            }
        }
        light_barrier();
    }
#pragma unroll
    for (int ni = 0; ni < 8; ++ni) {
        float bs = bias[ni * 16 + lr];
#pragma unroll
        for (int r4 = 0; r4 < 4; ++r4) acc[ni][r4] += bs;
    }
    float s[4], q[4];
#pragma unroll
    for (int r4 = 0; r4 < 4; ++r4) {
        float ss = 0.f, qq = 0.f;
#pragma unroll
        for (int ni = 0; ni < 8; ++ni) {
            float v = acc[ni][r4];
            ss += v; qq += v * v;
        }
#pragma unroll
        for (int o = 1; o < 16; o <<= 1) {
            ss += __shfl_xor(ss, o, 64);
            qq += __shfl_xor(qq, o, 64);
        }
        float mu = ss * (1.f / 128.f);
        float var = qq * (1.f / 128.f) - mu * mu;
        s[r4] = mu;
        q[r4] = rsqrtf(var + 1e-5f);
    }
#pragma unroll
    for (int ni = 0; ni < 8; ++ni) {
        int col = ni * 16 + lr;
        float gg = g[col], bb = bet[col];
        int cc = col >> 3, cin = col & 7;
#pragma unroll
        for (int r4 = 0; r4 < 4; ++r4) {
            int rowg = row0 + wid * 16 + lg * 4 + r4;
            int orow = (rowg & 511) * 64 + (rowg >> 9);
            float o = (acc[ni][r4] - s[r4]) * q[r4] * gg + bb;
            hn[(size_t)orow * HIDDEN + col] = o;
            hnbf[(size_t)orow * HIDDEN + col] = f2bf(o);
            int rl = wid * 16 + lg * 4 + r4;
            As[rl * 128 + ((cc ^ (rl & 7)) << 3) + cin] = f2bf(o);
        }
    }
    // layer-0 [A|B]: two W halves
#pragma unroll
    for (int half = 0; half < 2; ++half) {
#pragma unroll
        for (int jj = 0; jj < 8; ++jj) {
            int j = tid + jj * 256;
            int r = j >> 4, c = j & 15;
            s16x8 wv = *reinterpret_cast<const s16x8*>(
                w1ab0 + (size_t)(half * 128 + r) * 128 + c * 8);
            *reinterpret_cast<s16x8*>(&Ws[r * 128 + ((c ^ (r & 7)) << 3)]) = wv;
        }
        light_barrier();
#pragma unroll
        for (int ni = 0; ni < 8; ++ni) {
            f32x4 z = { 0.f, 0.f, 0.f, 0.f };
            acc[ni] = z;
        }
#pragma unroll
        for (int ks = 0; ks < 4; ++ks) {
            int c = ks * 4 + lg;
            int r = wid * 16 + lr;
            s16x8 af = *reinterpret_cast<s16x8*>(&As[r * 128 + ((c ^ (r & 7)) << 3)]);
#pragma unroll
            for (int ni = 0; ni < 8; ++ni) {
                int n = ni * 16 + lr;
                s16x8 bf = *reinterpret_cast<s16x8*>(&Ws[n * 128 + ((c ^ (n & 7)) << 3)]);
                acc[ni] = __builtin_amdgcn_mfma_f32_16x16x32_bf16(af, bf, acc[ni], 0, 0, 0);
            }
        }
#pragma unroll
        for (int ni = 0; ni < 8; ++ni) {
            int col = ni * 16 + lr;
            float bs = half ? eb1_0[col] : 0.f;
#pragma unroll
            for (int r4 = 0; r4 < 4; ++r4) {
                int rowg = row0 + wid * 16 + lg * 4 + r4;
                int orow = (rowg & 511) * 64 + (rowg >> 9);
                ab_out[(size_t)orow * 256 + half * 128 + col] =
                    f2bf(acc[ni][r4] + bs);
            }
        }
        if (half == 0) light_barrier();
    }
}

// ---------------- fused node MLP + next LN + next-layer [A|B] ------------
__global__ __launch_bounds__(256) void nmlp_ln(
    const unsigned short* __restrict__ hnbf,
    const unsigned short* __restrict__ magbf,
    const unsigned short* __restrict__ w1, const float* __restrict__ b1,
    const unsigned short* __restrict__ w2, const float* __restrict__ b2,
    const float* __restrict__ resid,
    const float* __restrict__ g, const float* __restrict__ bet,
    float* __restrict__ hn_out, unsigned short* __restrict__ hnbf_out,
    unsigned short* __restrict__ hbf_out,
    const unsigned short* __restrict__ w1ab_next,
    const float* __restrict__ eb1_next,
    unsigned short* __restrict__ ab_out) {
    __shared__ __align__(16) unsigned short As[64 * 128];
    __shared__ __align__(16) unsigned short Ws[128 * 128];
    int tid = threadIdx.x;
    int wid = tid >> 6, l = tid & 63, lr = l & 15, lg = l >> 4;
    int row0 = blockIdx.x * 64;
    int myrow = row0 + wid * 16 + lr;
    f32x4 acc[8];
#pragma unroll
    for (int ni = 0; ni < 8; ++ni) {
        f32x4 z = { 0.f, 0.f, 0.f, 0.f };
        acc[ni] = z;
    }
    // stage 1: K=256 over [hn | mag], A streamed from global
    for (int kc = 0; kc < 2; ++kc) {
        const unsigned short* Xsrc = kc ? magbf : hnbf;
#pragma unroll
        for (int jj = 0; jj < 8; ++jj) {
            int j = tid + jj * 256;
            int r = j >> 4, c = j & 15;
            s16x8 wv = *reinterpret_cast<const s16x8*>(
                w1 + (size_t)r * 256 + kc * 128 + c * 8);
            *reinterpret_cast<s16x8*>(&Ws[r * 128 + ((c ^ (r & 7)) << 3)]) = wv;
        }
        light_barrier();
#pragma unroll
        for (int ks = 0; ks < 4; ++ks) {
            s16x8 af = *reinterpret_cast<const s16x8*>(
                Xsrc + (size_t)myrow * 128 + ks * 32 + lg * 8);
#pragma unroll
            for (int ni = 0; ni < 8; ++ni) {
                int n = ni * 16 + lr;
                int c = ks * 4 + lg;
                s16x8 bf = *reinterpret_cast<s16x8*>(&Ws[n * 128 + ((c ^ (n & 7)) << 3)]);
                acc[ni] = __builtin_amdgcn_mfma_f32_16x16x32_bf16(af, bf, acc[ni], 0, 0, 0);
            }
        }
        light_barrier();
    }
    // t = silu(acc + b1) -> As (own rows, swizzled)
#pragma unroll
    for (int ni = 0; ni < 8; ++ni) {
        int col = ni * 16 + lr;
        float bs = b1[col];
        int cc = col >> 3, cin = col & 7;
#pragma unroll
        for (int r4 = 0; r4 < 4; ++r4) {
            int rl = wid * 16 + lg * 4 + r4;
            As[rl * 128 + ((cc ^ (rl & 7)) << 3) + cin] =
                f2bf(silu_f(acc[ni][r4] + bs));
            acc[ni][r4] = 0.f;
        }
    }
#pragma unroll
    for (int jj = 0; jj < 8; ++jj) {
        int j = tid + jj * 256;
        int r = j >> 4, c = j & 15;
        s16x8 wv = *reinterpret_cast<const s16x8*>(w2 + (size_t)r * 128 + c * 8);
        *reinterpret_cast<s16x8*>(&Ws[r * 128 + ((c ^ (r & 7)) << 3)]) = wv;
    }
    light_barrier();
    // stage 2: t @ W2^T
#pragma unroll
    for (int ks = 0; ks < 4; ++ks) {
        int c = ks * 4 + lg;
        int r = wid * 16 + lr;
        s16x8 af = *reinterpret_cast<s16x8*>(&As[r * 128 + ((c ^ (r & 7)) << 3)]);
#pragma unroll
        for (int ni = 0; ni < 8; ++ni) {
            int n = ni * 16 + lr;
            s16x8 bf = *reinterpret_cast<s16x8*>(&Ws[n * 128 + ((c ^ (n & 7)) << 3)]);
            acc[ni] = __builtin_amdgcn_mfma_f32_16x16x32_bf16(af, bf, acc[ni], 0, 0, 0);
        }
    }
    // h = acc + b2 + resid
#pragma unroll
    for (int ni = 0; ni < 8; ++ni) {
        int col = ni * 16 + lr;
        float bs = b2[col];
#pragma unroll
        for (int r4 = 0; r4 < 4; ++r4) {
            int rowg = row0 + wid * 16 + lg * 4 + r4;
            acc[ni][r4] += bs + resid[(size_t)rowg * HIDDEN + col];
        }
    }
    if (!g) {
#pragma unroll
        for (int ni = 0; ni < 8; ++ni) {
            int col = ni * 16 + lr;
#pragma unroll
            for (int r4 = 0; r4 < 4; ++r4) {
                int rowg = row0 + wid * 16 + lg * 4 + r4;
                hbf_out[(size_t)rowg * HIDDEN + col] = f2bf(acc[ni][r4]);
            }
        }
        return;
    }
    // LN
    float s[4], q[4];
#pragma unroll
    for (int r4 = 0; r4 < 4; ++r4) {
        float ss = 0.f, qq = 0.f;
#pragma unroll
        for (int ni = 0; ni < 8; ++ni) {
            float v = acc[ni][r4];
            ss += v; qq += v * v;
        }
#pragma unroll
        for (int o = 1; o < 16; o <<= 1) {
            ss += __shfl_xor(ss, o, 64);
            qq += __shfl_xor(qq, o, 64);
        }
        float mu = ss * (1.f / 128.f);
        float var = qq * (1.f / 128.f) - mu * mu;
        s[r4] = mu;
        q[r4] = rsqrtf(var + 1e-5f);
    }
#pragma unroll
    for (int ni = 0; ni < 8; ++ni) {
        int col = ni * 16 + lr;
        float gg = g[col], bb = bet[col];
        int cc = col >> 3, cin = col & 7;
#pragma unroll
        for (int r4 = 0; r4 < 4; ++r4) {
            int rowg = row0 + wid * 16 + lg * 4 + r4;
            float o = (acc[ni][r4] - s[r4]) * q[r4] * gg + bb;
            hn_out[(size_t)rowg * HIDDEN + col] = o;
            hnbf_out[(size_t)rowg * HIDDEN + col] = f2bf(o);
            int rl = wid * 16 + lg * 4 + r4;
            As[rl * 128 + ((cc ^ (rl & 7)) << 3) + cin] = f2bf(o);
        }
    }
    light_barrier();    // all waves done reading Ws (stage 2)
#pragma unroll
    for (int half = 0; half < 2; ++half) {
#pragma unroll
        for (int jj = 0; jj < 8; ++jj) {
            int j = tid + jj * 256;
            int r = j >> 4, c = j & 15;
            s16x8 wv = *reinterpret_cast<const s16x8*>(
                w1ab_next + (size_t)(half * 128 + r) * 128 + c * 8);
            *reinterpret_cast<s16x8*>(&Ws[r * 128 + ((c ^ (r & 7)) << 3)]) = wv;
        }
        light_barrier();
#pragma unroll
        for (int ni = 0; ni < 8; ++ni) {
            f32x4 z = { 0.f, 0.f, 0.f, 0.f };
            acc[ni] = z;
        }
#pragma unroll
        for (int ks = 0; ks < 4; ++ks) {
            int c = ks * 4 + lg;
            int r = wid * 16 + lr;
            s16x8 af = *reinterpret_cast<s16x8*>(&As[r * 128 + ((c ^ (r & 7)) << 3)]);
#pragma unroll
            for (int ni = 0; ni < 8; ++ni) {
                int n = ni * 16 + lr;
                s16x8 bf = *reinterpret_cast<s16x8*>(&Ws[n * 128 + ((c ^ (n & 7)) << 3)]);
                acc[ni] = __builtin_amdgcn_mfma_f32_16x16x32_bf16(af, bf, acc[ni], 0, 0, 0);
            }
        }
#pragma unroll
        for (int ni = 0; ni < 8; ++ni) {
            int col = ni * 16 + lr;
            float bs = half ? eb1_next[col] : 0.f;
#pragma unroll
            for (int r4 = 0; r4 < 4; ++r4) {
                int rowg = row0 + wid * 16 + lg * 4 + r4;
                ab_out[(size_t)rowg * 256 + half * 128 + col] =
                    f2bf(acc[ni][r4] + bs);
            }
        }
        if (half == 0) light_barrier();
    }
}

// ---------------- edge MLP v8: 2 edges per barrier, 4 LDS buffers ---------
__global__ __launch_bounds__(256, 4) void edge_mfma8(
    const unsigned short* __restrict__ ABbf,
    const int* __restrict__ bcol,
    const int* __restrict__ brp,
    const unsigned short* __restrict__ w2bf,
    const float* __restrict__ c01,
    const float* __restrict__ eb2l,
    unsigned short* __restrict__ magbf) {
    __shared__ __align__(16) unsigned short m1[4][16 * 128];
    int tid = threadIdx.x;
    int blk = blockIdx.x;
    int i = blk >> 2, qtr = blk & 3;
    int wid = tid >> 6, l = tid & 63, lr = l & 15, lg = l >> 4;
    int rowb = qtr * 16;
    int col0 = wid * 32;

    s16x8 wfr[4][2];
#pragma unroll
    for (int ks = 0; ks < 4; ++ks)
#pragma unroll
        for (int ni = 0; ni < 2; ++ni) {
            int n = col0 + ni * 16 + lr;
            wfr[ks][ni] = *reinterpret_cast<const s16x8*>(
                w2bf + (size_t)n * 128 + (ks * 4 + lg) * 8);
        }

    int s = brp[i], e = brp[i + 1];
    int br = tid >> 4, bc = tid & 15;
    s16x8 Bp[2];
    {
        union { s16x8 s; unsigned int w[4]; } bv;
        bv.s = *reinterpret_cast<const s16x8*>(
            ABbf + ((size_t)i * NB + rowb + br) * 256 + 128 + bc * 8);
#pragma unroll
        for (int cls = 0; cls < 2; ++cls) {
            const float* cp = c01 + cls * 128 + bc * 8;
            float4 ca = *reinterpret_cast<const float4*>(cp);
            float4 cb = *reinterpret_cast<const float4*>(cp + 4);
            union { s16x8 s; unsigned int w[4]; } pk;
            pk.w[0] = cvt_pk_bf16(__uint_as_float(bv.w[0] << 16) + ca.x,
                                  __uint_as_float(bv.w[0] & 0xffff0000u) + ca.y);
            pk.w[1] = cvt_pk_bf16(__uint_as_float(bv.w[1] << 16) + ca.z,
                                  __uint_as_float(bv.w[1] & 0xffff0000u) + ca.w);
            pk.w[2] = cvt_pk_bf16(__uint_as_float(bv.w[2] << 16) + cb.x,
                                  __uint_as_float(bv.w[2] & 0xffff0000u) + cb.y);
            pk.w[3] = cvt_pk_bf16(__uint_as_float(bv.w[3] << 16) + cb.z,
                                  __uint_as_float(bv.w[3] & 0xffff0000u) + cb.w);
            Bp[cls] = pk.s;
        }
    }
    float e2[2], se[2];
#pragma unroll
    for (int ni = 0; ni < 2; ++ni) {
        e2[ni] = eb2l[col0 + ni * 16 + lr];
        se[ni] = silu_f(e2[ni]);
    }
    f32x4 agg[2];
#pragma unroll
    for (int ni = 0; ni < 2; ++ni) {
        f32x4 z = { 0.f, 0.f, 0.f, 0.f };
        agg[ni] = z;
    }

    auto loadA = [&](int t, int& pk) -> s16x8 {
        pk = __builtin_amdgcn_readfirstlane(bcol[t]);
        return *reinterpret_cast<const s16x8*>(
            ABbf + ((size_t)(pk & 0x7fff) * NB + rowb + br) * 256 + bc * 8);
    };
    auto build = [&](s16x8 A, int cls, int buf) {
        union { s16x8 s; unsigned int w[4]; } av, bv2, pkv;
        av.s = A;
        bv2.s = cls ? Bp[1] : Bp[0];
#pragma unroll
        for (int q = 0; q < 4; ++q) {
            float a0 = __uint_as_float(av.w[q] << 16);
            float a1 = __uint_as_float(av.w[q] & 0xffff0000u);
            float b0 = __uint_as_float(bv2.w[q] << 16);
            float b1 = __uint_as_float(bv2.w[q] & 0xffff0000u);
            pkv.w[q] = cvt_pk_bf16(silu_f(a0 + b0), silu_f(a1 + b1));
        }
        *reinterpret_cast<s16x8*>(
            &m1[buf][br * 128 + ((bc ^ (br & 7)) << 3)]) = pkv.s;
    };
    auto mfma_epi = [&](int buf) {
        f32x4 acc[2];
#pragma unroll
        for (int ni = 0; ni < 2; ++ni) {
            f32x4 iv = { e2[ni], e2[ni], e2[ni], e2[ni] };
            acc[ni] = iv;
        }
#pragma unroll
        for (int ks = 0; ks < 4; ++ks) {
            int cc = ks * 4 + lg;
            s16x8 af = *reinterpret_cast<s16x8*>(
                &m1[buf][lr * 128 + ((cc ^ (lr & 7)) << 3)]);
            acc[0] = __builtin_amdgcn_mfma_f32_16x16x32_bf16(af, wfr[ks][0], acc[0], 0, 0, 0);
            acc[1] = __builtin_amdgcn_mfma_f32_16x16x32_bf16(af, wfr[ks][1], acc[1], 0, 0, 0);
        }
#pragma unroll
        for (int ni = 0; ni < 2; ++ni)
#pragma unroll
            for (int r4 = 0; r4 < 4; ++r4)
                agg[ni][r4] += silu_f(acc[ni][r4]) - se[ni];
    };

    int pk0, pk1;
    s16x8 A0 = loadA(s, pk0);
    s16x8 A1 = A0;
    pk1 = pk0;
    if (s + 1 < e) A1 = loadA(s + 1, pk1);

    for (int t = s; t < e; t += 2) {
        int pb = (((t - s) >> 1) & 1) << 1;     // 0 or 2
        bool has2 = (t + 1) < e;
        int pk2 = pk0, pk3 = pk1;
        s16x8 A2 = A0, A3 = A1;
        if (t + 2 < e) A2 = loadA(t + 2, pk2);
        if (t + 3 < e) A3 = loadA(t + 3, pk3);
        build(A0, (pk0 >> 15) & 1, pb);
        if (has2) build(A1, (pk1 >> 15) & 1, pb + 1);
        light_barrier();
        mfma_epi(pb);
        if (has2) mfma_epi(pb + 1);
        pk0 = pk2; A0 = A2; pk1 = pk3; A1 = A3;
    }

    float inv = (e > s) ? 1.f / (float)(e - s) : 0.f;
#pragma unroll
    for (int ni = 0; ni < 2; ++ni) {
#pragma unroll
        for (int r4 = 0; r4 < 4; ++r4) {
            size_t rowg = (size_t)i * NB + rowb + lg * 4 + r4;
            magbf[rowg * 128 + col0 + ni * 16 + lr] =
                f2bf(agg[ni][r4] * inv + se[ni]);
        }
    }
}

extern "C" void kernel_launch(void* const* d_in, const int* in_sizes, int n_in,
                              void* d_out, int out_size, void* d_ws, size_t ws_size,
                              hipStream_t stream) {
    const float* y     = (const float*)d_in[0];
    const float* gc    = (const float*)d_in[1];
    const int*   eidx  = (const int*)d_in[2];
    const float* W_in  = (const float*)d_in[3];
    const float* b_in  = (const float*)d_in[4];
    const float* gam   = (const float*)d_in[5];
    const float* bet   = (const float*)d_in[6];
    const float* eW1   = (const float*)d_in[7];
    const float* eb1   = (const float*)d_in[8];
    const float* eW2   = (const float*)d_in[9];
    const float* eb2   = (const float*)d_in[10];
    const float* nW1   = (const float*)d_in[11];
    const float* nb1   = (const float*)d_in[12];
    const float* nW2   = (const float*)d_in[13];
    const float* nb2   = (const float*)d_in[14];
    const float* W_out = (const float*)d_in[15];
    const float* b_out = (const float*)d_in[16];

    const int M = in_sizes[0] / CODE;       // 32768 (= NBASE * NB)
    const int E = in_sizes[2] / 2;
    const int baseE = E / NB;

    float* out = (float*)d_out;

    char* ws = (char*)d_ws;
    size_t off = 0;
    auto carve = [&](size_t bytes) {
        char* p = ws + off;
        off += (bytes + 255) & ~(size_t)255;
        return p;
    };
    float*          buf_hn  = (float*)carve((size_t)M * HIDDEN * 4);
    unsigned short* hnbf    = (unsigned short*)carve((size_t)M * HIDDEN * 2);
    unsigned short* ABbf    = (unsigned short*)carve((size_t)M * 256 * 2);
    unsigned short* magbf   = (unsigned short*)carve((size_t)M * HIDDEN * 2);
    unsigned short* hbf     = (unsigned short*)carve((size_t)M * HIDDEN * 2);
    int*            brp     = (int*)carve((size_t)(NBASE + 1) * 4);
    int*            bcol    = (int*)carve((size_t)baseE * 4);
    unsigned short* winbf   = (unsigned short*)carve((size_t)HIDDEN * CODE * 2);
    unsigned short* woutbf  = (unsigned short*)carve((size_t)CODE * HIDDEN * 2);
    unsigned short* wn1bf   = (unsigned short*)carve((size_t)NLAYERS * HIDDEN * 256 * 2);
    unsigned short* wn2bf   = (unsigned short*)carve((size_t)NLAYERS * HIDDEN * HIDDEN * 2);
    unsigned short* w2bf    = (unsigned short*)carve((size_t)NLAYERS * HIDDEN * HIDDEN * 2);
    unsigned short* w1ab    = (unsigned short*)carve((size_t)NLAYERS * 256 * HIDDEN * 2);
    float*          c01     = (float*)carve((size_t)NLAYERS * 256 * 4);

    const int* row  = eidx;
    const int* colA = eidx + E;

    int prep_blocks = 519 + (baseE + 255) / 256;
    prep_all<<<dim3(prep_blocks), 256, 0, stream>>>(
        W_in, W_out, nW1, nW2, eW2, eW1, eb1, row, colA, gc,
        winbf, woutbf, wn1bf, wn2bf, w2bf, w1ab, c01,
        brp, bcol, baseE);

    // h0 = y @ W_in^T + b_in ; hn0 = LN0 ; layer-0 [A|B] (all fused)
    inproj_ln<<<dim3(M / 64), 256, 0, stream>>>(
        y, winbf, b_in, gam, bet, buf_hn, hnbf, w1ab, eb1, ABbf);

    for (int l = 0; l < NLAYERS; ++l) {
        edge_mfma8<<<dim3(NBASE * 4), 256, 0, stream>>>(
            ABbf, bcol, brp,
            w2bf + (size_t)l * HIDDEN * HIDDEN, c01 + (size_t)l * 256,
            eb2 + (size_t)l * HIDDEN, magbf);

        bool last = (l == NLAYERS - 1);
        nmlp_ln<<<dim3(M / 64), 256, 0, stream>>>(
            hnbf, magbf,
            wn1bf + (size_t)l * HIDDEN * 256, nb1 + (size_t)l * HIDDEN,
            wn2bf + (size_t)l * HIDDEN * HIDDEN, nb2 + (size_t)l * HIDDEN,
            buf_hn,
            last ? nullptr : gam + (size_t)(l + 1) * HIDDEN,
            last ? nullptr : bet + (size_t)(l + 1) * HIDDEN,
            buf_hn, hnbf, hbf,
            last ? nullptr : w1ab + (size_t)(l + 1) * 256 * HIDDEN,
            last ? nullptr : eb1 + (size_t)(l + 1) * HIDDEN,
            last ? nullptr : ABbf);
    }

    // out = h @ W_out^T + b_out ; contiguous output rows, A gathered
    mgemm64<<<dim3(M / 64, CODE / 128), 256, 0, stream>>>(
        hbf, HIDDEN, woutbf, b_out, out, nullptr, CODE, 3);
}

// Round 16
// 400.928 us; speedup vs baseline: 1.3852x; 1.0541x over previous
//
#include <hip/hip_runtime.h>
#include <math.h>

// GNN denoiser: N=32768 (=512 base x 64 batch), HID=128, L=4.
// Base-major node layout. Edge MLP v8 (2 edges/barrier, 4 LDS buffers,
// W2 in regs, light barriers). Node MLP streams stage-1 A from global.
// In-proj fuses LN0 + layer-0 [A|B]. Out-proj gathers A rows.
// NEW: residual stream is bf16 (hnbf, updated in place) — fp32 buf_hn gone.

#define HIDDEN 128
#define NLAYERS 4
#define NBASE 512
#define NB 64
#define CODE 1024

typedef __attribute__((ext_vector_type(8))) short s16x8;
typedef __attribute__((ext_vector_type(4))) float f32x4;

__device__ __forceinline__ unsigned int cvt_pk_bf16(float lo, float hi) {
    unsigned int d;
    asm("v_cvt_pk_bf16_f32 %0, %1, %2" : "=v"(d) : "v"(lo), "v"(hi));
    return d;
}
__device__ __forceinline__ unsigned short f2bf(float x) {
    return (unsigned short)cvt_pk_bf16(x, x);
}
__device__ __forceinline__ float bf2f(unsigned short b) {
    return __uint_as_float(((unsigned int)b) << 16);
}
__device__ __forceinline__ float silu_f(float x) {
    float e = __expf(-x);
    float r;
    asm("v_rcp_f32 %0, %1" : "=v"(r) : "v"(1.f + e));
    return x * r;
}
// Barrier that does NOT drain vmcnt: LDS ops are lgkmcnt-tracked, so
// lgkmcnt(0)+s_barrier makes all ds_writes visible; in-flight global
// prefetches keep flying (compiler waits vmcnt at first use).
__device__ __forceinline__ void light_barrier() {
    __builtin_amdgcn_sched_barrier(0);
    asm volatile("s_waitcnt lgkmcnt(0)" ::: "memory");
    __builtin_amdgcn_s_barrier();
    __builtin_amdgcn_sched_barrier(0);
}

// ---------------- fused prep ----------------
__device__ __forceinline__ void conv_body(
    const float* __restrict__ s, unsigned short* __restrict__ d,
    int blk, int tid, int n) {
    int i = (blk * 256 + tid) * 4;
    if (i >= n) return;
    float4 v = *reinterpret_cast<const float4*>(s + i);
    uint2 o = { cvt_pk_bf16(v.x, v.y), cvt_pk_bf16(v.z, v.w) };
    *reinterpret_cast<uint2*>(d + i) = o;
}

__global__ __launch_bounds__(256) void prep_all(
    const float* __restrict__ W_in, const float* __restrict__ W_out,
    const float* __restrict__ nW1, const float* __restrict__ nW2,
    const float* __restrict__ eW2, const float* __restrict__ eW1,
    const float* __restrict__ eb1,
    const int* __restrict__ row, const int* __restrict__ col,
    const float* __restrict__ gc,
    unsigned short* __restrict__ winbf, unsigned short* __restrict__ woutbf,
    unsigned short* __restrict__ wn1bf, unsigned short* __restrict__ wn2bf,
    unsigned short* __restrict__ w2bf, unsigned short* __restrict__ w1ab,
    float* __restrict__ c01,
    int* __restrict__ brp, int* __restrict__ bcol, int baseE) {
    int blk = blockIdx.x, tid = threadIdx.x;
    if (blk < 128)      { conv_body(W_in,  winbf,  blk,       tid, HIDDEN * CODE); return; }
    if (blk < 256)      { conv_body(W_out, woutbf, blk - 128, tid, CODE * HIDDEN); return; }
    if (blk < 384)      { conv_body(nW1,   wn1bf,  blk - 256, tid, NLAYERS * HIDDEN * 256); return; }
    if (blk < 448)      { conv_body(nW2,   wn2bf,  blk - 384, tid, NLAYERS * HIDDEN * HIDDEN); return; }
    if (blk < 512)      { conv_body(eW2,   w2bf,   blk - 448, tid, NLAYERS * HIDDEN * HIDDEN); return; }
    if (blk < 516) {    // per-layer pack
        int l = blk - 512;
        const float* w = eW1 + (size_t)l * HIDDEN * 257;
        for (int i = tid; i < 256 * 128; i += 256) {
            int n = i >> 7, k = i & 127;
            float v = (n < 128) ? w[(size_t)n * 257 + k]
                                : w[(size_t)(n - 128) * 257 + 128 + k];
            w1ab[(size_t)l * 256 * 128 + i] = f2bf(v);
        }
        if (tid < 128) {
            float wd = w[(size_t)tid * 257 + 256];
            c01[(size_t)l * 256 + tid] = 2.f * wd;
            c01[(size_t)l * 256 + 128 + tid] = sqrtf(8.f) * wd;
        }
        return;
    }
    if (blk < 519) {    // rowptr over base graph
        int v = (blk - 516) * 256 + tid;
        if (v > NBASE) return;
        int lo = 0, hi = baseE;
        while (lo < hi) {
            int mid = (lo + hi) >> 1;
            if (row[mid] < v) lo = mid + 1; else hi = mid;
        }
        brp[v] = lo;
        return;
    }
    {   // basecol: packed cls<<15 | j
        int t = (blk - 519) * 256 + tid;
        if (t >= baseE) return;
        int u = col[t], v = row[t];
        float dx = gc[(size_t)u * 3 + 0] - gc[(size_t)v * 3 + 0];
        float dy = gc[(size_t)u * 3 + 1] - gc[(size_t)v * 3 + 1];
        float dz = gc[(size_t)u * 3 + 2] - gc[(size_t)v * 3 + 2];
        float d2 = dx * dx + dy * dy + dz * dz;
        bcol[t] = u | ((d2 > 6.f ? 1 : 0) << 15);
    }
}

// ---------------- generic bf16 MFMA GEMM, BM=64 (out-proj) ----------------
__global__ __launch_bounds__(256) void mgemm64(
    const unsigned short* __restrict__ A, int K,
    const unsigned short* __restrict__ W,
    const float* __restrict__ bias,
    float* __restrict__ Cf, unsigned short* __restrict__ Cb, int ldC, int perm) {
    __shared__ __align__(16) unsigned short As[64 * 128];
    __shared__ __align__(16) unsigned short Ws[128 * 128];
    int tid = threadIdx.x;
    int wid = tid >> 6, l = tid & 63, lr = l & 15, lg = l >> 4;
    int wm = wid >> 1, wn = wid & 1;
    int row0 = blockIdx.x * 64;
    int cb = blockIdx.y * 128;
    f32x4 acc[2][4];
#pragma unroll
    for (int i = 0; i < 2; ++i)
#pragma unroll
        for (int j = 0; j < 4; ++j) {
            f32x4 z = { 0.f, 0.f, 0.f, 0.f };
            acc[i][j] = z;
        }
    for (int kc = 0; kc < K; kc += 128) {
#pragma unroll
        for (int jj = 0; jj < 4; ++jj) {
            int j = tid + jj * 256;
            int r = j >> 4, c = j & 15;
            int srow = row0 + r;
            if (perm == 3) srow = ((srow & 511) << 6) | (srow >> 9);
            s16x8 v = *reinterpret_cast<const s16x8*>(
                A + (size_t)srow * K + kc + c * 8);
            *reinterpret_cast<s16x8*>(&As[r * 128 + ((c ^ (r & 7)) << 3)]) = v;
        }
#pragma unroll
        for (int jj = 0; jj < 8; ++jj) {
            int j = tid + jj * 256;
            int r = j >> 4, c = j & 15;
            s16x8 wv = *reinterpret_cast<const s16x8*>(
                W + (size_t)(cb + r) * K + kc + c * 8);
            *reinterpret_cast<s16x8*>(&Ws[r * 128 + ((c ^ (r & 7)) << 3)]) = wv;
        }
        light_barrier();
#pragma unroll
        for (int ks = 0; ks < 4; ++ks) {
            int c = ks * 4 + lg;
            s16x8 af[2], bf[4];
#pragma unroll
            for (int mi = 0; mi < 2; ++mi) {
                int r = wm * 32 + mi * 16 + lr;
                af[mi] = *reinterpret_cast<s16x8*>(&As[r * 128 + ((c ^ (r & 7)) << 3)]);
            }
#pragma unroll
            for (int ni = 0; ni < 4; ++ni) {
                int n = wn * 64 + ni * 16 + lr;
                bf[ni] = *reinterpret_cast<s16x8*>(&Ws[n * 128 + ((c ^ (n & 7)) << 3)]);
            }
#pragma unroll
            for (int mi = 0; mi < 2; ++mi)
#pragma unroll
                for (int ni = 0; ni < 4; ++ni)
                    acc[mi][ni] = __builtin_amdgcn_mfma_f32_16x16x32_bf16(
                        af[mi], bf[ni], acc[mi][ni], 0, 0, 0);
        }
        light_barrier();
    }
#pragma unroll
    for (int mi = 0; mi < 2; ++mi) {
#pragma unroll
        for (int ni = 0; ni < 4; ++ni) {
            int colg = cb + wn * 64 + ni * 16 + lr;
            float bs = bias ? bias[colg] : 0.f;
#pragma unroll
            for (int r4 = 0; r4 < 4; ++r4) {
                int rowg = row0 + wm * 32 + mi * 16 + lg * 4 + r4;
                float v = acc[mi][ni][r4] + bs;
                if (Cf) Cf[(size_t)rowg * ldC + colg] = v;
                if (Cb) Cb[(size_t)rowg * ldC + colg] = f2bf(v);
            }
        }
    }
}

// ---------------- in-projection + LN0 + layer-0 [A|B] ------------
__global__ __launch_bounds__(256) void inproj_ln(
    const float* __restrict__ y,
    const unsigned short* __restrict__ W, const float* __restrict__ bias,
    const float* __restrict__ g, const float* __restrict__ bet,
    unsigned short* __restrict__ hnbf,
    const unsigned short* __restrict__ w1ab0,
    const float* __restrict__ eb1_0,
    unsigned short* __restrict__ ab_out) {
    __shared__ __align__(16) unsigned short As[64 * 128];
    __shared__ __align__(16) unsigned short Ws[128 * 128];
    int tid = threadIdx.x;
    int wid = tid >> 6, l = tid & 63, lr = l & 15, lg = l >> 4;
    int row0 = blockIdx.x * 64;
    f32x4 acc[8];
#pragma unroll
    for (int ni = 0; ni < 8; ++ni) {
        f32x4 z = { 0.f, 0.f, 0.f, 0.f };
        acc[ni] = z;
    }
    float4 pa0[4], pa1[4];
    s16x8 pw[8];
    auto loadc = [&](int kc) {
#pragma unroll
        for (int jj = 0; jj < 4; ++jj) {
            int j = tid + jj * 256, r = j >> 4, c = j & 15;
            const float* p = y + (size_t)(row0 + r) * CODE + kc + c * 8;
            pa0[jj] = *reinterpret_cast<const float4*>(p);
            pa1[jj] = *reinterpret_cast<const float4*>(p + 4);
        }
#pragma unroll
        for (int jj = 0; jj < 8; ++jj) {
            int j = tid + jj * 256, r = j >> 4, c = j & 15;
            pw[jj] = *reinterpret_cast<const s16x8*>(W + (size_t)r * CODE + kc + c * 8);
        }
    };
    auto storec = [&]() {
#pragma unroll
        for (int jj = 0; jj < 4; ++jj) {
            int j = tid + jj * 256, r = j >> 4, c = j & 15;
            union { s16x8 s; unsigned int w[4]; } pk;
            pk.w[0] = cvt_pk_bf16(pa0[jj].x, pa0[jj].y);
            pk.w[1] = cvt_pk_bf16(pa0[jj].z, pa0[jj].w);
            pk.w[2] = cvt_pk_bf16(pa1[jj].x, pa1[jj].y);
            pk.w[3] = cvt_pk_bf16(pa1[jj].z, pa1[jj].w);
            *reinterpret_cast<s16x8*>(&As[r * 128 + ((c ^ (r & 7)) << 3)]) = pk.s;
        }
#pragma unroll
        for (int jj = 0; jj < 8; ++jj) {
            int j = tid + jj * 256, r = j >> 4, c = j & 15;
            *reinterpret_cast<s16x8*>(&Ws[r * 128 + ((c ^ (r & 7)) << 3)]) = pw[jj];
        }
    };
    loadc(0);
    for (int kc8 = 0; kc8 < 8; ++kc8) {
        storec();
        light_barrier();
        if (kc8 < 7) loadc((kc8 + 1) * 128);
#pragma unroll
        for (int ks = 0; ks < 4; ++ks) {
            int c = ks * 4 + lg;
            int r = wid * 16 + lr;
            s16x8 af = *reinterpret_cast<s16x8*>(&As[r * 128 + ((c ^ (r & 7)) << 3)]);
#pragma unroll
            for (int ni = 0; ni < 8; ++ni) {
                int n = ni * 16 + lr;
                s16x8 bf = *reinterpret_cast<s16x8*>(&Ws[n * 128 + ((c ^ (n & 7)) << 3)]);
                acc[ni] = __builtin_amdgcn_mfma_f32_16x16x32_bf16(af, bf, acc[ni], 0, 0, 0);
            }
        }
        light_barrier();
    }
#pragma unroll
    for (int ni = 0; ni < 8; ++ni) {
        float bs = bias[ni * 16 + lr];
#pragma unroll
        for (int r4 = 0; r4 < 4; ++r4) acc[ni][r4] += bs;
    }
    float s[4], q[4];
#pragma unroll
    for (int r4 = 0; r4 < 4; ++r4) {
        float ss = 0.f, qq = 0.f;
#pragma unroll
        for (int ni = 0; ni < 8; ++ni) {
            float v = acc[ni][r4];
            ss += v; qq += v * v;
        }
#pragma unroll
        for (int o = 1; o < 16; o <<= 1) {
            ss += __shfl_xor(ss, o, 64);
            qq += __shfl_xor(qq, o, 64);
        }
        float mu = ss * (1.f / 128.f);
        float var = qq * (1.f / 128.f) - mu * mu;
        s[r4] = mu;
        q[r4] = rsqrtf(var + 1e-5f);
    }
#pragma unroll
    for (int ni = 0; ni < 8; ++ni) {
        int col = ni * 16 + lr;
        float gg = g[col], bb = bet[col];
        int cc = col >> 3, cin = col & 7;
#pragma unroll
        for (int r4 = 0; r4 < 4; ++r4) {
            int rowg = row0 + wid * 16 + lg * 4 + r4;
            int orow = (rowg & 511) * 64 + (rowg >> 9);
            float o = (acc[ni][r4] - s[r4]) * q[r4] * gg + bb;
            hnbf[(size_t)orow * HIDDEN + col] = f2bf(o);
            int rl = wid * 16 + lg * 4 + r4;
            As[rl * 128 + ((cc ^ (rl & 7)) << 3) + cin] = f2bf(o);
        }
    }
    // layer-0 [A|B]: two W halves
#pragma unroll
    for (int half = 0; half < 2; ++half) {
#pragma unroll
        for (int jj = 0; jj < 8; ++jj) {
            int j = tid + jj * 256;
            int r = j >> 4, c = j & 15;
            s16x8 wv = *reinterpret_cast<const s16x8*>(
                w1ab0 + (size_t)(half * 128 + r) * 128 + c * 8);
            *reinterpret_cast<s16x8*>(&Ws[r * 128 + ((c ^ (r & 7)) << 3)]) = wv;
        }
        light_barrier();
#pragma unroll
        for (int ni = 0; ni < 8; ++ni) {
            f32x4 z = { 0.f, 0.f, 0.f, 0.f };
            acc[ni] = z;
        }
#pragma unroll
        for (int ks = 0; ks < 4; ++ks) {
            int c = ks * 4 + lg;
            int r = wid * 16 + lr;
            s16x8 af = *reinterpret_cast<s16x8*>(&As[r * 128 + ((c ^ (r & 7)) << 3)]);
#pragma unroll
            for (int ni = 0; ni < 8; ++ni) {
                int n = ni * 16 + lr;
                s16x8 bf = *reinterpret_cast<s16x8*>(&Ws[n * 128 + ((c ^ (n & 7)) << 3)]);
                acc[ni] = __builtin_amdgcn_mfma_f32_16x16x32_bf16(af, bf, acc[ni], 0, 0, 0);
            }
        }
#pragma unroll
        for (int ni = 0; ni < 8; ++ni) {
            int col = ni * 16 + lr;
            float bs = half ? eb1_0[col] : 0.f;
#pragma unroll
            for (int r4 = 0; r4 < 4; ++r4) {
                int rowg = row0 + wid * 16 + lg * 4 + r4;
                int orow = (rowg & 511) * 64 + (rowg >> 9);
                ab_out[(size_t)orow * 256 + half * 128 + col] =
                    f2bf(acc[ni][r4] + bs);
            }
        }
        if (half == 0) light_barrier();
    }
}

// ---------------- fused node MLP + next LN + next-layer [A|B] ------------
// Residual read from hnbf (bf16); hnbf updated IN PLACE (per-element same
// thread reads resid then writes; each wave touches only its own 16 rows).
__global__ __launch_bounds__(256) void nmlp_ln(
    unsigned short* __restrict__ hnbf,
    const unsigned short* __restrict__ magbf,
    const unsigned short* __restrict__ w1, const float* __restrict__ b1,
    const unsigned short* __restrict__ w2, const float* __restrict__ b2,
    const float* __restrict__ g, const float* __restrict__ bet,
    unsigned short* __restrict__ hbf_out,
    const unsigned short* __restrict__ w1ab_next,
    const float* __restrict__ eb1_next,
    unsigned short* __restrict__ ab_out) {
    __shared__ __align__(16) unsigned short As[64 * 128];
    __shared__ __align__(16) unsigned short Ws[128 * 128];
    int tid = threadIdx.x;
    int wid = tid >> 6, l = tid & 63, lr = l & 15, lg = l >> 4;
    int row0 = blockIdx.x * 64;
    int myrow = row0 + wid * 16 + lr;
    f32x4 acc[8];
#pragma unroll
    for (int ni = 0; ni < 8; ++ni) {
        f32x4 z = { 0.f, 0.f, 0.f, 0.f };
        acc[ni] = z;
    }
    // stage 1: K=256 over [hn | mag], A streamed from global
    for (int kc = 0; kc < 2; ++kc) {
        const unsigned short* Xsrc = kc ? magbf : hnbf;
#pragma unroll
        for (int jj = 0; jj < 8; ++jj) {
            int j = tid + jj * 256;
            int r = j >> 4, c = j & 15;
            s16x8 wv = *reinterpret_cast<const s16x8*>(
                w1 + (size_t)r * 256 + kc * 128 + c * 8);
            *reinterpret_cast<s16x8*>(&Ws[r * 128 + ((c ^ (r & 7)) << 3)]) = wv;
        }
        light_barrier();
#pragma unroll
        for (int ks = 0; ks < 4; ++ks) {
            s16x8 af = *reinterpret_cast<const s16x8*>(
                Xsrc + (size_t)myrow * 128 + ks * 32 + lg * 8);
#pragma unroll
            for (int ni = 0; ni < 8; ++ni) {
                int n = ni * 16 + lr;
                int c = ks * 4 + lg;
                s16x8 bf = *reinterpret_cast<s16x8*>(&Ws[n * 128 + ((c ^ (n & 7)) << 3)]);
                acc[ni] = __builtin_amdgcn_mfma_f32_16x16x32_bf16(af, bf, acc[ni], 0, 0, 0);
            }
        }
        light_barrier();
    }
    // t = silu(acc + b1) -> As (own rows, swizzled)
#pragma unroll
    for (int ni = 0; ni < 8; ++ni) {
        int col = ni * 16 + lr;
        float bs = b1[col];
        int cc = col >> 3, cin = col & 7;
#pragma unroll
        for (int r4 = 0; r4 < 4; ++r4) {
            int rl = wid * 16 + lg * 4 + r4;
            As[rl * 128 + ((cc ^ (rl & 7)) << 3) + cin] =
                f2bf(silu_f(acc[ni][r4] + bs));
            acc[ni][r4] = 0.f;
        }
    }
#pragma unroll
    for (int jj = 0; jj < 8; ++jj) {
        int j = tid + jj * 256;
        int r = j >> 4, c = j & 15;
        s16x8 wv = *reinterpret_cast<const s16x8*>(w2 + (size_t)r * 128 + c * 8);
        *reinterpret_cast<s16x8*>(&Ws[r * 128 + ((c ^ (r & 7)) << 3)]) = wv;
    }
    light_barrier();
    // stage 2: t @ W2^T
#pragma unroll
    for (int ks = 0; ks < 4; ++ks) {
        int c = ks * 4 + lg;
        int r = wid * 16 + lr;
        s16x8 af = *reinterpret_cast<s16x8*>(&As[r * 128 + ((c ^ (r & 7)) << 3)]);
#pragma unroll
        for (int ni = 0; ni < 8; ++ni) {
            int n = ni * 16 + lr;
            s16x8 bf = *reinterpret_cast<s16x8*>(&Ws[n * 128 + ((c ^ (n & 7)) << 3)]);
            acc[ni] = __builtin_amdgcn_mfma_f32_16x16x32_bf16(af, bf, acc[ni], 0, 0, 0);
        }
    }
    // h = acc + b2 + resid(bf16 hn)
#pragma unroll
    for (int ni = 0; ni < 8; ++ni) {
        int col = ni * 16 + lr;
        float bs = b2[col];
#pragma unroll
        for (int r4 = 0; r4 < 4; ++r4) {
            int rowg = row0 + wid * 16 + lg * 4 + r4;
            acc[ni][r4] += bs + bf2f(hnbf[(size_t)rowg * HIDDEN + col]);
        }
    }
    if (!g) {
#pragma unroll
        for (int ni = 0; ni < 8; ++ni) {
            int col = ni * 16 + lr;
#pragma unroll
            for (int r4 = 0; r4 < 4; ++r4) {
                int rowg = row0 + wid * 16 + lg * 4 + r4;
                hbf_out[(size_t)rowg * HIDDEN + col] = f2bf(acc[ni][r4]);
            }
        }
        return;
    }
    // LN
    float s[4], q[4];
#pragma unroll
    for (int r4 = 0; r4 < 4; ++r4) {
        float ss = 0.f, qq = 0.f;
#pragma unroll
        for (int ni = 0; ni < 8; ++ni) {
            float v = acc[ni][r4];
            ss += v; qq += v * v;
        }
#pragma unroll
        for (int o = 1; o < 16; o <<= 1) {
            ss += __shfl_xor(ss, o, 64);
            qq += __shfl_xor(qq, o, 64);
        }
        float mu = ss * (1.f / 128.f);
        float var = qq * (1.f / 128.f) - mu * mu;
        s[r4] = mu;
        q[r4] = rsqrtf(var + 1e-5f);
    }
#pragma unroll
    for (int ni = 0; ni < 8; ++ni) {
        int col = ni * 16 + lr;
        float gg = g[col], bb = bet[col];
        int cc = col >> 3, cin = col & 7;
#pragma unroll
        for (int r4 = 0; r4 < 4; ++r4) {
            int rowg = row0 + wid * 16 + lg * 4 + r4;
            float o = (acc[ni][r4] - s[r4]) * q[r4] * gg + bb;
            hnbf[(size_t)rowg * HIDDEN + col] = f2bf(o);   // in-place update
            int rl = wid * 16 + lg * 4 + r4;
            As[rl * 128 + ((cc ^ (rl & 7)) << 3) + cin] = f2bf(o);
        }
    }
    light_barrier();    // all waves done reading Ws (stage 2)
#pragma unroll
    for (int half = 0; half < 2; ++half) {
#pragma unroll
        for (int jj = 0; jj < 8; ++jj) {
            int j = tid + jj * 256;
            int r = j >> 4, c = j & 15;
            s16x8 wv = *reinterpret_cast<const s16x8*>(
                w1ab_next + (size_t)(half * 128 + r) * 128 + c * 8);
            *reinterpret_cast<s16x8*>(&Ws[r * 128 + ((c ^ (r & 7)) << 3)]) = wv;
        }
        light_barrier();
#pragma unroll
        for (int ni = 0; ni < 8; ++ni) {
            f32x4 z = { 0.f, 0.f, 0.f, 0.f };
            acc[ni] = z;
        }
#pragma unroll
        for (int ks = 0; ks < 4; ++ks) {
            int c = ks * 4 + lg;
            int r = wid * 16 + lr;
            s16x8 af = *reinterpret_cast<s16x8*>(&As[r * 128 + ((c ^ (r & 7)) << 3)]);
#pragma unroll
            for (int ni = 0; ni < 8; ++ni) {
                int n = ni * 16 + lr;
                s16x8 bf = *reinterpret_cast<s16x8*>(&Ws[n * 128 + ((c ^ (n & 7)) << 3)]);
                acc[ni] = __builtin_amdgcn_mfma_f32_16x16x32_bf16(af, bf, acc[ni], 0, 0, 0);
            }
        }
#pragma unroll
        for (int ni = 0; ni < 8; ++ni) {
            int col = ni * 16 + lr;
            float bs = half ? eb1_next[col] : 0.f;
#pragma unroll
            for (int r4 = 0; r4 < 4; ++r4) {
                int rowg = row0 + wid * 16 + lg * 4 + r4;
                ab_out[(size_t)rowg * 256 + half * 128 + col] =
                    f2bf(acc[ni][r4] + bs);
            }
        }
        if (half == 0) light_barrier();
    }
}

// ---------------- edge MLP v8: 2 edges per barrier, 4 LDS buffers ---------
__global__ __launch_bounds__(256, 4) void edge_mfma8(
    const unsigned short* __restrict__ ABbf,
    const int* __restrict__ bcol,
    const int* __restrict__ brp,
    const unsigned short* __restrict__ w2bf,
    const float* __restrict__ c01,
    const float* __restrict__ eb2l,
    unsigned short* __restrict__ magbf) {
    __shared__ __align__(16) unsigned short m1[4][16 * 128];
    int tid = threadIdx.x;
    int blk = blockIdx.x;
    int i = blk >> 2, qtr = blk & 3;
    int wid = tid >> 6, l = tid & 63, lr = l & 15, lg = l >> 4;
    int rowb = qtr * 16;
    int col0 = wid * 32;

    s16x8 wfr[4][2];
#pragma unroll
    for (int ks = 0; ks < 4; ++ks)
#pragma unroll
        for (int ni = 0; ni < 2; ++ni) {
            int n = col0 + ni * 16 + lr;
            wfr[ks][ni] = *reinterpret_cast<const s16x8*>(
                w2bf + (size_t)n * 128 + (ks * 4 + lg) * 8);
        }

    int s = brp[i], e = brp[i + 1];
    int br = tid >> 4, bc = tid & 15;
    s16x8 Bp[2];
    {
        union { s16x8 s; unsigned int w[4]; } bv;
        bv.s = *reinterpret_cast<const s16x8*>(
            ABbf + ((size_t)i * NB + rowb + br) * 256 + 128 + bc * 8);
#pragma unroll
        for (int cls = 0; cls < 2; ++cls) {
            const float* cp = c01 + cls * 128 + bc * 8;
            float4 ca = *reinterpret_cast<const float4*>(cp);
            float4 cb = *reinterpret_cast<const float4*>(cp + 4);
            union { s16x8 s; unsigned int w[4]; } pk;
            pk.w[0] = cvt_pk_bf16(__uint_as_float(bv.w[0] << 16) + ca.x,
                                  __uint_as_float(bv.w[0] & 0xffff0000u) + ca.y);
            pk.w[1] = cvt_pk_bf16(__uint_as_float(bv.w[1] << 16) + ca.z,
                                  __uint_as_float(bv.w[1] & 0xffff0000u) + ca.w);
            pk.w[2] = cvt_pk_bf16(__uint_as_float(bv.w[2] << 16) + cb.x,
                                  __uint_as_float(bv.w[2] & 0xffff0000u) + cb.y);
            pk.w[3] = cvt_pk_bf16(__uint_as_float(bv.w[3] << 16) + cb.z,
                                  __uint_as_float(bv.w[3] & 0xffff0000u) + cb.w);
            Bp[cls] = pk.s;
        }
    }
    float e2[2], se[2];
#pragma unroll
    for (int ni = 0; ni < 2; ++ni) {
        e2[ni] = eb2l[col0 + ni * 16 + lr];
        se[ni] = silu_f(e2[ni]);
    }
    f32x4 agg[2];
#pragma unroll
    for (int ni = 0; ni < 2; ++ni) {
        f32x4 z = { 0.f, 0.f, 0.f, 0.f };
        agg[ni] = z;
    }

    auto loadA = [&](int t, int& pk) -> s16x8 {
        pk = __builtin_amdgcn_readfirstlane(bcol[t]);
        return *reinterpret_cast<const s16x8*>(
            ABbf + ((size_t)(pk & 0x7fff) * NB + rowb + br) * 256 + bc * 8);
    };
    auto build = [&](s16x8 A, int cls, int buf) {
        union { s16x8 s; unsigned int w[4]; } av, bv2, pkv;
        av.s = A;
        bv2.s = cls ? Bp[1] : Bp[0];
#pragma unroll
        for (int q = 0; q < 4; ++q) {
            float a0 = __uint_as_float(av.w[q] << 16);
            float a1 = __uint_as_float(av.w[q] & 0xffff0000u);
            float b0 = __uint_as_float(bv2.w[q] << 16);
            float b1 = __uint_as_float(bv2.w[q] & 0xffff0000u);
            pkv.w[q] = cvt_pk_bf16(silu_f(a0 + b0), silu_f(a1 + b1));
        }
        *reinterpret_cast<s16x8*>(
            &m1[buf][br * 128 + ((bc ^ (br & 7)) << 3)]) = pkv.s;
    };
    auto mfma_epi = [&](int buf) {
        f32x4 acc[2];
#pragma unroll
        for (int ni = 0; ni < 2; ++ni) {
            f32x4 iv = { e2[ni], e2[ni], e2[ni], e2[ni] };
            acc[ni] = iv;
        }
#pragma unroll
        for (int ks = 0; ks < 4; ++ks) {
            int cc = ks * 4 + lg;
            s16x8 af = *reinterpret_cast<s16x8*>(
                &m1[buf][lr * 128 + ((cc ^ (lr & 7)) << 3)]);
            acc[0] = __builtin_amdgcn_mfma_f32_16x16x32_bf16(af, wfr[ks][0], acc[0], 0, 0, 0);
            acc[1] = __builtin_amdgcn_mfma_f32_16x16x32_bf16(af, wfr[ks][1], acc[1], 0, 0, 0);
        }
#pragma unroll
        for (int ni = 0; ni < 2; ++ni)
#pragma unroll
            for (int r4 = 0; r4 < 4; ++r4)
                agg[ni][r4] += silu_f(acc[ni][r4]) - se[ni];
    };

    int pk0, pk1;
    s16x8 A0 = loadA(s, pk0);
    s16x8 A1 = A0;
    pk1 = pk0;
    if (s + 1 < e) A1 = loadA(s + 1, pk1);

    for (int t = s; t < e; t += 2) {
        int pb = (((t - s) >> 1) & 1) << 1;     // 0 or 2
        bool has2 = (t + 1) < e;
        int pk2 = pk0, pk3 = pk1;
        s16x8 A2 = A0, A3 = A1;
        if (t + 2 < e) A2 = loadA(t + 2, pk2);
        if (t + 3 < e) A3 = loadA(t + 3, pk3);
        build(A0, (pk0 >> 15) & 1, pb);
        if (has2) build(A1, (pk1 >> 15) & 1, pb + 1);
        light_barrier();
        mfma_epi(pb);
        if (has2) mfma_epi(pb + 1);
        pk0 = pk2; A0 = A2; pk1 = pk3; A1 = A3;
    }

    float inv = (e > s) ? 1.f / (float)(e - s) : 0.f;
#pragma unroll
    for (int ni = 0; ni < 2; ++ni) {
#pragma unroll
        for (int r4 = 0; r4 < 4; ++r4) {
            size_t rowg = (size_t)i * NB + rowb + lg * 4 + r4;
            magbf[rowg * 128 + col0 + ni * 16 + lr] =
                f2bf(agg[ni][r4] * inv + se[ni]);
        }
    }
}

extern "C" void kernel_launch(void* const* d_in, const int* in_sizes, int n_in,
                              void* d_out, int out_size, void* d_ws, size_t ws_size,
                              hipStream_t stream) {
    const float* y     = (const float*)d_in[0];
    const float* gc    = (const float*)d_in[1];
    const int*   eidx  = (const int*)d_in[2];
    const float* W_in  = (const float*)d_in[3];
    const float* b_in  = (const float*)d_in[4];
    const float* gam   = (const float*)d_in[5];
    const float* bet   = (const float*)d_in[6];
    const float* eW1   = (const float*)d_in[7];
    const float* eb1   = (const float*)d_in[8];
    const float* eW2   = (const float*)d_in[9];
    const float* eb2   = (const float*)d_in[10];
    const float* nW1   = (const float*)d_in[11];
    const float* nb1   = (const float*)d_in[12];
    const float* nW2   = (const float*)d_in[13];
    const float* nb2   = (const float*)d_in[14];
    const float* W_out = (const float*)d_in[15];
    const float* b_out = (const float*)d_in[16];

    const int M = in_sizes[0] / CODE;       // 32768 (= NBASE * NB)
    const int E = in_sizes[2] / 2;
    const int baseE = E / NB;

    float* out = (float*)d_out;

    char* ws = (char*)d_ws;
    size_t off = 0;
    auto carve = [&](size_t bytes) {
        char* p = ws + off;
        off += (bytes + 255) & ~(size_t)255;
        return p;
    };
    unsigned short* hnbf    = (unsigned short*)carve((size_t)M * HIDDEN * 2);
    unsigned short* ABbf    = (unsigned short*)carve((size_t)M * 256 * 2);
    unsigned short* magbf   = (unsigned short*)carve((size_t)M * HIDDEN * 2);
    unsigned short* hbf     = (unsigned short*)carve((size_t)M * HIDDEN * 2);
    int*            brp     = (int*)carve((size_t)(NBASE + 1) * 4);
    int*            bcol    = (int*)carve((size_t)baseE * 4);
    unsigned short* winbf   = (unsigned short*)carve((size_t)HIDDEN * CODE * 2);
    unsigned short* woutbf  = (unsigned short*)carve((size_t)CODE * HIDDEN * 2);
    unsigned short* wn1bf   = (unsigned short*)carve((size_t)NLAYERS * HIDDEN * 256 * 2);
    unsigned short* wn2bf   = (unsigned short*)carve((size_t)NLAYERS * HIDDEN * HIDDEN * 2);
    unsigned short* w2bf    = (unsigned short*)carve((size_t)NLAYERS * HIDDEN * HIDDEN * 2);
    unsigned short* w1ab    = (unsigned short*)carve((size_t)NLAYERS * 256 * HIDDEN * 2);
    float*          c01     = (float*)carve((size_t)NLAYERS * 256 * 4);

    const int* row  = eidx;
    const int* colA = eidx + E;

    int prep_blocks = 519 + (baseE + 255) / 256;
    prep_all<<<dim3(prep_blocks), 256, 0, stream>>>(
        W_in, W_out, nW1, nW2, eW2, eW1, eb1, row, colA, gc,
        winbf, woutbf, wn1bf, wn2bf, w2bf, w1ab, c01,
        brp, bcol, baseE);

    // h0 = y @ W_in^T + b_in ; hn0 = LN0 ; layer-0 [A|B] (all fused)
    inproj_ln<<<dim3(M / 64), 256, 0, stream>>>(
        y, winbf, b_in, gam, bet, hnbf, w1ab, eb1, ABbf);

    for (int l = 0; l < NLAYERS; ++l) {
        edge_mfma8<<<dim3(NBASE * 4), 256, 0, stream>>>(
            ABbf, bcol, brp,
            w2bf + (size_t)l * HIDDEN * HIDDEN, c01 + (size_t)l * 256,
            eb2 + (size_t)l * HIDDEN, magbf);

        bool last = (l == NLAYERS - 1);
        nmlp_ln<<<dim3(M / 64), 256, 0, stream>>>(
            hnbf, magbf,
            wn1bf + (size_t)l * HIDDEN * 256, nb1 + (size_t)l * HIDDEN,
            wn2bf + (size_t)l * HIDDEN * HIDDEN, nb2 + (size_t)l * HIDDEN,
            last ? nullptr : gam + (size_t)(l + 1) * HIDDEN,
            last ? nullptr : bet + (size_t)(l + 1) * HIDDEN,
            hbf,
            last ? nullptr : w1ab + (size_t)(l + 1) * 256 * HIDDEN,
            last ? nullptr : eb1 + (size_t)(l + 1) * HIDDEN,
            last ? nullptr : ABbf);
    }

    // out = h @ W_out^T + b_out ; contiguous output rows, A gathered
    mgemm64<<<dim3(M / 64, CODE / 128), 256, 0, stream>>>(
        hbf, HIDDEN, woutbf, b_out, out, nullptr, CODE, 3);
}

// Round 17
// 399.681 us; speedup vs baseline: 1.3895x; 1.0031x over previous
//
#include <hip/hip_runtime.h>
#include <math.h>

// GNN denoiser: N=32768 (=512 base x 64 batch), HID=128, L=4.
// Base-major node layout. Edge MLP v9: 4 edges per light barrier, 8 LDS
// buffers (quad rotation), W2 in regs, 4-deep A prefetch. Node MLP streams
// stage-1 A from global; bf16 residual in place. In-proj fuses LN0 +
// layer-0 [A|B]. Out-proj gathers A rows (streaming writes).

#define HIDDEN 128
#define NLAYERS 4
#define NBASE 512
#define NB 64
#define CODE 1024

typedef __attribute__((ext_vector_type(8))) short s16x8;
typedef __attribute__((ext_vector_type(4))) float f32x4;

__device__ __forceinline__ unsigned int cvt_pk_bf16(float lo, float hi) {
    unsigned int d;
    asm("v_cvt_pk_bf16_f32 %0, %1, %2" : "=v"(d) : "v"(lo), "v"(hi));
    return d;
}
__device__ __forceinline__ unsigned short f2bf(float x) {
    return (unsigned short)cvt_pk_bf16(x, x);
}
__device__ __forceinline__ float bf2f(unsigned short b) {
    return __uint_as_float(((unsigned int)b) << 16);
}
__device__ __forceinline__ float silu_f(float x) {
    float e = __expf(-x);
    float r;
    asm("v_rcp_f32 %0, %1" : "=v"(r) : "v"(1.f + e));
    return x * r;
}
// Barrier that does NOT drain vmcnt: LDS ops are lgkmcnt-tracked, so
// lgkmcnt(0)+s_barrier makes all ds_writes visible; in-flight global
// prefetches keep flying (compiler waits vmcnt at first use).
__device__ __forceinline__ void light_barrier() {
    __builtin_amdgcn_sched_barrier(0);
    asm volatile("s_waitcnt lgkmcnt(0)" ::: "memory");
    __builtin_amdgcn_s_barrier();
    __builtin_amdgcn_sched_barrier(0);
}

// ---------------- fused prep ----------------
__device__ __forceinline__ void conv_body(
    const float* __restrict__ s, unsigned short* __restrict__ d,
    int blk, int tid, int n) {
    int i = (blk * 256 + tid) * 4;
    if (i >= n) return;
    float4 v = *reinterpret_cast<const float4*>(s + i);
    uint2 o = { cvt_pk_bf16(v.x, v.y), cvt_pk_bf16(v.z, v.w) };
    *reinterpret_cast<uint2*>(d + i) = o;
}

__global__ __launch_bounds__(256) void prep_all(
    const float* __restrict__ W_in, const float* __restrict__ W_out,
    const float* __restrict__ nW1, const float* __restrict__ nW2,
    const float* __restrict__ eW2, const float* __restrict__ eW1,
    const float* __restrict__ eb1,
    const int* __restrict__ row, const int* __restrict__ col,
    const float* __restrict__ gc,
    unsigned short* __restrict__ winbf, unsigned short* __restrict__ woutbf,
    unsigned short* __restrict__ wn1bf, unsigned short* __restrict__ wn2bf,
    unsigned short* __restrict__ w2bf, unsigned short* __restrict__ w1ab,
    float* __restrict__ c01,
    int* __restrict__ brp, int* __restrict__ bcol, int baseE) {
    int blk = blockIdx.x, tid = threadIdx.x;
    if (blk < 128)      { conv_body(W_in,  winbf,  blk,       tid, HIDDEN * CODE); return; }
    if (blk < 256)      { conv_body(W_out, woutbf, blk - 128, tid, CODE * HIDDEN); return; }
    if (blk < 384)      { conv_body(nW1,   wn1bf,  blk - 256, tid, NLAYERS * HIDDEN * 256); return; }
    if (blk < 448)      { conv_body(nW2,   wn2bf,  blk - 384, tid, NLAYERS * HIDDEN * HIDDEN); return; }
    if (blk < 512)      { conv_body(eW2,   w2bf,   blk - 448, tid, NLAYERS * HIDDEN * HIDDEN); return; }
    if (blk < 516) {    // per-layer pack
        int l = blk - 512;
        const float* w = eW1 + (size_t)l * HIDDEN * 257;
        for (int i = tid; i < 256 * 128; i += 256) {
            int n = i >> 7, k = i & 127;
            float v = (n < 128) ? w[(size_t)n * 257 + k]
                                : w[(size_t)(n - 128) * 257 + 128 + k];
            w1ab[(size_t)l * 256 * 128 + i] = f2bf(v);
        }
        if (tid < 128) {
            float wd = w[(size_t)tid * 257 + 256];
            c01[(size_t)l * 256 + tid] = 2.f * wd;
            c01[(size_t)l * 256 + 128 + tid] = sqrtf(8.f) * wd;
        }
        return;
    }
    if (blk < 519) {    // rowptr over base graph
        int v = (blk - 516) * 256 + tid;
        if (v > NBASE) return;
        int lo = 0, hi = baseE;
        while (lo < hi) {
            int mid = (lo + hi) >> 1;
            if (row[mid] < v) lo = mid + 1; else hi = mid;
        }
        brp[v] = lo;
        return;
    }
    {   // basecol: packed cls<<15 | j
        int t = (blk - 519) * 256 + tid;
        if (t >= baseE) return;
        int u = col[t], v = row[t];
        float dx = gc[(size_t)u * 3 + 0] - gc[(size_t)v * 3 + 0];
        float dy = gc[(size_t)u * 3 + 1] - gc[(size_t)v * 3 + 1];
        float dz = gc[(size_t)u * 3 + 2] - gc[(size_t)v * 3 + 2];
        float d2 = dx * dx + dy * dy + dz * dz;
        bcol[t] = u | ((d2 > 6.f ? 1 : 0) << 15);
    }
}

// ---------------- generic bf16 MFMA GEMM, BM=64 (out-proj) ----------------
__global__ __launch_bounds__(256) void mgemm64(
    const unsigned short* __restrict__ A, int K,
    const unsigned short* __restrict__ W,
    const float* __restrict__ bias,
    float* __restrict__ Cf, unsigned short* __restrict__ Cb, int ldC, int perm) {
    __shared__ __align__(16) unsigned short As[64 * 128];
    __shared__ __align__(16) unsigned short Ws[128 * 128];
    int tid = threadIdx.x;
    int wid = tid >> 6, l = tid & 63, lr = l & 15, lg = l >> 4;
    int wm = wid >> 1, wn = wid & 1;
    int row0 = blockIdx.x * 64;
    int cb = blockIdx.y * 128;
    f32x4 acc[2][4];
#pragma unroll
    for (int i = 0; i < 2; ++i)
#pragma unroll
        for (int j = 0; j < 4; ++j) {
            f32x4 z = { 0.f, 0.f, 0.f, 0.f };
            acc[i][j] = z;
        }
    for (int kc = 0; kc < K; kc += 128) {
#pragma unroll
        for (int jj = 0; jj < 4; ++jj) {
            int j = tid + jj * 256;
            int r = j >> 4, c = j & 15;
            int srow = row0 + r;
            if (perm == 3) srow = ((srow & 511) << 6) | (srow >> 9);
            s16x8 v = *reinterpret_cast<const s16x8*>(
                A + (size_t)srow * K + kc + c * 8);
            *reinterpret_cast<s16x8*>(&As[r * 128 + ((c ^ (r & 7)) << 3)]) = v;
        }
#pragma unroll
        for (int jj = 0; jj < 8; ++jj) {
            int j = tid + jj * 256;
            int r = j >> 4, c = j & 15;
            s16x8 wv = *reinterpret_cast<const s16x8*>(
                W + (size_t)(cb + r) * K + kc + c * 8);
            *reinterpret_cast<s16x8*>(&Ws[r * 128 + ((c ^ (r & 7)) << 3)]) = wv;
        }
        light_barrier();
#pragma unroll
        for (int ks = 0; ks < 4; ++ks) {
            int c = ks * 4 + lg;
            s16x8 af[2], bf[4];
#pragma unroll
            for (int mi = 0; mi < 2; ++mi) {
                int r = wm * 32 + mi * 16 + lr;
                af[mi] = *reinterpret_cast<s16x8*>(&As[r * 128 + ((c ^ (r & 7)) << 3)]);
            }
#pragma unroll
            for (int ni = 0; ni < 4; ++ni) {
                int n = wn * 64 + ni * 16 + lr;
                bf[ni] = *reinterpret_cast<s16x8*>(&Ws[n * 128 + ((c ^ (n & 7)) << 3)]);
            }
#pragma unroll
            for (int mi = 0; mi < 2; ++mi)
#pragma unroll
                for (int ni = 0; ni < 4; ++ni)
                    acc[mi][ni] = __builtin_amdgcn_mfma_f32_16x16x32_bf16(
                        af[mi], bf[ni], acc[mi][ni], 0, 0, 0);
        }
        light_barrier();
    }
#pragma unroll
    for (int mi = 0; mi < 2; ++mi) {
#pragma unroll
        for (int ni = 0; ni < 4; ++ni) {
            int colg = cb + wn * 64 + ni * 16 + lr;
            float bs = bias ? bias[colg] : 0.f;
#pragma unroll
            for (int r4 = 0; r4 < 4; ++r4) {
                int rowg = row0 + wm * 32 + mi * 16 + lg * 4 + r4;
                float v = acc[mi][ni][r4] + bs;
                if (Cf) Cf[(size_t)rowg * ldC + colg] = v;
                if (Cb) Cb[(size_t)rowg * ldC + colg] = f2bf(v);
            }
        }
    }
}

// ---------------- in-projection + LN0 + layer-0 [A|B] ------------
__global__ __launch_bounds__(256) void inproj_ln(
    const float* __restrict__ y,
    const unsigned short* __restrict__ W, const float* __restrict__ bias,
    const float* __restrict__ g, const float* __restrict__ bet,
    unsigned short* __restrict__ hnbf,
    const unsigned short* __restrict__ w1ab0,
    const float* __restrict__ eb1_0,
    unsigned short* __restrict__ ab_out) {
    __shared__ __align__(16) unsigned short As[64 * 128];
    __shared__ __align__(16) unsigned short Ws[128 * 128];
    int tid = threadIdx.x;
    int wid = tid >> 6, l = tid & 63, lr = l & 15, lg = l >> 4;
    int row0 = blockIdx.x * 64;
    f32x4 acc[8];
#pragma unroll
    for (int ni = 0; ni < 8; ++ni) {
        f32x4 z = { 0.f, 0.f, 0.f, 0.f };
        acc[ni] = z;
    }
    float4 pa0[4], pa1[4];
    s16x8 pw[8];
    auto loadc = [&](int kc) {
#pragma unroll
        for (int jj = 0; jj < 4; ++jj) {
            int j = tid + jj * 256, r = j >> 4, c = j & 15;
            const float* p = y + (size_t)(row0 + r) * CODE + kc + c * 8;
            pa0[jj] = *reinterpret_cast<const float4*>(p);
            pa1[jj] = *reinterpret_cast<const float4*>(p + 4);
        }
#pragma unroll
        for (int jj = 0; jj < 8; ++jj) {
            int j = tid + jj * 256, r = j >> 4, c = j & 15;
            pw[jj] = *reinterpret_cast<const s16x8*>(W + (size_t)r * CODE + kc + c * 8);
        }
    };
    auto storec = [&]() {
#pragma unroll
        for (int jj = 0; jj < 4; ++jj) {
            int j = tid + jj * 256, r = j >> 4, c = j & 15;
            union { s16x8 s; unsigned int w[4]; } pk;
            pk.w[0] = cvt_pk_bf16(pa0[jj].x, pa0[jj].y);
            pk.w[1] = cvt_pk_bf16(pa0[jj].z, pa0[jj].w);
            pk.w[2] = cvt_pk_bf16(pa1[jj].x, pa1[jj].y);
            pk.w[3] = cvt_pk_bf16(pa1[jj].z, pa1[jj].w);
            *reinterpret_cast<s16x8*>(&As[r * 128 + ((c ^ (r & 7)) << 3)]) = pk.s;
        }
#pragma unroll
        for (int jj = 0; jj < 8; ++jj) {
            int j = tid + jj * 256, r = j >> 4, c = j & 15;
            *reinterpret_cast<s16x8*>(&Ws[r * 128 + ((c ^ (r & 7)) << 3)]) = pw[jj];
        }
    };
    loadc(0);
    for (int kc8 = 0; kc8 < 8; ++kc8) {
        storec();
        light_barrier();
        if (kc8 < 7) loadc((kc8 + 1) * 128);
#pragma unroll
        for (int ks = 0; ks < 4; ++ks) {
            int c = ks * 4 + lg;
            int r = wid * 16 + lr;
            s16x8 af = *reinterpret_cast<s16x8*>(&As[r * 128 + ((c ^ (r & 7)) << 3)]);
#pragma unroll
            for (int ni = 0; ni < 8; ++ni) {
                int n = ni * 16 + lr;
                s16x8 bf = *reinterpret_cast<s16x8*>(&Ws[n * 128 + ((c ^ (n & 7)) << 3)]);
                acc[ni] = __builtin_amdgcn_mfma_f32_16x16x32_bf16(af, bf, acc[ni], 0, 0, 0);
            }
        }
        light_barrier();
    }
#pragma unroll
    for (int ni = 0; ni < 8; ++ni) {
        float bs = bias[ni * 16 + lr];
#pragma unroll
        for (int r4 = 0; r4 < 4; ++r4) acc[ni][r4] += bs;
    }
    float s[4], q[4];
#pragma unroll
    for (int r4 = 0; r4 < 4; ++r4) {
        float ss = 0.f, qq = 0.f;
#pragma unroll
        for (int ni = 0; ni < 8; ++ni) {
            float v = acc[ni][r4];
            ss += v; qq += v * v;
        }
#pragma unroll
        for (int o = 1; o < 16; o <<= 1) {
            ss += __shfl_xor(ss, o, 64);
            qq += __shfl_xor(qq, o, 64);
        }
        float mu = ss * (1.f / 128.f);
        float var = qq * (1.f / 128.f) - mu * mu;
        s[r4] = mu;
        q[r4] = rsqrtf(var + 1e-5f);
    }
#pragma unroll
    for (int ni = 0; ni < 8; ++ni) {
        int col = ni * 16 + lr;
        float gg = g[col], bb = bet[col];
        int cc = col >> 3, cin = col & 7;
#pragma unroll
        for (int r4 = 0; r4 < 4; ++r4) {
            int rowg = row0 + wid * 16 + lg * 4 + r4;
            int orow = (rowg & 511) * 64 + (rowg >> 9);
            float o = (acc[ni][r4] - s[r4]) * q[r4] * gg + bb;
            hnbf[(size_t)orow * HIDDEN + col] = f2bf(o);
            int rl = wid * 16 + lg * 4 + r4;
            As[rl * 128 + ((cc ^ (rl & 7)) << 3) + cin] = f2bf(o);
        }
    }
    // layer-0 [A|B]: two W halves
#pragma unroll
    for (int half = 0; half < 2; ++half) {
#pragma unroll
        for (int jj = 0; jj < 8; ++jj) {
            int j = tid + jj * 256;
            int r = j >> 4, c = j & 15;
            s16x8 wv = *reinterpret_cast<const s16x8*>(
                w1ab0 + (size_t)(half * 128 + r) * 128 + c * 8);
            *reinterpret_cast<s16x8*>(&Ws[r * 128 + ((c ^ (r & 7)) << 3)]) = wv;
        }
        light_barrier();
#pragma unroll
        for (int ni = 0; ni < 8; ++ni) {
            f32x4 z = { 0.f, 0.f, 0.f, 0.f };
            acc[ni] = z;
        }
#pragma unroll
        for (int ks = 0; ks < 4; ++ks) {
            int c = ks * 4 + lg;
            int r = wid * 16 + lr;
            s16x8 af = *reinterpret_cast<s16x8*>(&As[r * 128 + ((c ^ (r & 7)) << 3)]);
#pragma unroll
            for (int ni = 0; ni < 8; ++ni) {
                int n = ni * 16 + lr;
                s16x8 bf = *reinterpret_cast<s16x8*>(&Ws[n * 128 + ((c ^ (n & 7)) << 3)]);
                acc[ni] = __builtin_amdgcn_mfma_f32_16x16x32_bf16(af, bf, acc[ni], 0, 0, 0);
            }
        }
#pragma unroll
        for (int ni = 0; ni < 8; ++ni) {
            int col = ni * 16 + lr;
            float bs = half ? eb1_0[col] : 0.f;
#pragma unroll
            for (int r4 = 0; r4 < 4; ++r4) {
                int rowg = row0 + wid * 16 + lg * 4 + r4;
                int orow = (rowg & 511) * 64 + (rowg >> 9);
                ab_out[(size_t)orow * 256 + half * 128 + col] =
                    f2bf(acc[ni][r4] + bs);
            }
        }
        if (half == 0) light_barrier();
    }
}

// ---------------- fused node MLP + next LN + next-layer [A|B] ------------
__global__ __launch_bounds__(256) void nmlp_ln(
    unsigned short* __restrict__ hnbf,
    const unsigned short* __restrict__ magbf,
    const unsigned short* __restrict__ w1, const float* __restrict__ b1,
    const unsigned short* __restrict__ w2, const float* __restrict__ b2,
    const float* __restrict__ g, const float* __restrict__ bet,
    unsigned short* __restrict__ hbf_out,
    const unsigned short* __restrict__ w1ab_next,
    const float* __restrict__ eb1_next,
    unsigned short* __restrict__ ab_out) {
    __shared__ __align__(16) unsigned short As[64 * 128];
    __shared__ __align__(16) unsigned short Ws[128 * 128];
    int tid = threadIdx.x;
    int wid = tid >> 6, l = tid & 63, lr = l & 15, lg = l >> 4;
    int row0 = blockIdx.x * 64;
    int myrow = row0 + wid * 16 + lr;
    f32x4 acc[8];
#pragma unroll
    for (int ni = 0; ni < 8; ++ni) {
        f32x4 z = { 0.f, 0.f, 0.f, 0.f };
        acc[ni] = z;
    }
    // stage 1: K=256 over [hn | mag], A streamed from global
    for (int kc = 0; kc < 2; ++kc) {
        const unsigned short* Xsrc = kc ? magbf : hnbf;
#pragma unroll
        for (int jj = 0; jj < 8; ++jj) {
            int j = tid + jj * 256;
            int r = j >> 4, c = j & 15;
            s16x8 wv = *reinterpret_cast<const s16x8*>(
                w1 + (size_t)r * 256 + kc * 128 + c * 8);
            *reinterpret_cast<s16x8*>(&Ws[r * 128 + ((c ^ (r & 7)) << 3)]) = wv;
        }
        light_barrier();
#pragma unroll
        for (int ks = 0; ks < 4; ++ks) {
            s16x8 af = *reinterpret_cast<const s16x8*>(
                Xsrc + (size_t)myrow * 128 + ks * 32 + lg * 8);
#pragma unroll
            for (int ni = 0; ni < 8; ++ni) {
                int n = ni * 16 + lr;
                int c = ks * 4 + lg;
                s16x8 bf = *reinterpret_cast<s16x8*>(&Ws[n * 128 + ((c ^ (n & 7)) << 3)]);
                acc[ni] = __builtin_amdgcn_mfma_f32_16x16x32_bf16(af, bf, acc[ni], 0, 0, 0);
            }
        }
        light_barrier();
    }
    // t = silu(acc + b1) -> As (own rows, swizzled)
#pragma unroll
    for (int ni = 0; ni < 8; ++ni) {
        int col = ni * 16 + lr;
        float bs = b1[col];
        int cc = col >> 3, cin = col & 7;
#pragma unroll
        for (int r4 = 0; r4 < 4; ++r4) {
            int rl = wid * 16 + lg * 4 + r4;
            As[rl * 128 + ((cc ^ (rl & 7)) << 3) + cin] =
                f2bf(silu_f(acc[ni][r4] + bs));
            acc[ni][r4] = 0.f;
        }
    }
#pragma unroll
    for (int jj = 0; jj < 8; ++jj) {
        int j = tid + jj * 256;
        int r = j >> 4, c = j & 15;
        s16x8 wv = *reinterpret_cast<const s16x8*>(w2 + (size_t)r * 128 + c * 8);
        *reinterpret_cast<s16x8*>(&Ws[r * 128 + ((c ^ (r & 7)) << 3)]) = wv;
    }
    light_barrier();
    // stage 2: t @ W2^T
#pragma unroll
    for (int ks = 0; ks < 4; ++ks) {
        int c = ks * 4 + lg;
        int r = wid * 16 + lr;
        s16x8 af = *reinterpret_cast<s16x8*>(&As[r * 128 + ((c ^ (r & 7)) << 3)]);
#pragma unroll
        for (int ni = 0; ni < 8; ++ni) {
            int n = ni * 16 + lr;
            s16x8 bf = *reinterpret_cast<s16x8*>(&Ws[n * 128 + ((c ^ (n & 7)) << 3)]);
            acc[ni] = __builtin_amdgcn_mfma_f32_16x16x32_bf16(af, bf, acc[ni], 0, 0, 0);
        }
    }
    // h = acc + b2 + resid(bf16 hn)
#pragma unroll
    for (int ni = 0; ni < 8; ++ni) {
        int col = ni * 16 + lr;
        float bs = b2[col];
#pragma unroll
        for (int r4 = 0; r4 < 4; ++r4) {
            int rowg = row0 + wid * 16 + lg * 4 + r4;
            acc[ni][r4] += bs + bf2f(hnbf[(size_t)rowg * HIDDEN + col]);
        }
    }
    if (!g) {
#pragma unroll
        for (int ni = 0; ni < 8; ++ni) {
            int col = ni * 16 + lr;
#pragma unroll
            for (int r4 = 0; r4 < 4; ++r4) {
                int rowg = row0 + wid * 16 + lg * 4 + r4;
                hbf_out[(size_t)rowg * HIDDEN + col] = f2bf(acc[ni][r4]);
            }
        }
        return;
    }
    // LN
    float s[4], q[4];
#pragma unroll
    for (int r4 = 0; r4 < 4; ++r4) {
        float ss = 0.f, qq = 0.f;
#pragma unroll
        for (int ni = 0; ni < 8; ++ni) {
            float v = acc[ni][r4];
            ss += v; qq += v * v;
        }
#pragma unroll
        for (int o = 1; o < 16; o <<= 1) {
            ss += __shfl_xor(ss, o, 64);
            qq += __shfl_xor(qq, o, 64);
        }
        float mu = ss * (1.f / 128.f);
        float var = qq * (1.f / 128.f) - mu * mu;
        s[r4] = mu;
        q[r4] = rsqrtf(var + 1e-5f);
    }
#pragma unroll
    for (int ni = 0; ni < 8; ++ni) {
        int col = ni * 16 + lr;
        float gg = g[col], bb = bet[col];
        int cc = col >> 3, cin = col & 7;
#pragma unroll
        for (int r4 = 0; r4 < 4; ++r4) {
            int rowg = row0 + wid * 16 + lg * 4 + r4;
            float o = (acc[ni][r4] - s[r4]) * q[r4] * gg + bb;
            hnbf[(size_t)rowg * HIDDEN + col] = f2bf(o);   // in-place update
            int rl = wid * 16 + lg * 4 + r4;
            As[rl * 128 + ((cc ^ (rl & 7)) << 3) + cin] = f2bf(o);
        }
    }
    light_barrier();    // all waves done reading Ws (stage 2)
#pragma unroll
    for (int half = 0; half < 2; ++half) {
#pragma unroll
        for (int jj = 0; jj < 8; ++jj) {
            int j = tid + jj * 256;
            int r = j >> 4, c = j & 15;
            s16x8 wv = *reinterpret_cast<const s16x8*>(
                w1ab_next + (size_t)(half * 128 + r) * 128 + c * 8);
            *reinterpret_cast<s16x8*>(&Ws[r * 128 + ((c ^ (r & 7)) << 3)]) = wv;
        }
        light_barrier();
#pragma unroll
        for (int ni = 0; ni < 8; ++ni) {
            f32x4 z = { 0.f, 0.f, 0.f, 0.f };
            acc[ni] = z;
        }
#pragma unroll
        for (int ks = 0; ks < 4; ++ks) {
            int c = ks * 4 + lg;
            int r = wid * 16 + lr;
            s16x8 af = *reinterpret_cast<s16x8*>(&As[r * 128 + ((c ^ (r & 7)) << 3)]);
#pragma unroll
            for (int ni = 0; ni < 8; ++ni) {
                int n = ni * 16 + lr;
                s16x8 bf = *reinterpret_cast<s16x8*>(&Ws[n * 128 + ((c ^ (n & 7)) << 3)]);
                acc[ni] = __builtin_amdgcn_mfma_f32_16x16x32_bf16(af, bf, acc[ni], 0, 0, 0);
            }
        }
#pragma unroll
        for (int ni = 0; ni < 8; ++ni) {
            int col = ni * 16 + lr;
            float bs = half ? eb1_next[col] : 0.f;
#pragma unroll
            for (int r4 = 0; r4 < 4; ++r4) {
                int rowg = row0 + wid * 16 + lg * 4 + r4;
                ab_out[(size_t)rowg * 256 + half * 128 + col] =
                    f2bf(acc[ni][r4] + bs);
            }
        }
        if (half == 0) light_barrier();
    }
}

// ---------------- edge MLP v9: 4 edges per barrier, 8 LDS buffers ---------
// Rounds alternate buffer quads (0-3 / 4-7): barrier of round r proves all
// waves finished round r-1 MFMAs (same quad as r+1's builds) -> race-free.
__global__ __launch_bounds__(256, 4) void edge_mfma9(
    const unsigned short* __restrict__ ABbf,
    const int* __restrict__ bcol,
    const int* __restrict__ brp,
    const unsigned short* __restrict__ w2bf,
    const float* __restrict__ c01,
    const float* __restrict__ eb2l,
    unsigned short* __restrict__ magbf) {
    __shared__ __align__(16) unsigned short m1[8][16 * 128];
    int tid = threadIdx.x;
    int blk = blockIdx.x;
    int i = blk >> 2, qtr = blk & 3;
    int wid = tid >> 6, l = tid & 63, lr = l & 15, lg = l >> 4;
    int rowb = qtr * 16;
    int col0 = wid * 32;

    s16x8 wfr[4][2];
#pragma unroll
    for (int ks = 0; ks < 4; ++ks)
#pragma unroll
        for (int ni = 0; ni < 2; ++ni) {
            int n = col0 + ni * 16 + lr;
            wfr[ks][ni] = *reinterpret_cast<const s16x8*>(
                w2bf + (size_t)n * 128 + (ks * 4 + lg) * 8);
        }

    int s = brp[i], e = brp[i + 1];
    int br = tid >> 4, bc = tid & 15;
    s16x8 Bp[2];
    {
        union { s16x8 s; unsigned int w[4]; } bv;
        bv.s = *reinterpret_cast<const s16x8*>(
            ABbf + ((size_t)i * NB + rowb + br) * 256 + 128 + bc * 8);
#pragma unroll
        for (int cls = 0; cls < 2; ++cls) {
            const float* cp = c01 + cls * 128 + bc * 8;
            float4 ca = *reinterpret_cast<const float4*>(cp);
            float4 cb = *reinterpret_cast<const float4*>(cp + 4);
            union { s16x8 s; unsigned int w[4]; } pk;
            pk.w[0] = cvt_pk_bf16(__uint_as_float(bv.w[0] << 16) + ca.x,
                                  __uint_as_float(bv.w[0] & 0xffff0000u) + ca.y);
            pk.w[1] = cvt_pk_bf16(__uint_as_float(bv.w[1] << 16) + ca.z,
                                  __uint_as_float(bv.w[1] & 0xffff0000u) + ca.w);
            pk.w[2] = cvt_pk_bf16(__uint_as_float(bv.w[2] << 16) + cb.x,
                                  __uint_as_float(bv.w[2] & 0xffff0000u) + cb.y);
            pk.w[3] = cvt_pk_bf16(__uint_as_float(bv.w[3] << 16) + cb.z,
                                  __uint_as_float(bv.w[3] & 0xffff0000u) + cb.w);
            Bp[cls] = pk.s;
        }
    }
    float e2[2], se[2];
#pragma unroll
    for (int ni = 0; ni < 2; ++ni) {
        e2[ni] = eb2l[col0 + ni * 16 + lr];
        se[ni] = silu_f(e2[ni]);
    }
    f32x4 agg[2];
#pragma unroll
    for (int ni = 0; ni < 2; ++ni) {
        f32x4 z = { 0.f, 0.f, 0.f, 0.f };
        agg[ni] = z;
    }

    auto loadA = [&](int t, int& pk) -> s16x8 {
        pk = __builtin_amdgcn_readfirstlane(bcol[t]);
        return *reinterpret_cast<const s16x8*>(
            ABbf + ((size_t)(pk & 0x7fff) * NB + rowb + br) * 256 + bc * 8);
    };
    auto build = [&](s16x8 A, int cls, int buf) {
        union { s16x8 s; unsigned int w[4]; } av, bv2, pkv;
        av.s = A;
        bv2.s = cls ? Bp[1] : Bp[0];
#pragma unroll
        for (int q = 0; q < 4; ++q) {
            float a0 = __uint_as_float(av.w[q] << 16);
            float a1 = __uint_as_float(av.w[q] & 0xffff0000u);
            float b0 = __uint_as_float(bv2.w[q] << 16);
            float b1 = __uint_as_float(bv2.w[q] & 0xffff0000u);
            pkv.w[q] = cvt_pk_bf16(silu_f(a0 + b0), silu_f(a1 + b1));
        }
        *reinterpret_cast<s16x8*>(
            &m1[buf][br * 128 + ((bc ^ (br & 7)) << 3)]) = pkv.s;
    };
    auto mfma_epi = [&](int buf) {
        f32x4 acc[2];
#pragma unroll
        for (int ni = 0; ni < 2; ++ni) {
            f32x4 iv = { e2[ni], e2[ni], e2[ni], e2[ni] };
            acc[ni] = iv;
        }
#pragma unroll
        for (int ks = 0; ks < 4; ++ks) {
            int cc = ks * 4 + lg;
            s16x8 af = *reinterpret_cast<s16x8*>(
                &m1[buf][lr * 128 + ((cc ^ (lr & 7)) << 3)]);
            acc[0] = __builtin_amdgcn_mfma_f32_16x16x32_bf16(af, wfr[ks][0], acc[0], 0, 0, 0);
            acc[1] = __builtin_amdgcn_mfma_f32_16x16x32_bf16(af, wfr[ks][1], acc[1], 0, 0, 0);
        }
#pragma unroll
        for (int ni = 0; ni < 2; ++ni)
#pragma unroll
            for (int r4 = 0; r4 < 4; ++r4)
                agg[ni][r4] += silu_f(acc[ni][r4]) - se[ni];
    };

    // preload first quad of edges
    int pk[4];
    s16x8 A[4];
    A[0] = loadA(s, pk[0]);
#pragma unroll
    for (int k = 1; k < 4; ++k) {
        pk[k] = pk[0];
        A[k] = A[0];
    }
#pragma unroll
    for (int k = 1; k < 4; ++k)
        if (s + k < e) A[k] = loadA(s + k, pk[k]);

    for (int t = s; t < e; t += 4) {
        int qb = (((t - s) >> 2) & 1) << 2;     // 0 or 4
        // prefetch next quad
        int pkn[4];
        s16x8 An[4];
#pragma unroll
        for (int k = 0; k < 4; ++k) {
            pkn[k] = pk[k];
            An[k] = A[k];
        }
#pragma unroll
        for (int k = 0; k < 4; ++k)
            if (t + 4 + k < e) An[k] = loadA(t + 4 + k, pkn[k]);
        // build this quad
        build(A[0], (pk[0] >> 15) & 1, qb);
#pragma unroll
        for (int k = 1; k < 4; ++k)
            if (t + k < e) build(A[k], (pk[k] >> 15) & 1, qb + k);
        light_barrier();
        mfma_epi(qb);
#pragma unroll
        for (int k = 1; k < 4; ++k)
            if (t + k < e) mfma_epi(qb + k);
#pragma unroll
        for (int k = 0; k < 4; ++k) {
            pk[k] = pkn[k];
            A[k] = An[k];
        }
    }

    float inv = (e > s) ? 1.f / (float)(e - s) : 0.f;
#pragma unroll
    for (int ni = 0; ni < 2; ++ni) {
#pragma unroll
        for (int r4 = 0; r4 < 4; ++r4) {
            size_t rowg = (size_t)i * NB + rowb + lg * 4 + r4;
            magbf[rowg * 128 + col0 + ni * 16 + lr] =
                f2bf(agg[ni][r4] * inv + se[ni]);
        }
    }
}

extern "C" void kernel_launch(void* const* d_in, const int* in_sizes, int n_in,
                              void* d_out, int out_size, void* d_ws, size_t ws_size,
                              hipStream_t stream) {
    const float* y     = (const float*)d_in[0];
    const float* gc    = (const float*)d_in[1];
    const int*   eidx  = (const int*)d_in[2];
    const float* W_in  = (const float*)d_in[3];
    const float* b_in  = (const float*)d_in[4];
    const float* gam   = (const float*)d_in[5];
    const float* bet   = (const float*)d_in[6];
    const float* eW1   = (const float*)d_in[7];
    const float* eb1   = (const float*)d_in[8];
    const float* eW2   = (const float*)d_in[9];
    const float* eb2   = (const float*)d_in[10];
    const float* nW1   = (const float*)d_in[11];
    const float* nb1   = (const float*)d_in[12];
    const float* nW2   = (const float*)d_in[13];
    const float* nb2   = (const float*)d_in[14];
    const float* W_out = (const float*)d_in[15];
    const float* b_out = (const float*)d_in[16];

    const int M = in_sizes[0] / CODE;       // 32768 (= NBASE * NB)
    const int E = in_sizes[2] / 2;
    const int baseE = E / NB;

    float* out = (float*)d_out;

    char* ws = (char*)d_ws;
    size_t off = 0;
    auto carve = [&](size_t bytes) {
        char* p = ws + off;
        off += (bytes + 255) & ~(size_t)255;
        return p;
    };
    unsigned short* hnbf    = (unsigned short*)carve((size_t)M * HIDDEN * 2);
    unsigned short* ABbf    = (unsigned short*)carve((size_t)M * 256 * 2);
    unsigned short* magbf   = (unsigned short*)carve((size_t)M * HIDDEN * 2);
    unsigned short* hbf     = (unsigned short*)carve((size_t)M * HIDDEN * 2);
    int*            brp     = (int*)carve((size_t)(NBASE + 1) * 4);
    int*            bcol    = (int*)carve((size_t)baseE * 4);
    unsigned short* winbf   = (unsigned short*)carve((size_t)HIDDEN * CODE * 2);
    unsigned short* woutbf  = (unsigned short*)carve((size_t)CODE * HIDDEN * 2);
    unsigned short* wn1bf   = (unsigned short*)carve((size_t)NLAYERS * HIDDEN * 256 * 2);
    unsigned short* wn2bf   = (unsigned short*)carve((size_t)NLAYERS * HIDDEN * HIDDEN * 2);
    unsigned short* w2bf    = (unsigned short*)carve((size_t)NLAYERS * HIDDEN * HIDDEN * 2);
    unsigned short* w1ab    = (unsigned short*)carve((size_t)NLAYERS * 256 * HIDDEN * 2);
    float*          c01     = (float*)carve((size_t)NLAYERS * 256 * 4);

    const int* row  = eidx;
    const int* colA = eidx + E;

    int prep_blocks = 519 + (baseE + 255) / 256;
    prep_all<<<dim3(prep_blocks), 256, 0, stream>>>(
        W_in, W_out, nW1, nW2, eW2, eW1, eb1, row, colA, gc,
        winbf, woutbf, wn1bf, wn2bf, w2bf, w1ab, c01,
        brp, bcol, baseE);

    // h0 = y @ W_in^T + b_in ; hn0 = LN0 ; layer-0 [A|B] (all fused)
    inproj_ln<<<dim3(M / 64), 256, 0, stream>>>(
        y, winbf, b_in, gam, bet, hnbf, w1ab, eb1, ABbf);

    for (int l = 0; l < NLAYERS; ++l) {
        edge_mfma9<<<dim3(NBASE * 4), 256, 0, stream>>>(
            ABbf, bcol, brp,
            w2bf + (size_t)l * HIDDEN * HIDDEN, c01 + (size_t)l * 256,
            eb2 + (size_t)l * HIDDEN, magbf);

        bool last = (l == NLAYERS - 1);
        nmlp_ln<<<dim3(M / 64), 256, 0, stream>>>(
            hnbf, magbf,
            wn1bf + (size_t)l * HIDDEN * 256, nb1 + (size_t)l * HIDDEN,
            wn2bf + (size_t)l * HIDDEN * HIDDEN, nb2 + (size_t)l * HIDDEN,
            last ? nullptr : gam + (size_t)(l + 1) * HIDDEN,
            last ? nullptr : bet + (size_t)(l + 1) * HIDDEN,
            hbf,
            last ? nullptr : w1ab + (size_t)(l + 1) * 256 * HIDDEN,
            last ? nullptr : eb1 + (size_t)(l + 1) * HIDDEN,
            last ? nullptr : ABbf);
    }

    // out = h @ W_out^T + b_out ; contiguous output rows, A gathered
    mgemm64<<<dim3(M / 64, CODE / 128), 256, 0, stream>>>(
        hbf, HIDDEN, woutbf, b_out, out, nullptr, CODE, 3);
}